// Round 2
// baseline (6417.629 us; speedup 1.0000x reference)
//
#include <hip/hip_runtime.h>
#include <math.h>

// ---------- constants ----------
#define Bc 4
#define Mc 4
#define Tc 128
#define Ec 512
#define Hc 2048
#define NEc 8
#define NSc 2
#define NHEADc 4
#define Pc 128
#define GRUHc 128
#define AKc 64
#define AVc 64
#define NTc 2048        // B*S
#define HDc 128         // E/NHEAD

typedef __bf16 bfv8 __attribute__((ext_vector_type(8)));
typedef float f32x4 __attribute__((ext_vector_type(4)));

// ---------------------------------------------------------------
__global__ __launch_bounds__(256)
void zero_k(float* __restrict__ out, int* __restrict__ cnt)
{
    int i = blockIdx.x * 256 + threadIdx.x;
    float4* o4 = (float4*)out;
    if (i < (NTc * Ec) / 4) o4[i] = make_float4(0.f, 0.f, 0.f, 0.f);
    if (i < NEc) cnt[i] = 0;
}

// ---------------------------------------------------------------
// fp32 tiled GEMM (router only — keeps top-2 routing bit-stable)
__global__ __launch_bounds__(256)
void gemm_k(const float* __restrict__ A, int lda,
            const float* __restrict__ B, int ldb,
            const float* __restrict__ bias,
            float* __restrict__ C, int ldc,
            int M, int N, int K, int relu)
{
    int tm = blockIdx.x * 64, tn = blockIdx.y * 64;
    if (tm >= M || tn >= N) return;
    __shared__ float As[16][68];
    __shared__ float Bs[16][68];
    int tid = threadIdx.x;
    int tx = tid & 15, ty = tid >> 4;
    float acc[4][4] = {};
    int arow = tid >> 2;
    int ak0  = (tid & 3) * 4;
    int bk   = tid >> 4;
    int bc0  = (tid & 15) * 4;
    int grA = tm + arow;
    const float* Arow = (grA < M) ? (A + (size_t)grA * lda) : nullptr;

    for (int k0 = 0; k0 < K; k0 += 16) {
#pragma unroll
        for (int u = 0; u < 4; ++u) {
            int k = k0 + ak0 + u;
            As[ak0 + u][arow] = (Arow && k < K) ? Arow[k] : 0.f;
        }
        int kb = k0 + bk;
#pragma unroll
        for (int u = 0; u < 4; ++u) {
            int n2 = tn + bc0 + u;
            Bs[bk][bc0 + u] = (kb < K && n2 < N) ? B[(size_t)kb * ldb + n2] : 0.f;
        }
        __syncthreads();
#pragma unroll
        for (int kk = 0; kk < 16; ++kk) {
            float a0 = As[kk][ty * 4 + 0], a1 = As[kk][ty * 4 + 1];
            float a2 = As[kk][ty * 4 + 2], a3 = As[kk][ty * 4 + 3];
            float b0 = Bs[kk][tx * 4 + 0], b1 = Bs[kk][tx * 4 + 1];
            float b2 = Bs[kk][tx * 4 + 2], b3 = Bs[kk][tx * 4 + 3];
            acc[0][0] += a0 * b0; acc[0][1] += a0 * b1; acc[0][2] += a0 * b2; acc[0][3] += a0 * b3;
            acc[1][0] += a1 * b0; acc[1][1] += a1 * b1; acc[1][2] += a1 * b2; acc[1][3] += a1 * b3;
            acc[2][0] += a2 * b0; acc[2][1] += a2 * b1; acc[2][2] += a2 * b2; acc[2][3] += a2 * b3;
            acc[3][0] += a3 * b0; acc[3][1] += a3 * b1; acc[3][2] += a3 * b2; acc[3][3] += a3 * b3;
        }
        __syncthreads();
    }
#pragma unroll
    for (int i = 0; i < 4; ++i) {
        int gr = tm + ty * 4 + i;
        if (gr >= M) continue;
#pragma unroll
        for (int j = 0; j < 4; ++j) {
            int gc = tn + tx * 4 + j;
            if (gc >= N) continue;
            float v = acc[i][j] + (bias ? bias[gc] : 0.f);
            if (relu) v = fmaxf(v, 0.f);
            C[(size_t)gr * ldc + gc] = v;
        }
    }
}

// ---------------------------------------------------------------
// bf16 MFMA GEMM: C = relu?( alpha*(A@B) + bias ), fp32 in/out,
// on-the-fly bf16 conversion in LDS staging.
// 128x128 block tile, 4 waves (each 64x64 = 4x4 mfma 16x16x32 tiles), BK=32.
// Options: dynamic M/N/K via device ptrs, row gather on A, B-transposed
// (B given as [N,K] rows), scatter-add epilogue.
#define LDA_S 40   // row stride in bf16 elems (32 + 8 pad, keeps 16B align)
__global__ __launch_bounds__(256)
void gemm_bf_k(const float* __restrict__ A, int lda,
               const float* __restrict__ B, int ldb, int btrans,
               const float* __restrict__ bias,
               float* __restrict__ C, int ldc,
               int M, int N, int K,
               const int* __restrict__ Mptr, const int* __restrict__ Nptr,
               const int* __restrict__ Kptr,
               const int* __restrict__ gatherA,
               float alpha, int relu,
               float* __restrict__ scatterOut,
               const int* __restrict__ scatterList,
               const float* __restrict__ wvec)
{
    if (Mptr) M = *Mptr;
    if (Nptr) N = *Nptr;
    if (Kptr) K = *Kptr;
    int tm = blockIdx.x * 128, tn = blockIdx.y * 128;
    if (tm >= M || tn >= N) return;

    __shared__ __bf16 As[128 * LDA_S];
    __shared__ __bf16 Bs[128 * LDA_S];
    int tid = threadIdx.x, lane = tid & 63, wv = tid >> 6;
    int wm = (wv & 1) * 64, wn = (wv >> 1) * 64;
    f32x4 acc[4][4] = {};

    // A staging: thread -> row ar (0..127), half ah (0 or 16 k's)
    int ar = tid >> 1, ah = (tid & 1) * 16;
    const float* Aptr = nullptr;
    {
        int arow = tm + ar;
        if (arow < M) {
            int g = gatherA ? gatherA[arow] : arow;
            Aptr = A + (size_t)g * lda;
        }
    }
    const float* Bptr_t = nullptr;     // btrans: B row pointer (free dim)
    if (btrans) {
        int brow = tn + ar;
        if (brow < N) Bptr_t = B + (size_t)brow * ldb;
    }
    int kg = tid >> 7, bn = tid & 127; // normal-B staging coords
    bool bnok = (tn + bn) < N;

    for (int k0 = 0; k0 < K; k0 += 32) {
        // ---- stage A ----
        {
            float f[16];
            int kb = k0 + ah;
            if (Aptr) {
                if (kb + 16 <= K) {
                    const float4* p = (const float4*)(Aptr + kb);
                    float4 x0 = p[0], x1 = p[1], x2 = p[2], x3 = p[3];
                    f[0]=x0.x; f[1]=x0.y; f[2]=x0.z; f[3]=x0.w;
                    f[4]=x1.x; f[5]=x1.y; f[6]=x1.z; f[7]=x1.w;
                    f[8]=x2.x; f[9]=x2.y; f[10]=x2.z; f[11]=x2.w;
                    f[12]=x3.x; f[13]=x3.y; f[14]=x3.z; f[15]=x3.w;
                } else {
#pragma unroll
                    for (int i = 0; i < 16; ++i) f[i] = (kb + i < K) ? Aptr[kb + i] : 0.f;
                }
            } else {
#pragma unroll
                for (int i = 0; i < 16; ++i) f[i] = 0.f;
            }
            bfv8 p0, p1;
#pragma unroll
            for (int i = 0; i < 8; ++i) { p0[i] = (__bf16)f[i]; p1[i] = (__bf16)f[8 + i]; }
            *(bfv8*)(As + ar * LDA_S + ah) = p0;
            *(bfv8*)(As + ar * LDA_S + ah + 8) = p1;
        }
        // ---- stage B ----
        if (btrans) {
            float f[16];
            int kb = k0 + ah;
            if (Bptr_t) {
                if (kb + 16 <= K) {
                    const float4* p = (const float4*)(Bptr_t + kb);
                    float4 x0 = p[0], x1 = p[1], x2 = p[2], x3 = p[3];
                    f[0]=x0.x; f[1]=x0.y; f[2]=x0.z; f[3]=x0.w;
                    f[4]=x1.x; f[5]=x1.y; f[6]=x1.z; f[7]=x1.w;
                    f[8]=x2.x; f[9]=x2.y; f[10]=x2.z; f[11]=x2.w;
                    f[12]=x3.x; f[13]=x3.y; f[14]=x3.z; f[15]=x3.w;
                } else {
#pragma unroll
                    for (int i = 0; i < 16; ++i) f[i] = (kb + i < K) ? Bptr_t[kb + i] : 0.f;
                }
            } else {
#pragma unroll
                for (int i = 0; i < 16; ++i) f[i] = 0.f;
            }
            bfv8 p0, p1;
#pragma unroll
            for (int i = 0; i < 8; ++i) { p0[i] = (__bf16)f[i]; p1[i] = (__bf16)f[8 + i]; }
            *(bfv8*)(Bs + ar * LDA_S + ah) = p0;
            *(bfv8*)(Bs + ar * LDA_S + ah + 8) = p1;
        } else {
            float f[16];
            const float* bp = B + (size_t)(k0 + kg * 16) * ldb + tn + bn;
#pragma unroll
            for (int j = 0; j < 16; ++j) {
                int kk = k0 + kg * 16 + j;
                f[j] = (bnok && kk < K) ? bp[(size_t)j * ldb] : 0.f;
            }
            bfv8 p0, p1;
#pragma unroll
            for (int i = 0; i < 8; ++i) { p0[i] = (__bf16)f[i]; p1[i] = (__bf16)f[8 + i]; }
            *(bfv8*)(Bs + bn * LDA_S + kg * 16) = p0;
            *(bfv8*)(Bs + bn * LDA_S + kg * 16 + 8) = p1;
        }
        __syncthreads();
        // ---- fragments + MFMA ----
        {
            int fr = lane & 15, quad = lane >> 4;
            bfv8 af[4], bfr[4];
            const __bf16* Ab = As + quad * 8 + fr * LDA_S;
            const __bf16* Bb = Bs + quad * 8 + fr * LDA_S;
#pragma unroll
            for (int t2 = 0; t2 < 4; ++t2) {
                af[t2]  = *(const bfv8*)(Ab + (wm + t2 * 16) * LDA_S);
                bfr[t2] = *(const bfv8*)(Bb + (wn + t2 * 16) * LDA_S);
            }
#pragma unroll
            for (int i = 0; i < 4; ++i)
#pragma unroll
                for (int j = 0; j < 4; ++j)
                    acc[i][j] = __builtin_amdgcn_mfma_f32_16x16x32_bf16(af[i], bfr[j], acc[i][j], 0, 0, 0);
        }
        __syncthreads();
    }

    // ---- epilogue: C layout col=lane&15, row=(lane>>4)*4+reg ----
    int col = lane & 15, rq = (lane >> 4) * 4;
#pragma unroll
    for (int ti = 0; ti < 4; ++ti) {
#pragma unroll
        for (int tj = 0; tj < 4; ++tj) {
#pragma unroll
            for (int r = 0; r < 4; ++r) {
                int gm = tm + wm + ti * 16 + rq + r;
                int gn = tn + wn + tj * 16 + col;
                if (gm < M && gn < N) {
                    float v = acc[ti][tj][r] * alpha + (bias ? bias[gn] : 0.f);
                    if (relu) v = fmaxf(v, 0.f);
                    if (scatterOut) {
                        int g = scatterList[gm];
                        scatterOut[(size_t)g * Ec + gn] += v * wvec[(size_t)g * NEc];
                    } else {
                        C[(size_t)gm * ldc + gn] = v;
                    }
                }
            }
        }
    }
}

// ---------------------------------------------------------------
// router 3-key attention -> ctx [2048,64]; one wave per token
__global__ __launch_bounds__(256)
void router_ctx_k(const float* __restrict__ q4, const float* __restrict__ rR,
                  const float* __restrict__ rS,
                  const float* __restrict__ Wk, const float* __restrict__ bk,
                  const float* __restrict__ Wv, const float* __restrict__ bv,
                  float* __restrict__ ctx)
{
    int tid = threadIdx.x;
    int lane = tid & 63;
    int n = blockIdx.x * 4 + (tid >> 6);
    int m = (n >> 7) & 3, t = n & 127, b = n >> 9;
    float q = q4[(size_t)n * AKc + lane];
    float sc[3], rv[3], sv[3];
#pragma unroll
    for (int o = 0; o < 3; ++o) {
        int oth = o + (o >= m ? 1 : 0);
        float r = rR[(((size_t)(b * Mc + m)) * Mc + oth) * Tc + t];
        float s_ = rS[(((size_t)(b * Mc + m)) * Mc + oth) * Tc + t];
        rv[o] = r; sv[o] = s_;
        float key = r * Wk[lane] + s_ * Wk[64 + lane] + bk[lane];
        float p = q * key;
#pragma unroll
        for (int off = 32; off; off >>= 1) p += __shfl_xor(p, off, 64);
        sc[o] = p * 0.125f;
    }
    float mx = fmaxf(sc[0], fmaxf(sc[1], sc[2]));
    float e0 = expf(sc[0] - mx), e1 = expf(sc[1] - mx), e2 = expf(sc[2] - mx);
    float inv = 1.f / (e0 + e1 + e2);
    float p0 = e0 * inv, p1 = e1 * inv, p2 = e2 * inv;
    float v0 = rv[0] * Wv[lane] + sv[0] * Wv[64 + lane] + bv[lane];
    float v1 = rv[1] * Wv[lane] + sv[1] * Wv[64 + lane] + bv[lane];
    float v2 = rv[2] * Wv[lane] + sv[2] * Wv[64 + lane] + bv[lane];
    ctx[(size_t)n * AVc + lane] = p0 * v0 + p1 * v1 + p2 * v2;
}

// ---------------------------------------------------------------
__global__ __launch_bounds__(256)
void gi_k(const float* __restrict__ rU, const float* __restrict__ ctx,
          const float* __restrict__ gWih, const float* __restrict__ gbih,
          float* __restrict__ gi)
{
    int idx = blockIdx.x * 256 + threadIdx.x;   // < 2048*384
    int g = idx % 384, nt = idx / 384;
    const float* Wr = gWih + (size_t)g * 65;
    float a = gbih[g] + rU[nt] * Wr[0];
    const float* c = ctx + (size_t)nt * AVc;
#pragma unroll
    for (int d = 0; d < 64; ++d) a += c[d] * Wr[1 + d];
    gi[(size_t)nt * 384 + g] = a;
}

// ---------------------------------------------------------------
// GRU scan: one block per sequence (16), 384 threads.
// Each thread keeps its gWhh row (128 floats) in VGPRs; h broadcast from LDS.
__global__ __launch_bounds__(384)
void gru_scan_k(const float* __restrict__ gi, const float* __restrict__ gWhh,
                const float* __restrict__ gbhh, float* __restrict__ hs)
{
    int seq = blockIdx.x, g = threadIdx.x;
    __shared__ float h[128];
    __shared__ float gh[384];
    float w[128];
    const float4* wr = (const float4*)(gWhh + (size_t)g * 128);
#pragma unroll
    for (int i = 0; i < 32; ++i) {
        float4 t = wr[i];
        w[4*i] = t.x; w[4*i+1] = t.y; w[4*i+2] = t.z; w[4*i+3] = t.w;
    }
    float bh = gbhh[g];
    if (g < 128) h[g] = 0.f;
    __syncthreads();
    for (int t = 0; t < 128; ++t) {
        const float* gr = gi + ((size_t)seq * 128 + t) * 384;
        float g0 = 0.f, g1 = 0.f, g2 = 0.f;
        if (g < 128) { g0 = gr[g]; g1 = gr[128 + g]; g2 = gr[256 + g]; }
        float a0 = 0.f, a1 = 0.f, a2 = 0.f, a3 = 0.f;
#pragma unroll
        for (int d = 0; d < 128; d += 4) {
            float4 h4 = *(const float4*)(&h[d]);   // LDS broadcast
            a0 += h4.x * w[d];     a1 += h4.y * w[d + 1];
            a2 += h4.z * w[d + 2]; a3 += h4.w * w[d + 3];
        }
        gh[g] = bh + (a0 + a1) + (a2 + a3);
        __syncthreads();
        if (g < 128) {
            float r = 1.f / (1.f + expf(-(g0 + gh[g])));
            float z = 1.f / (1.f + expf(-(g1 + gh[128 + g])));
            float nn = tanhf(g2 + r * gh[256 + g]);
            float hn = (1.f - z) * nn + z * h[g];
            hs[((size_t)seq * 128 + t) * 128 + g] = hn;
            h[g] = hn;
        }
        __syncthreads();
    }
}

// ---------------------------------------------------------------
__global__ __launch_bounds__(128)
void mlp_route_k(const float* __restrict__ proc, const float* __restrict__ hs,
                 const float* __restrict__ mW1, const float* __restrict__ mb1,
                 const float* __restrict__ mW2, const float* __restrict__ mb2,
                 float* __restrict__ probsOut, float* __restrict__ idxOut,
                 float* __restrict__ w)
{
    int n = blockIdx.x, tid = threadIdx.x;
    __shared__ float comb[256], tmp[128], lg[8];
    comb[tid] = proc[(size_t)n * 128 + tid];
    comb[128 + tid] = hs[(size_t)n * 128 + tid];
    __syncthreads();
    float a = mb1[tid];
#pragma unroll 8
    for (int d = 0; d < 256; ++d) a += comb[d] * mW1[(size_t)d * 128 + tid];
    tmp[tid] = fmaxf(a, 0.f);
    __syncthreads();
    if (tid < 8) {
        float l = mb2[tid];
        for (int d = 0; d < 128; ++d) l += tmp[d] * mW2[(size_t)d * 8 + tid];
        lg[tid] = l;
    }
    __syncthreads();
    if (tid == 0) {
        float mx = lg[0];
        for (int e = 1; e < 8; ++e) mx = fmaxf(mx, lg[e]);
        float p[8], s = 0.f;
        for (int e = 0; e < 8; ++e) { p[e] = expf(lg[e] - mx); s += p[e]; }
        float inv = 1.f / s;
        for (int e = 0; e < 8; ++e) probsOut[(size_t)n * 8 + e] = p[e] * inv;
        int a0 = 0; float v0 = lg[0];
        for (int e = 1; e < 8; ++e) if (lg[e] > v0) { v0 = lg[e]; a0 = e; }
        int a1 = -1; float v1 = -1e30f;
        for (int e = 0; e < 8; ++e) if (e != a0 && lg[e] > v1) { v1 = lg[e]; a1 = e; }
        float e1 = expf(v1 - v0);
        float t0 = 1.f / (1.f + e1), t1 = e1 / (1.f + e1);
        idxOut[(size_t)n * 2 + 0] = (float)a0;
        idxOut[(size_t)n * 2 + 1] = (float)a1;
        for (int e = 0; e < 8; ++e) w[(size_t)n * 8 + e] = 0.f;
        w[(size_t)n * 8 + a0] = t0;
        w[(size_t)n * 8 + a1] = t1;
    }
}

__global__ __launch_bounds__(256)
void compact_k(const float* __restrict__ w, int* __restrict__ cnt,
               int* __restrict__ list)
{
    int n = blockIdx.x * 256 + threadIdx.x;
    if (n >= NTc) return;
    for (int e = 0; e < NEc; ++e)
        if (w[(size_t)n * 8 + e] > 0.f) {
            int p = atomicAdd(&cnt[e], 1);
            list[e * NTc + p] = n;
        }
}

// ---------------------------------------------------------------
__global__ __launch_bounds__(256)
void softmax_rows_k(float* __restrict__ S, const int* __restrict__ cntPtr)
{
    int nv = *cntPtr;
    int i = blockIdx.x;
    if (i >= nv) return;
    float* row = S + (size_t)i * NTc;
    int tid = threadIdx.x;
    __shared__ float red[256];
    float mx = -1e30f;
    for (int j = tid; j < nv; j += 256) mx = fmaxf(mx, row[j]);
    red[tid] = mx; __syncthreads();
    for (int st = 128; st > 0; st >>= 1) { if (tid < st) red[tid] = fmaxf(red[tid], red[tid + st]); __syncthreads(); }
    mx = red[0]; __syncthreads();
    float sum = 0.f;
    for (int j = tid; j < nv; j += 256) { float e = expf(row[j] - mx); row[j] = e; sum += e; }
    red[tid] = sum; __syncthreads();
    for (int st = 128; st > 0; st >>= 1) { if (tid < st) red[tid] += red[tid + st]; __syncthreads(); }
    float inv = 1.f / red[0];
    for (int j = tid; j < nv; j += 256) row[j] *= inv;
}

__global__ __launch_bounds__(256)
void ln1_k(const float* __restrict__ x, const int* __restrict__ list,
           const float* __restrict__ add, const float* __restrict__ s,
           const float* __restrict__ b, float* __restrict__ outRows,
           const int* __restrict__ cntPtr)
{
    int i = blockIdx.x;
    if (i >= *cntPtr) return;
    int tid = threadIdx.x;
    int g = list[i];
    float v0 = x[(size_t)g * Ec + tid] + add[(size_t)i * Ec + tid];
    float v1 = x[(size_t)g * Ec + 256 + tid] + add[(size_t)i * Ec + 256 + tid];
    __shared__ float red[256];
    __shared__ float bc;
    red[tid] = v0 + v1; __syncthreads();
    for (int st = 128; st > 0; st >>= 1) { if (tid < st) red[tid] += red[tid + st]; __syncthreads(); }
    if (tid == 0) bc = red[0] * (1.f / 512.f);
    __syncthreads();
    float mu = bc;
    float d0 = v0 - mu, d1 = v1 - mu;
    __syncthreads();
    red[tid] = d0 * d0 + d1 * d1; __syncthreads();
    for (int st = 128; st > 0; st >>= 1) { if (tid < st) red[tid] += red[tid + st]; __syncthreads(); }
    if (tid == 0) bc = rsqrtf(red[0] * (1.f / 512.f) + 1e-5f);
    __syncthreads();
    float inv = bc;
    outRows[(size_t)i * Ec + tid] = d0 * inv * s[tid] + b[tid];
    outRows[(size_t)i * Ec + 256 + tid] = d1 * inv * s[256 + tid] + b[256 + tid];
}

__global__ __launch_bounds__(256)
void ln2_scatter_k(const float* __restrict__ H1, const float* __restrict__ Y,
                   const float* __restrict__ s, const float* __restrict__ b,
                   float* __restrict__ out, const int* __restrict__ list,
                   const int* __restrict__ cntPtr, const float* __restrict__ wvec)
{
    int i = blockIdx.x;
    if (i >= *cntPtr) return;
    int tid = threadIdx.x;
    int g = list[i];
    float v0 = H1[(size_t)i * Ec + tid] + Y[(size_t)i * Ec + tid];
    float v1 = H1[(size_t)i * Ec + 256 + tid] + Y[(size_t)i * Ec + 256 + tid];
    __shared__ float red[256];
    __shared__ float bc;
    red[tid] = v0 + v1; __syncthreads();
    for (int st = 128; st > 0; st >>= 1) { if (tid < st) red[tid] += red[tid + st]; __syncthreads(); }
    if (tid == 0) bc = red[0] * (1.f / 512.f);
    __syncthreads();
    float mu = bc;
    float d0 = v0 - mu, d1 = v1 - mu;
    __syncthreads();
    red[tid] = d0 * d0 + d1 * d1; __syncthreads();
    for (int st = 128; st > 0; st >>= 1) { if (tid < st) red[tid] += red[tid + st]; __syncthreads(); }
    if (tid == 0) bc = rsqrtf(red[0] * (1.f / 512.f) + 1e-5f);
    __syncthreads();
    float inv = bc;
    float wv = wvec[(size_t)g * 8];
    out[(size_t)g * Ec + tid] += (d0 * inv * s[tid] + b[tid]) * wv;
    out[(size_t)g * Ec + 256 + tid] += (d1 * inv * s[256 + tid] + b[256 + tid]) * wv;
}

// ---------------------------------------------------------------
static inline void gemm_bf(hipStream_t st, int gx, int gy,
                           const float* A, int lda, const float* B, int ldb, int btrans,
                           const float* bias, float* C, int ldc,
                           int M, int N, int K,
                           const int* Mptr, const int* Nptr, const int* Kptr,
                           const int* gatherA, float alpha, int relu,
                           float* scOut, const int* scList, const float* wv)
{
    gemm_bf_k<<<dim3(gx, gy), 256, 0, st>>>(A, lda, B, ldb, btrans, bias, C, ldc,
                                            M, N, K, Mptr, Nptr, Kptr, gatherA,
                                            alpha, relu, scOut, scList, wv);
}

extern "C" void kernel_launch(void* const* d_in, const int* in_sizes, int n_in,
                              void* d_out, int out_size, void* d_ws, size_t ws_size,
                              hipStream_t stream)
{
    const float* x    = (const float*)d_in[0];
    const float* rU   = (const float*)d_in[1];
    const float* rR   = (const float*)d_in[2];
    const float* rS   = (const float*)d_in[3];
    const float* Wtp  = (const float*)d_in[6];
    const float* btp  = (const float*)d_in[7];
    const float* Wq   = (const float*)d_in[8];
    const float* bq   = (const float*)d_in[9];
    const float* Wk   = (const float*)d_in[10];
    const float* bk   = (const float*)d_in[11];
    const float* Wv   = (const float*)d_in[12];
    const float* bv   = (const float*)d_in[13];
    const float* gWih = (const float*)d_in[14];
    const float* gbih = (const float*)d_in[15];
    const float* gWhh = (const float*)d_in[16];
    const float* gbhh = (const float*)d_in[17];
    const float* mW1  = (const float*)d_in[18];
    const float* mb1  = (const float*)d_in[19];
    const float* mW2  = (const float*)d_in[20];
    const float* mb2  = (const float*)d_in[21];
    const float* sWq  = (const float*)d_in[22];
    const float* sbq  = (const float*)d_in[23];
    const float* sWk  = (const float*)d_in[24];
    const float* sbk  = (const float*)d_in[25];
    const float* sWv  = (const float*)d_in[26];
    const float* sbv  = (const float*)d_in[27];
    const float* sWo  = (const float*)d_in[28];
    const float* sbo  = (const float*)d_in[29];
    const float* sln1s = (const float*)d_in[30];
    const float* sln1b = (const float*)d_in[31];
    const float* sW1  = (const float*)d_in[32];
    const float* sb1  = (const float*)d_in[33];
    const float* sW2  = (const float*)d_in[34];
    const float* sb2  = (const float*)d_in[35];
    const float* sln2s = (const float*)d_in[36];
    const float* sln2b = (const float*)d_in[37];
    const float* fW1  = (const float*)d_in[38];
    const float* fb1  = (const float*)d_in[39];
    const float* fW2  = (const float*)d_in[40];
    const float* fb2  = (const float*)d_in[41];

    float* out      = (float*)d_out;                 // [2048,512]
    float* probsOut = out + (size_t)NTc * Ec;        // [2048,8]
    float* idxOut   = probsOut + (size_t)NTc * NEc;  // [2048,2]

    // workspace layout
    int*   cnt  = (int*)d_ws;
    int*   list = cnt + 64;
    float* w    = (float*)d_ws + 64 + NEc * NTc;
    float* B0   = w + NTc * NEc;
    // router region (dead before experts start)
    float* proc = B0;                  // 2048*128
    float* q4   = proc + 262144;       // 2048*64
    float* ctx  = q4 + 131072;         // 2048*64
    float* gi   = ctx + 131072;        // 16*128*384
    float* hs   = gi + 786432;         // 2048*128
    // expert region (overlays router region)
    float* S   = B0;                   // 2048*2048
    float* Qb  = S + 4194304;          // 2048*512
    float* Kb  = Qb + 1048576;
    float* Vb  = Kb + 1048576;
    float* AO  = Vb + 1048576;
    float* PRJ = AO + 1048576;
    float* H1  = PRJ + 1048576;
    float* Yb  = H1 + 1048576;
    float* FF1 = Yb + 1048576;         // 2048*2048

    const float invsq = 0.08838834764831845f;  // 1/sqrt(128)

    // ---- init ----
    zero_k<<<1024, 256, 0, stream>>>(out, cnt);

    // ---- router (fp32 — keeps top-2 idx bit-stable) ----
    gemm_k<<<dim3(32, 2), 256, 0, stream>>>(x, Ec, Wtp, Pc, btp, proc, Pc, NTc, Pc, Ec, 1);
    gemm_k<<<dim3(32, 1), 256, 0, stream>>>(proc, Pc, Wq, AKc, bq, q4, AKc, NTc, AKc, Pc, 0);
    router_ctx_k<<<512, 256, 0, stream>>>(q4, rR, rS, Wk, bk, Wv, bv, ctx);
    gi_k<<<3072, 256, 0, stream>>>(rU, ctx, gWih, gbih, gi);
    gru_scan_k<<<16, 384, 0, stream>>>(gi, gWhh, gbhh, hs);
    mlp_route_k<<<2048, 128, 0, stream>>>(proc, hs, mW1, mb1, mW2, mb2,
                                          probsOut, idxOut, w);
    compact_k<<<8, 256, 0, stream>>>(w, cnt, list);

    // ---- synergy experts (bf16 MFMA) ----
    for (int e = 0; e < NSc; ++e) {
        const int* cl = list + e * NTc;
        const int* ce = cnt + e;
        gemm_bf(stream, 16, 4, x, Ec, sWq + (size_t)e * Ec * Ec, Ec, 0, sbq + e * Ec, Qb, Ec,
                NTc, Ec, Ec, ce, nullptr, nullptr, cl, 1.f, 0, nullptr, nullptr, nullptr);
        gemm_bf(stream, 16, 4, x, Ec, sWk + (size_t)e * Ec * Ec, Ec, 0, sbk + e * Ec, Kb, Ec,
                NTc, Ec, Ec, ce, nullptr, nullptr, cl, 1.f, 0, nullptr, nullptr, nullptr);
        gemm_bf(stream, 16, 4, x, Ec, sWv + (size_t)e * Ec * Ec, Ec, 0, sbv + e * Ec, Vb, Ec,
                NTc, Ec, Ec, ce, nullptr, nullptr, cl, 1.f, 0, nullptr, nullptr, nullptr);
        for (int h = 0; h < NHEADc; ++h) {
            gemm_bf(stream, 16, 16, Qb + h * HDc, Ec, Kb + h * HDc, Ec, 1, nullptr, S, NTc,
                    NTc, NTc, HDc, ce, ce, nullptr, nullptr, invsq, 0, nullptr, nullptr, nullptr);
            softmax_rows_k<<<2048, 256, 0, stream>>>(S, ce);
            gemm_bf(stream, 16, 1, S, NTc, Vb + h * HDc, Ec, 0, nullptr, AO + h * HDc, Ec,
                    NTc, HDc, NTc, ce, nullptr, ce, nullptr, 1.f, 0, nullptr, nullptr, nullptr);
        }
        gemm_bf(stream, 16, 4, AO, Ec, sWo + (size_t)e * Ec * Ec, Ec, 0, sbo + e * Ec, PRJ, Ec,
                NTc, Ec, Ec, ce, nullptr, nullptr, nullptr, 1.f, 0, nullptr, nullptr, nullptr);
        ln1_k<<<2048, 256, 0, stream>>>(x, cl, PRJ, sln1s + e * Ec, sln1b + e * Ec, H1, ce);
        gemm_bf(stream, 16, 16, H1, Ec, sW1 + (size_t)e * Ec * Hc, Hc, 0, sb1 + e * Hc, FF1, Hc,
                NTc, Hc, Ec, ce, nullptr, nullptr, nullptr, 1.f, 1, nullptr, nullptr, nullptr);
        gemm_bf(stream, 16, 4, FF1, Hc, sW2 + (size_t)e * Hc * Ec, Ec, 0, sb2 + e * Ec, Yb, Ec,
                NTc, Ec, Hc, ce, nullptr, nullptr, nullptr, 1.f, 0, nullptr, nullptr, nullptr);
        ln2_scatter_k<<<2048, 256, 0, stream>>>(H1, Yb, sln2s + e * Ec, sln2b + e * Ec,
                                                out, cl, ce, w + e);
    }

    // ---- FFN experts (bf16 MFMA) ----
    for (int f = 0; f < NEc - NSc; ++f) {
        int e = f + NSc;
        const int* cl = list + e * NTc;
        const int* ce = cnt + e;
        gemm_bf(stream, 16, 16, x, Ec, fW1 + (size_t)f * Ec * Hc, Hc, 0, fb1 + f * Hc, FF1, Hc,
                NTc, Hc, Ec, ce, nullptr, nullptr, cl, 1.f, 1, nullptr, nullptr, nullptr);
        gemm_bf(stream, 16, 4, FF1, Hc, fW2 + (size_t)f * Hc * Ec, Ec, 0, fb2 + f * Ec,
                nullptr, Ec, NTc, Ec, Hc, ce, nullptr, nullptr, nullptr, 1.f, 0,
                out, cl, w + e);
    }
}

// Round 3
// 2167.504 us; speedup vs baseline: 2.9608x; 2.9608x over previous
//
#include <hip/hip_runtime.h>
#include <math.h>

// ---------- constants ----------
#define Bc 4
#define Mc 4
#define Tc 128
#define Ec 512
#define Hc 2048
#define NEc 8
#define NSc 2
#define NHEADc 4
#define Pc 128
#define GRUHc 128
#define AKc 64
#define AVc 64
#define NTc 2048        // B*S
#define HDc 128         // E/NHEAD

typedef __bf16 bfv8 __attribute__((ext_vector_type(8)));
typedef float f32x4 __attribute__((ext_vector_type(4)));

// ---------------------------------------------------------------
__global__ __launch_bounds__(256)
void zero_k(float* __restrict__ out, int* __restrict__ cnt)
{
    int i = blockIdx.x * 256 + threadIdx.x;
    float4* o4 = (float4*)out;
    if (i < (NTc * Ec) / 4) o4[i] = make_float4(0.f, 0.f, 0.f, 0.f);
    if (i < NEc) cnt[i] = 0;
}

// ---------------------------------------------------------------
// tiled transpose + fp32->bf16 convert: W[K,N] -> Wt[N,K]
__global__ __launch_bounds__(256)
void convT_k(const float* __restrict__ W, __bf16* __restrict__ Wt, int K, int N)
{
    __shared__ float t[32][33];
    int bx = blockIdx.x * 32;   // n tile
    int by = blockIdx.y * 32;   // k tile
    int tx = threadIdx.x & 31, ty = threadIdx.x >> 5;   // 32 x 8
#pragma unroll
    for (int i = 0; i < 4; ++i) {
        int k = by + ty + i * 8, n = bx + tx;
        t[ty + i * 8][tx] = (k < K && n < N) ? W[(size_t)k * N + n] : 0.f;
    }
    __syncthreads();
#pragma unroll
    for (int i = 0; i < 4; ++i) {
        int n = bx + ty + i * 8, k = by + tx;
        if (n < N && k < K) Wt[(size_t)n * K + k] = (__bf16)t[tx][ty + i * 8];
    }
}

// ---------------------------------------------------------------
// fp32 tiled GEMM (router only — keeps top-2 routing bit-stable)
__global__ __launch_bounds__(256)
void gemm_k(const float* __restrict__ A, int lda,
            const float* __restrict__ B, int ldb,
            const float* __restrict__ bias,
            float* __restrict__ C, int ldc,
            int M, int N, int K, int relu)
{
    int tm = blockIdx.x * 64, tn = blockIdx.y * 64;
    if (tm >= M || tn >= N) return;
    __shared__ float As[16][68];
    __shared__ float Bs[16][68];
    int tid = threadIdx.x;
    int tx = tid & 15, ty = tid >> 4;
    float acc[4][4] = {};
    int arow = tid >> 2;
    int ak0  = (tid & 3) * 4;
    int bk   = tid >> 4;
    int bc0  = (tid & 15) * 4;
    int grA = tm + arow;
    const float* Arow = (grA < M) ? (A + (size_t)grA * lda) : nullptr;

    for (int k0 = 0; k0 < K; k0 += 16) {
#pragma unroll
        for (int u = 0; u < 4; ++u) {
            int k = k0 + ak0 + u;
            As[ak0 + u][arow] = (Arow && k < K) ? Arow[k] : 0.f;
        }
        int kb = k0 + bk;
#pragma unroll
        for (int u = 0; u < 4; ++u) {
            int n2 = tn + bc0 + u;
            Bs[bk][bc0 + u] = (kb < K && n2 < N) ? B[(size_t)kb * ldb + n2] : 0.f;
        }
        __syncthreads();
#pragma unroll
        for (int kk = 0; kk < 16; ++kk) {
            float a0 = As[kk][ty * 4 + 0], a1 = As[kk][ty * 4 + 1];
            float a2 = As[kk][ty * 4 + 2], a3 = As[kk][ty * 4 + 3];
            float b0 = Bs[kk][tx * 4 + 0], b1 = Bs[kk][tx * 4 + 1];
            float b2 = Bs[kk][tx * 4 + 2], b3 = Bs[kk][tx * 4 + 3];
            acc[0][0] += a0 * b0; acc[0][1] += a0 * b1; acc[0][2] += a0 * b2; acc[0][3] += a0 * b3;
            acc[1][0] += a1 * b0; acc[1][1] += a1 * b1; acc[1][2] += a1 * b2; acc[1][3] += a1 * b3;
            acc[2][0] += a2 * b0; acc[2][1] += a2 * b1; acc[2][2] += a2 * b2; acc[2][3] += a2 * b3;
            acc[3][0] += a3 * b0; acc[3][1] += a3 * b1; acc[3][2] += a3 * b2; acc[3][3] += a3 * b3;
        }
        __syncthreads();
    }
#pragma unroll
    for (int i = 0; i < 4; ++i) {
        int gr = tm + ty * 4 + i;
        if (gr >= M) continue;
#pragma unroll
        for (int j = 0; j < 4; ++j) {
            int gc = tn + tx * 4 + j;
            if (gc >= N) continue;
            float v = acc[i][j] + (bias ? bias[gc] : 0.f);
            if (relu) v = fmaxf(v, 0.f);
            C[(size_t)gr * ldc + gc] = v;
        }
    }
}

// ---------------------------------------------------------------
// bf16 MFMA GEMM, v2.
// A: fp32 rows [M][lda] (optional row gather), converted on the fly.
// B (BMODE=0): bf16 rows [N][ldb], K-contiguous (pre-transposed weights).
// B (BMODE=1): fp32 rows [N][ldb], K-contiguous (activations, "btrans").
// 128x128 tile, 4 waves, BK=32, register-prefetch pipeline.
// Epilogue: alpha, bias, relu, optional transposed store, optional
// scatter-add (out[list[r]] += v * w[list[r]*8]).
#define LDA_S 40   // LDS row stride in bf16 elems (32 + 8 pad)
template<int BMODE>
__global__ __launch_bounds__(256)
void gemm_bf_k(const float* __restrict__ A, int lda,
               const void* __restrict__ Bv, int ldb,
               const float* __restrict__ bias,
               float* __restrict__ C, int ldc,
               int M, int N, int K,
               const int* __restrict__ Mptr, const int* __restrict__ Nptr,
               const int* __restrict__ Kptr,
               const int* __restrict__ gatherA,
               float alpha, int relu, int storeT,
               float* __restrict__ scatterOut,
               const int* __restrict__ scatterList,
               const float* __restrict__ wvec)
{
    if (Mptr) M = *Mptr;
    if (Nptr) N = *Nptr;
    if (Kptr) K = *Kptr;
    int tm = blockIdx.x * 128, tn = blockIdx.y * 128;
    if (tm >= M || tn >= N) return;

    __shared__ __bf16 As[128 * LDA_S];
    __shared__ __bf16 Bs[128 * LDA_S];
    int tid = threadIdx.x, lane = tid & 63, wvi = tid >> 6;
    int wm = (wvi & 1) * 64, wn = (wvi >> 1) * 64;
    f32x4 acc[4][4] = {};

    int ar = tid >> 1, ah = (tid & 1) * 16;   // staging row / k-half
    const float* Aptr = nullptr;
    if (tm + ar < M) {
        int g = gatherA ? gatherA[tm + ar] : (tm + ar);
        Aptr = A + (size_t)g * lda;
    }
    const __bf16* Bb = nullptr;
    const float*  Bf = nullptr;
    if (tn + ar < N) {
        if (BMODE == 0) Bb = (const __bf16*)Bv + (size_t)(tn + ar) * ldb;
        else            Bf = (const float*)Bv + (size_t)(tn + ar) * ldb;
    }

    float fa[16];
    float fb[16];
    bfv8 rb0, rb1;

    auto LOADA = [&](int k0) {
        int kb = k0 + ah;
        if (Aptr) {
            if (kb + 16 <= K) {
                const float4* p = (const float4*)(Aptr + kb);
                float4 x0 = p[0], x1 = p[1], x2 = p[2], x3 = p[3];
                fa[0]=x0.x; fa[1]=x0.y; fa[2]=x0.z; fa[3]=x0.w;
                fa[4]=x1.x; fa[5]=x1.y; fa[6]=x1.z; fa[7]=x1.w;
                fa[8]=x2.x; fa[9]=x2.y; fa[10]=x2.z; fa[11]=x2.w;
                fa[12]=x3.x; fa[13]=x3.y; fa[14]=x3.z; fa[15]=x3.w;
            } else {
#pragma unroll
                for (int i = 0; i < 16; ++i) fa[i] = (kb + i < K) ? Aptr[kb + i] : 0.f;
            }
        } else {
#pragma unroll
            for (int i = 0; i < 16; ++i) fa[i] = 0.f;
        }
    };
    auto LOADB = [&](int k0) {
        int kb = k0 + ah;
        if (BMODE == 0) {
            if (Bb) {
                if (kb + 16 <= K) {
                    rb0 = *(const bfv8*)(Bb + kb);
                    rb1 = *(const bfv8*)(Bb + kb + 8);
                } else {
#pragma unroll
                    for (int i = 0; i < 8; ++i) {
                        rb0[i] = (kb + i < K) ? Bb[kb + i] : (__bf16)0.f;
                        rb1[i] = (kb + 8 + i < K) ? Bb[kb + 8 + i] : (__bf16)0.f;
                    }
                }
            } else {
#pragma unroll
                for (int i = 0; i < 8; ++i) { rb0[i] = (__bf16)0.f; rb1[i] = (__bf16)0.f; }
            }
        } else {
            if (Bf) {
                if (kb + 16 <= K) {
                    const float4* p = (const float4*)(Bf + kb);
                    float4 x0 = p[0], x1 = p[1], x2 = p[2], x3 = p[3];
                    fb[0]=x0.x; fb[1]=x0.y; fb[2]=x0.z; fb[3]=x0.w;
                    fb[4]=x1.x; fb[5]=x1.y; fb[6]=x1.z; fb[7]=x1.w;
                    fb[8]=x2.x; fb[9]=x2.y; fb[10]=x2.z; fb[11]=x2.w;
                    fb[12]=x3.x; fb[13]=x3.y; fb[14]=x3.z; fb[15]=x3.w;
                } else {
#pragma unroll
                    for (int i = 0; i < 16; ++i) fb[i] = (kb + i < K) ? Bf[kb + i] : 0.f;
                }
            } else {
#pragma unroll
                for (int i = 0; i < 16; ++i) fb[i] = 0.f;
            }
        }
    };

    int KT = (K + 31) / 32;
    LOADA(0);
    LOADB(0);

    for (int kt = 0; kt < KT; ++kt) {
        __syncthreads();   // prev iter's frag reads done before overwrite
        {
            bfv8 p0, p1;
#pragma unroll
            for (int i = 0; i < 8; ++i) { p0[i] = (__bf16)fa[i]; p1[i] = (__bf16)fa[8 + i]; }
            *(bfv8*)(As + ar * LDA_S + ah) = p0;
            *(bfv8*)(As + ar * LDA_S + ah + 8) = p1;
        }
        if (BMODE == 0) {
            *(bfv8*)(Bs + ar * LDA_S + ah) = rb0;
            *(bfv8*)(Bs + ar * LDA_S + ah + 8) = rb1;
        } else {
            bfv8 p0, p1;
#pragma unroll
            for (int i = 0; i < 8; ++i) { p0[i] = (__bf16)fb[i]; p1[i] = (__bf16)fb[8 + i]; }
            *(bfv8*)(Bs + ar * LDA_S + ah) = p0;
            *(bfv8*)(Bs + ar * LDA_S + ah + 8) = p1;
        }
        __syncthreads();
        if (kt + 1 < KT) {     // prefetch next tile while MFMA runs
            LOADA((kt + 1) * 32);
            LOADB((kt + 1) * 32);
        }
        {
            int fr = lane & 15, quad = lane >> 4;
            bfv8 af[4], bfr[4];
            const __bf16* Ab = As + quad * 8 + fr * LDA_S;
            const __bf16* Bb2 = Bs + quad * 8 + fr * LDA_S;
#pragma unroll
            for (int t2 = 0; t2 < 4; ++t2) {
                af[t2]  = *(const bfv8*)(Ab + (wm + t2 * 16) * LDA_S);
                bfr[t2] = *(const bfv8*)(Bb2 + (wn + t2 * 16) * LDA_S);
            }
#pragma unroll
            for (int i = 0; i < 4; ++i)
#pragma unroll
                for (int j = 0; j < 4; ++j)
                    acc[i][j] = __builtin_amdgcn_mfma_f32_16x16x32_bf16(af[i], bfr[j], acc[i][j], 0, 0, 0);
        }
    }

    // ---- epilogue: C layout col=lane&15, row=(lane>>4)*4+reg ----
    int col = lane & 15, rq = (lane >> 4) * 4;
#pragma unroll
    for (int ti = 0; ti < 4; ++ti) {
#pragma unroll
        for (int tj = 0; tj < 4; ++tj) {
#pragma unroll
            for (int r = 0; r < 4; ++r) {
                int gm = tm + wm + ti * 16 + rq + r;
                int gn = tn + wn + tj * 16 + col;
                if (gm < M && gn < N) {
                    float v = acc[ti][tj][r] * alpha + (bias ? bias[gn] : 0.f);
                    if (relu) v = fmaxf(v, 0.f);
                    if (scatterOut) {
                        int g = scatterList[gm];
                        scatterOut[(size_t)g * Ec + gn] += v * wvec[(size_t)g * NEc];
                    } else if (storeT) {
                        C[(size_t)gn * ldc + gm] = v;
                    } else {
                        C[(size_t)gm * ldc + gn] = v;
                    }
                }
            }
        }
    }
}

// ---------------------------------------------------------------
// router 3-key attention -> ctx [2048,64]; one wave per token
__global__ __launch_bounds__(256)
void router_ctx_k(const float* __restrict__ q4, const float* __restrict__ rR,
                  const float* __restrict__ rS,
                  const float* __restrict__ Wk, const float* __restrict__ bk,
                  const float* __restrict__ Wv, const float* __restrict__ bv,
                  float* __restrict__ ctx)
{
    int tid = threadIdx.x;
    int lane = tid & 63;
    int n = blockIdx.x * 4 + (tid >> 6);
    int m = (n >> 7) & 3, t = n & 127, b = n >> 9;
    float q = q4[(size_t)n * AKc + lane];
    float sc[3], rv[3], sv[3];
#pragma unroll
    for (int o = 0; o < 3; ++o) {
        int oth = o + (o >= m ? 1 : 0);
        float r = rR[(((size_t)(b * Mc + m)) * Mc + oth) * Tc + t];
        float s_ = rS[(((size_t)(b * Mc + m)) * Mc + oth) * Tc + t];
        rv[o] = r; sv[o] = s_;
        float key = r * Wk[lane] + s_ * Wk[64 + lane] + bk[lane];
        float p = q * key;
#pragma unroll
        for (int off = 32; off; off >>= 1) p += __shfl_xor(p, off, 64);
        sc[o] = p * 0.125f;
    }
    float mx = fmaxf(sc[0], fmaxf(sc[1], sc[2]));
    float e0 = expf(sc[0] - mx), e1 = expf(sc[1] - mx), e2 = expf(sc[2] - mx);
    float inv = 1.f / (e0 + e1 + e2);
    float p0 = e0 * inv, p1 = e1 * inv, p2 = e2 * inv;
    float v0 = rv[0] * Wv[lane] + sv[0] * Wv[64 + lane] + bv[lane];
    float v1 = rv[1] * Wv[lane] + sv[1] * Wv[64 + lane] + bv[lane];
    float v2 = rv[2] * Wv[lane] + sv[2] * Wv[64 + lane] + bv[lane];
    ctx[(size_t)n * AVc + lane] = p0 * v0 + p1 * v1 + p2 * v2;
}

// ---------------------------------------------------------------
__global__ __launch_bounds__(256)
void gi_k(const float* __restrict__ rU, const float* __restrict__ ctx,
          const float* __restrict__ gWih, const float* __restrict__ gbih,
          float* __restrict__ gi)
{
    int idx = blockIdx.x * 256 + threadIdx.x;   // < 2048*384
    int g = idx % 384, nt = idx / 384;
    const float* Wr = gWih + (size_t)g * 65;
    float a = gbih[g] + rU[nt] * Wr[0];
    const float* c = ctx + (size_t)nt * AVc;
#pragma unroll
    for (int d = 0; d < 64; ++d) a += c[d] * Wr[1 + d];
    gi[(size_t)nt * 384 + g] = a;
}

// ---------------------------------------------------------------
// GRU scan: one block per sequence (16), 384 threads; gWhh row in VGPRs.
__global__ __launch_bounds__(384)
void gru_scan_k(const float* __restrict__ gi, const float* __restrict__ gWhh,
                const float* __restrict__ gbhh, float* __restrict__ hs)
{
    int seq = blockIdx.x, g = threadIdx.x;
    __shared__ float h[128];
    __shared__ float gh[384];
    float w[128];
    const float4* wr = (const float4*)(gWhh + (size_t)g * 128);
#pragma unroll
    for (int i = 0; i < 32; ++i) {
        float4 t = wr[i];
        w[4*i] = t.x; w[4*i+1] = t.y; w[4*i+2] = t.z; w[4*i+3] = t.w;
    }
    float bh = gbhh[g];
    if (g < 128) h[g] = 0.f;
    __syncthreads();
    for (int t = 0; t < 128; ++t) {
        const float* gr = gi + ((size_t)seq * 128 + t) * 384;
        float g0 = 0.f, g1 = 0.f, g2 = 0.f;
        if (g < 128) { g0 = gr[g]; g1 = gr[128 + g]; g2 = gr[256 + g]; }
        float a0 = 0.f, a1 = 0.f, a2 = 0.f, a3 = 0.f;
#pragma unroll
        for (int d = 0; d < 128; d += 4) {
            float4 h4 = *(const float4*)(&h[d]);
            a0 += h4.x * w[d];     a1 += h4.y * w[d + 1];
            a2 += h4.z * w[d + 2]; a3 += h4.w * w[d + 3];
        }
        gh[g] = bh + (a0 + a1) + (a2 + a3);
        __syncthreads();
        if (g < 128) {
            float r = 1.f / (1.f + expf(-(g0 + gh[g])));
            float z = 1.f / (1.f + expf(-(g1 + gh[128 + g])));
            float nn = tanhf(g2 + r * gh[256 + g]);
            float hn = (1.f - z) * nn + z * h[g];
            hs[((size_t)seq * 128 + t) * 128 + g] = hn;
            h[g] = hn;
        }
        __syncthreads();
    }
}

// ---------------------------------------------------------------
__global__ __launch_bounds__(128)
void mlp_route_k(const float* __restrict__ proc, const float* __restrict__ hs,
                 const float* __restrict__ mW1, const float* __restrict__ mb1,
                 const float* __restrict__ mW2, const float* __restrict__ mb2,
                 float* __restrict__ probsOut, float* __restrict__ idxOut,
                 float* __restrict__ w)
{
    int n = blockIdx.x, tid = threadIdx.x;
    __shared__ float comb[256], tmp[128], lg[8];
    comb[tid] = proc[(size_t)n * 128 + tid];
    comb[128 + tid] = hs[(size_t)n * 128 + tid];
    __syncthreads();
    float a = mb1[tid];
#pragma unroll 8
    for (int d = 0; d < 256; ++d) a += comb[d] * mW1[(size_t)d * 128 + tid];
    tmp[tid] = fmaxf(a, 0.f);
    __syncthreads();
    if (tid < 8) {
        float l = mb2[tid];
        for (int d = 0; d < 128; ++d) l += tmp[d] * mW2[(size_t)d * 8 + tid];
        lg[tid] = l;
    }
    __syncthreads();
    if (tid == 0) {
        float mx = lg[0];
        for (int e = 1; e < 8; ++e) mx = fmaxf(mx, lg[e]);
        float p[8], s = 0.f;
        for (int e = 0; e < 8; ++e) { p[e] = expf(lg[e] - mx); s += p[e]; }
        float inv = 1.f / s;
        for (int e = 0; e < 8; ++e) probsOut[(size_t)n * 8 + e] = p[e] * inv;
        int a0 = 0; float v0 = lg[0];
        for (int e = 1; e < 8; ++e) if (lg[e] > v0) { v0 = lg[e]; a0 = e; }
        int a1 = -1; float v1 = -1e30f;
        for (int e = 0; e < 8; ++e) if (e != a0 && lg[e] > v1) { v1 = lg[e]; a1 = e; }
        float e1 = expf(v1 - v0);
        float t0 = 1.f / (1.f + e1), t1 = e1 / (1.f + e1);
        idxOut[(size_t)n * 2 + 0] = (float)a0;
        idxOut[(size_t)n * 2 + 1] = (float)a1;
        for (int e = 0; e < 8; ++e) w[(size_t)n * 8 + e] = 0.f;
        w[(size_t)n * 8 + a0] = t0;
        w[(size_t)n * 8 + a1] = t1;
    }
}

__global__ __launch_bounds__(256)
void compact_k(const float* __restrict__ w, int* __restrict__ cnt,
               int* __restrict__ list)
{
    int n = blockIdx.x * 256 + threadIdx.x;
    if (n >= NTc) return;
    for (int e = 0; e < NEc; ++e)
        if (w[(size_t)n * 8 + e] > 0.f) {
            int p = atomicAdd(&cnt[e], 1);
            list[e * NTc + p] = n;
        }
}

// ---------------------------------------------------------------
__global__ __launch_bounds__(256)
void softmax_rows_k(float* __restrict__ S, const int* __restrict__ cntPtr)
{
    int nv = *cntPtr;
    int i = blockIdx.x;
    if (i >= nv) return;
    float* row = S + (size_t)i * NTc;
    int tid = threadIdx.x;
    __shared__ float red[256];
    float mx = -1e30f;
    for (int j = tid; j < nv; j += 256) mx = fmaxf(mx, row[j]);
    red[tid] = mx; __syncthreads();
    for (int st = 128; st > 0; st >>= 1) { if (tid < st) red[tid] = fmaxf(red[tid], red[tid + st]); __syncthreads(); }
    mx = red[0]; __syncthreads();
    float sum = 0.f;
    for (int j = tid; j < nv; j += 256) { float e = expf(row[j] - mx); row[j] = e; sum += e; }
    red[tid] = sum; __syncthreads();
    for (int st = 128; st > 0; st >>= 1) { if (tid < st) red[tid] += red[tid + st]; __syncthreads(); }
    float inv = 1.f / red[0];
    for (int j = tid; j < nv; j += 256) row[j] *= inv;
}

__global__ __launch_bounds__(256)
void ln1_k(const float* __restrict__ x, const int* __restrict__ list,
           const float* __restrict__ add, const float* __restrict__ s,
           const float* __restrict__ b, float* __restrict__ outRows,
           const int* __restrict__ cntPtr)
{
    int i = blockIdx.x;
    if (i >= *cntPtr) return;
    int tid = threadIdx.x;
    int g = list[i];
    float v0 = x[(size_t)g * Ec + tid] + add[(size_t)i * Ec + tid];
    float v1 = x[(size_t)g * Ec + 256 + tid] + add[(size_t)i * Ec + 256 + tid];
    __shared__ float red[256];
    __shared__ float bc;
    red[tid] = v0 + v1; __syncthreads();
    for (int st = 128; st > 0; st >>= 1) { if (tid < st) red[tid] += red[tid + st]; __syncthreads(); }
    if (tid == 0) bc = red[0] * (1.f / 512.f);
    __syncthreads();
    float mu = bc;
    float d0 = v0 - mu, d1 = v1 - mu;
    __syncthreads();
    red[tid] = d0 * d0 + d1 * d1; __syncthreads();
    for (int st = 128; st > 0; st >>= 1) { if (tid < st) red[tid] += red[tid + st]; __syncthreads(); }
    if (tid == 0) bc = rsqrtf(red[0] * (1.f / 512.f) + 1e-5f);
    __syncthreads();
    float inv = bc;
    outRows[(size_t)i * Ec + tid] = d0 * inv * s[tid] + b[tid];
    outRows[(size_t)i * Ec + 256 + tid] = d1 * inv * s[256 + tid] + b[256 + tid];
}

__global__ __launch_bounds__(256)
void ln2_scatter_k(const float* __restrict__ H1, const float* __restrict__ Y,
                   const float* __restrict__ s, const float* __restrict__ b,
                   float* __restrict__ out, const int* __restrict__ list,
                   const int* __restrict__ cntPtr, const float* __restrict__ wvec)
{
    int i = blockIdx.x;
    if (i >= *cntPtr) return;
    int tid = threadIdx.x;
    int g = list[i];
    float v0 = H1[(size_t)i * Ec + tid] + Y[(size_t)i * Ec + tid];
    float v1 = H1[(size_t)i * Ec + 256 + tid] + Y[(size_t)i * Ec + 256 + tid];
    __shared__ float red[256];
    __shared__ float bc;
    red[tid] = v0 + v1; __syncthreads();
    for (int st = 128; st > 0; st >>= 1) { if (tid < st) red[tid] += red[tid + st]; __syncthreads(); }
    if (tid == 0) bc = red[0] * (1.f / 512.f);
    __syncthreads();
    float mu = bc;
    float d0 = v0 - mu, d1 = v1 - mu;
    __syncthreads();
    red[tid] = d0 * d0 + d1 * d1; __syncthreads();
    for (int st = 128; st > 0; st >>= 1) { if (tid < st) red[tid] += red[tid + st]; __syncthreads(); }
    if (tid == 0) bc = rsqrtf(red[0] * (1.f / 512.f) + 1e-5f);
    __syncthreads();
    float inv = bc;
    float wv = wvec[(size_t)g * 8];
    out[(size_t)g * Ec + tid] += (d0 * inv * s[tid] + b[tid]) * wv;
    out[(size_t)g * Ec + 256 + tid] += (d1 * inv * s[256 + tid] + b[256 + tid]) * wv;
}

// ---------------------------------------------------------------
// launch helpers
static inline void gemm_w(hipStream_t st, int gx, int gy,          // B = bf16 weights [N][K]
                          const float* A, int lda, const __bf16* Bt, int ldb,
                          const float* bias, float* C, int ldc,
                          int M, int N, int K,
                          const int* Mptr, const int* Kptr,
                          const int* gatherA, int relu, int storeT,
                          float* scOut, const int* scList, const float* wv)
{
    gemm_bf_k<0><<<dim3(gx, gy), 256, 0, st>>>(A, lda, (const void*)Bt, ldb, bias, C, ldc,
                                               M, N, K, Mptr, nullptr, Kptr, gatherA,
                                               1.f, relu, storeT, scOut, scList, wv);
}
static inline void gemm_a(hipStream_t st, int gx, int gy,          // B = fp32 rows [N][ldb]
                          const float* A, int lda, const float* Bt, int ldb,
                          float* C, int ldc,
                          int M, int N, int K,
                          const int* Mptr, const int* Nptr, const int* Kptr,
                          float alpha)
{
    gemm_bf_k<1><<<dim3(gx, gy), 256, 0, st>>>(A, lda, (const void*)Bt, ldb, nullptr, C, ldc,
                                               M, N, K, Mptr, Nptr, Kptr, nullptr,
                                               alpha, 0, 0, nullptr, nullptr, nullptr);
}

extern "C" void kernel_launch(void* const* d_in, const int* in_sizes, int n_in,
                              void* d_out, int out_size, void* d_ws, size_t ws_size,
                              hipStream_t stream)
{
    const float* x    = (const float*)d_in[0];
    const float* rU   = (const float*)d_in[1];
    const float* rR   = (const float*)d_in[2];
    const float* rS   = (const float*)d_in[3];
    const float* Wtp  = (const float*)d_in[6];
    const float* btp  = (const float*)d_in[7];
    const float* Wq   = (const float*)d_in[8];
    const float* bq   = (const float*)d_in[9];
    const float* Wk   = (const float*)d_in[10];
    const float* bk   = (const float*)d_in[11];
    const float* Wv   = (const float*)d_in[12];
    const float* bv   = (const float*)d_in[13];
    const float* gWih = (const float*)d_in[14];
    const float* gbih = (const float*)d_in[15];
    const float* gWhh = (const float*)d_in[16];
    const float* gbhh = (const float*)d_in[17];
    const float* mW1  = (const float*)d_in[18];
    const float* mb1  = (const float*)d_in[19];
    const float* mW2  = (const float*)d_in[20];
    const float* mb2  = (const float*)d_in[21];
    const float* sWq  = (const float*)d_in[22];
    const float* sbq  = (const float*)d_in[23];
    const float* sWk  = (const float*)d_in[24];
    const float* sbk  = (const float*)d_in[25];
    const float* sWv  = (const float*)d_in[26];
    const float* sbv  = (const float*)d_in[27];
    const float* sWo  = (const float*)d_in[28];
    const float* sbo  = (const float*)d_in[29];
    const float* sln1s = (const float*)d_in[30];
    const float* sln1b = (const float*)d_in[31];
    const float* sW1  = (const float*)d_in[32];
    const float* sb1  = (const float*)d_in[33];
    const float* sW2  = (const float*)d_in[34];
    const float* sb2  = (const float*)d_in[35];
    const float* sln2s = (const float*)d_in[36];
    const float* sln2b = (const float*)d_in[37];
    const float* fW1  = (const float*)d_in[38];
    const float* fb1  = (const float*)d_in[39];
    const float* fW2  = (const float*)d_in[40];
    const float* fb2  = (const float*)d_in[41];

    float* out      = (float*)d_out;                 // [2048,512]
    float* probsOut = out + (size_t)NTc * Ec;        // [2048,8]
    float* idxOut   = probsOut + (size_t)NTc * NEc;  // [2048,2]

    // ---- workspace layout (floats unless noted) ----
    int*   cnt  = (int*)d_ws;                        // 64
    int*   list = cnt + 64;                          // 8*2048
    float* w    = (float*)d_ws + 64 + NEc * NTc;     // [2048,8]
    // rotating bf16 weight region (per-expert): QKVO 4*262144 + W1T 1M + W2T 1M
    __bf16* WB   = (__bf16*)(w + NTc * NEc);
    __bf16* WqT  = WB;                     // [512][512]
    __bf16* WkT  = WB + 262144;
    __bf16* WvT  = WB + 2 * 262144;
    __bf16* WoT  = WB + 3 * 262144;
    __bf16* W1T  = WB + 4 * 262144;        // [2048][512]
    __bf16* W2T  = W1T + 1048576;          // [512][2048]
    float* B0 = (float*)(W2T + 1048576);
    // router region (dead before experts start)
    float* proc = B0;                  // 2048*128
    float* q4   = proc + 262144;       // 2048*64
    float* ctx  = q4 + 131072;         // 2048*64
    float* gi   = ctx + 131072;        // 16*128*384
    float* hs   = gi + 786432;         // 2048*128
    // expert region (overlays router region)
    float* S   = B0;                   // 2048*2048
    float* Qb  = S + 4194304;          // 2048*512
    float* Kb  = Qb + 1048576;
    float* Vt  = Kb + 1048576;         // transposed V: [512][2048]
    float* AO  = Vt + 1048576;
    float* PRJ = AO + 1048576;
    float* H1  = PRJ + 1048576;
    float* Yb  = H1 + 1048576;
    float* FF1 = Yb + 1048576;         // 2048*2048

    const float invsq = 0.08838834764831845f;  // 1/sqrt(128)

    // ---- init ----
    zero_k<<<1024, 256, 0, stream>>>(out, cnt);

    // ---- router (fp32 — keeps top-2 idx bit-stable) ----
    gemm_k<<<dim3(32, 2), 256, 0, stream>>>(x, Ec, Wtp, Pc, btp, proc, Pc, NTc, Pc, Ec, 1);
    gemm_k<<<dim3(32, 1), 256, 0, stream>>>(proc, Pc, Wq, AKc, bq, q4, AKc, NTc, AKc, Pc, 0);
    router_ctx_k<<<512, 256, 0, stream>>>(q4, rR, rS, Wk, bk, Wv, bv, ctx);
    gi_k<<<3072, 256, 0, stream>>>(rU, ctx, gWih, gbih, gi);
    gru_scan_k<<<16, 384, 0, stream>>>(gi, gWhh, gbhh, hs);
    mlp_route_k<<<2048, 128, 0, stream>>>(proc, hs, mW1, mb1, mW2, mb2,
                                          probsOut, idxOut, w);
    compact_k<<<8, 256, 0, stream>>>(w, cnt, list);

    // ---- synergy experts ----
    for (int e = 0; e < NSc; ++e) {
        const int* cl = list + e * NTc;
        const int* ce = cnt + e;
        // weight conversion (transpose to [N][K] bf16)
        convT_k<<<dim3(16, 16), 256, 0, stream>>>(sWq + (size_t)e * Ec * Ec, WqT, Ec, Ec);
        convT_k<<<dim3(16, 16), 256, 0, stream>>>(sWk + (size_t)e * Ec * Ec, WkT, Ec, Ec);
        convT_k<<<dim3(16, 16), 256, 0, stream>>>(sWv + (size_t)e * Ec * Ec, WvT, Ec, Ec);
        convT_k<<<dim3(16, 16), 256, 0, stream>>>(sWo + (size_t)e * Ec * Ec, WoT, Ec, Ec);
        convT_k<<<dim3(64, 16), 256, 0, stream>>>(sW1 + (size_t)e * Ec * Hc, W1T, Ec, Hc);
        convT_k<<<dim3(16, 64), 256, 0, stream>>>(sW2 + (size_t)e * Hc * Ec, W2T, Hc, Ec);

        gemm_w(stream, 16, 4, x, Ec, WqT, Ec, sbq + e * Ec, Qb, Ec,
               NTc, Ec, Ec, ce, nullptr, cl, 0, 0, nullptr, nullptr, nullptr);
        gemm_w(stream, 16, 4, x, Ec, WkT, Ec, sbk + e * Ec, Kb, Ec,
               NTc, Ec, Ec, ce, nullptr, cl, 0, 0, nullptr, nullptr, nullptr);
        gemm_w(stream, 16, 4, x, Ec, WvT, Ec, sbv + e * Ec, Vt, NTc,     // transposed store
               NTc, Ec, Ec, ce, nullptr, cl, 0, 1, nullptr, nullptr, nullptr);
        for (int h = 0; h < NHEADc; ++h) {
            gemm_a(stream, 16, 16, Qb + h * HDc, Ec, Kb + h * HDc, Ec, S, NTc,
                   NTc, NTc, HDc, ce, ce, nullptr, invsq);
            softmax_rows_k<<<2048, 256, 0, stream>>>(S, ce);
            gemm_a(stream, 16, 1, S, NTc, Vt + (size_t)h * HDc * NTc, NTc, AO + h * HDc, Ec,
                   NTc, HDc, NTc, ce, nullptr, ce, 1.f);
        }
        gemm_w(stream, 16, 4, AO, Ec, WoT, Ec, sbo + e * Ec, PRJ, Ec,
               NTc, Ec, Ec, ce, nullptr, nullptr, 0, 0, nullptr, nullptr, nullptr);
        ln1_k<<<2048, 256, 0, stream>>>(x, cl, PRJ, sln1s + e * Ec, sln1b + e * Ec, H1, ce);
        gemm_w(stream, 16, 16, H1, Ec, W1T, Ec, sb1 + e * Hc, FF1, Hc,
               NTc, Hc, Ec, ce, nullptr, nullptr, 1, 0, nullptr, nullptr, nullptr);
        gemm_w(stream, 16, 4, FF1, Hc, W2T, Hc, sb2 + e * Ec, Yb, Ec,
               NTc, Ec, Hc, ce, nullptr, nullptr, 0, 0, nullptr, nullptr, nullptr);
        ln2_scatter_k<<<2048, 256, 0, stream>>>(H1, Yb, sln2s + e * Ec, sln2b + e * Ec,
                                                out, cl, ce, w + e);
    }

    // ---- FFN experts ----
    for (int f = 0; f < NEc - NSc; ++f) {
        int e = f + NSc;
        const int* cl = list + e * NTc;
        const int* ce = cnt + e;
        convT_k<<<dim3(64, 16), 256, 0, stream>>>(fW1 + (size_t)f * Ec * Hc, W1T, Ec, Hc);
        convT_k<<<dim3(16, 64), 256, 0, stream>>>(fW2 + (size_t)f * Hc * Ec, W2T, Hc, Ec);
        gemm_w(stream, 16, 16, x, Ec, W1T, Ec, fb1 + f * Hc, FF1, Hc,
               NTc, Hc, Ec, ce, nullptr, cl, 1, 0, nullptr, nullptr, nullptr);
        gemm_w(stream, 16, 4, FF1, Hc, W2T, Hc, fb2 + f * Ec, nullptr, Ec,
               NTc, Ec, Hc, ce, nullptr, nullptr, 0, 0, out, cl, w + e);
    }
}

// Round 4
// 1191.848 us; speedup vs baseline: 5.3846x; 1.8186x over previous
//
#include <hip/hip_runtime.h>
#include <math.h>

// ---------- constants ----------
#define Bc 4
#define Mc 4
#define Tc 128
#define Ec 512
#define Hc 2048
#define NEc 8
#define NSc 2
#define NHEADc 4
#define Pc 128
#define GRUHc 128
#define AKc 64
#define AVc 64
#define NTc 2048        // B*S
#define HDc 128         // E/NHEAD

typedef __bf16 bfv8 __attribute__((ext_vector_type(8)));
typedef float f32x4 __attribute__((ext_vector_type(4)));

// ---------------------------------------------------------------
__global__ __launch_bounds__(256)
void zero_k(float* __restrict__ out, int* __restrict__ cnt)
{
    int i = blockIdx.x * 256 + threadIdx.x;
    float4* o4 = (float4*)out;
    if (i < (NTc * Ec) / 4) o4[i] = make_float4(0.f, 0.f, 0.f, 0.f);
    if (i < NEc) cnt[i] = 0;
}

// ---------------------------------------------------------------
// batched tiled transpose + fp32->bf16 convert: W[K,N] -> Wt[N,K]
struct CJob { const float* src; __bf16* dst; };

__global__ __launch_bounds__(256)
void convT_k(CJob j0, CJob j1, CJob j2, CJob j3, int K, int N)
{
    CJob J = j0;
    if (blockIdx.z == 1) J = j1;
    else if (blockIdx.z == 2) J = j2;
    else if (blockIdx.z == 3) J = j3;
    __shared__ float t[32][33];
    int bx = blockIdx.x * 32;   // n tile
    int by = blockIdx.y * 32;   // k tile
    int tx = threadIdx.x & 31, ty = threadIdx.x >> 5;   // 32 x 8
#pragma unroll
    for (int i = 0; i < 4; ++i) {
        int k = by + ty + i * 8, n = bx + tx;
        t[ty + i * 8][tx] = (k < K && n < N) ? J.src[(size_t)k * N + n] : 0.f;
    }
    __syncthreads();
#pragma unroll
    for (int i = 0; i < 4; ++i) {
        int n = bx + ty + i * 8, k = by + tx;
        if (n < N && k < K) J.dst[(size_t)n * K + k] = (__bf16)t[tx][ty + i * 8];
    }
}

// ---------------------------------------------------------------
// fp32 tiled GEMM (router only — keeps top-2 routing bit-stable)
__global__ __launch_bounds__(256)
void gemm_k(const float* __restrict__ A, int lda,
            const float* __restrict__ B, int ldb,
            const float* __restrict__ bias,
            float* __restrict__ C, int ldc,
            int M, int N, int K, int relu)
{
    int tm = blockIdx.x * 64, tn = blockIdx.y * 64;
    if (tm >= M || tn >= N) return;
    __shared__ float As[16][68];
    __shared__ float Bs[16][68];
    int tid = threadIdx.x;
    int tx = tid & 15, ty = tid >> 4;
    float acc[4][4] = {};
    int arow = tid >> 2;
    int ak0  = (tid & 3) * 4;
    int bk   = tid >> 4;
    int bc0  = (tid & 15) * 4;
    int grA = tm + arow;
    const float* Arow = (grA < M) ? (A + (size_t)grA * lda) : nullptr;

    for (int k0 = 0; k0 < K; k0 += 16) {
#pragma unroll
        for (int u = 0; u < 4; ++u) {
            int k = k0 + ak0 + u;
            As[ak0 + u][arow] = (Arow && k < K) ? Arow[k] : 0.f;
        }
        int kb = k0 + bk;
#pragma unroll
        for (int u = 0; u < 4; ++u) {
            int n2 = tn + bc0 + u;
            Bs[bk][bc0 + u] = (kb < K && n2 < N) ? B[(size_t)kb * ldb + n2] : 0.f;
        }
        __syncthreads();
#pragma unroll
        for (int kk = 0; kk < 16; ++kk) {
            float a0 = As[kk][ty * 4 + 0], a1 = As[kk][ty * 4 + 1];
            float a2 = As[kk][ty * 4 + 2], a3 = As[kk][ty * 4 + 3];
            float b0 = Bs[kk][tx * 4 + 0], b1 = Bs[kk][tx * 4 + 1];
            float b2 = Bs[kk][tx * 4 + 2], b3 = Bs[kk][tx * 4 + 3];
            acc[0][0] += a0 * b0; acc[0][1] += a0 * b1; acc[0][2] += a0 * b2; acc[0][3] += a0 * b3;
            acc[1][0] += a1 * b0; acc[1][1] += a1 * b1; acc[1][2] += a1 * b2; acc[1][3] += a1 * b3;
            acc[2][0] += a2 * b0; acc[2][1] += a2 * b1; acc[2][2] += a2 * b2; acc[2][3] += a2 * b3;
            acc[3][0] += a3 * b0; acc[3][1] += a3 * b1; acc[3][2] += a3 * b2; acc[3][3] += a3 * b3;
        }
        __syncthreads();
    }
#pragma unroll
    for (int i = 0; i < 4; ++i) {
        int gr = tm + ty * 4 + i;
        if (gr >= M) continue;
#pragma unroll
        for (int j = 0; j < 4; ++j) {
            int gc = tn + tx * 4 + j;
            if (gc >= N) continue;
            float v = acc[i][j] + (bias ? bias[gc] : 0.f);
            if (relu) v = fmaxf(v, 0.f);
            C[(size_t)gr * ldc + gc] = v;
        }
    }
}

// ---------------------------------------------------------------
// batched bf16 MFMA GEMM. A: fp32 (AMODE=0) or bf16 (AMODE=1) rows,
// optional row gather. B: bf16 [N][K] K-contiguous. 128x128 tile, 4 waves,
// BK=32, register-prefetch pipeline. K % 32 == 0 assumed (512/2048).
// flags: 1=relu, 2=storeT (fp32 C[gn*ldc+gm]), 4=storeBf (bf16 C).
struct GJob {
    const void* A;
    const void* B;
    const float* bias;
    void* C;
    const int* Mptr;
    const int* gatherA;
    float* scatterOut;
    const int* scatterList;
    const float* wvec;
    int ldc;
    int flags;
};

#define LDA_S 40   // LDS row stride in bf16 elems (32 + 8 pad)
template<int AMODE>
__global__ __launch_bounds__(256)
void gemm_batch_k(GJob ja, GJob jb, GJob jc, int lda, int ldb, int N, int K)
{
    GJob J = ja;
    if (blockIdx.z == 1) J = jb;
    else if (blockIdx.z == 2) J = jc;
    int M = *J.Mptr;
    int tm = blockIdx.x * 128, tn = blockIdx.y * 128;
    if (tm >= M || tn >= N) return;

    __shared__ __bf16 As[128 * LDA_S];
    __shared__ __bf16 Bs[128 * LDA_S];
    int tid = threadIdx.x, lane = tid & 63, wvi = tid >> 6;
    int wm = (wvi & 1) * 64, wn = (wvi >> 1) * 64;
    f32x4 acc[4][4] = {};

    int ar = tid >> 1, ah = (tid & 1) * 16;   // staging row / k-half
    const float*  Apf = nullptr;
    const __bf16* Apb = nullptr;
    if (tm + ar < M) {
        int g = J.gatherA ? J.gatherA[tm + ar] : (tm + ar);
        if (AMODE == 0) Apf = (const float*)J.A + (size_t)g * lda;
        else            Apb = (const __bf16*)J.A + (size_t)g * lda;
    }
    const __bf16* Bp = ((tn + ar) < N) ? ((const __bf16*)J.B + (size_t)(tn + ar) * ldb)
                                       : nullptr;

    float fa[16];
    bfv8 ra0, ra1, rb0, rb1;

    auto LOADA = [&](int k0) {
        int kb = k0 + ah;
        if (AMODE == 0) {
            if (Apf) {
                const float4* p = (const float4*)(Apf + kb);
                float4 x0 = p[0], x1 = p[1], x2 = p[2], x3 = p[3];
                fa[0]=x0.x; fa[1]=x0.y; fa[2]=x0.z; fa[3]=x0.w;
                fa[4]=x1.x; fa[5]=x1.y; fa[6]=x1.z; fa[7]=x1.w;
                fa[8]=x2.x; fa[9]=x2.y; fa[10]=x2.z; fa[11]=x2.w;
                fa[12]=x3.x; fa[13]=x3.y; fa[14]=x3.z; fa[15]=x3.w;
            } else {
#pragma unroll
                for (int i = 0; i < 16; ++i) fa[i] = 0.f;
            }
        } else {
            if (Apb) {
                ra0 = *(const bfv8*)(Apb + kb);
                ra1 = *(const bfv8*)(Apb + kb + 8);
            } else {
#pragma unroll
                for (int i = 0; i < 8; ++i) { ra0[i] = (__bf16)0.f; ra1[i] = (__bf16)0.f; }
            }
        }
    };
    auto LOADB = [&](int k0) {
        int kb = k0 + ah;
        if (Bp) {
            rb0 = *(const bfv8*)(Bp + kb);
            rb1 = *(const bfv8*)(Bp + kb + 8);
        } else {
#pragma unroll
            for (int i = 0; i < 8; ++i) { rb0[i] = (__bf16)0.f; rb1[i] = (__bf16)0.f; }
        }
    };

    int KT = K / 32;
    LOADA(0);
    LOADB(0);

    for (int kt = 0; kt < KT; ++kt) {
        __syncthreads();
        if (AMODE == 0) {
            bfv8 p0, p1;
#pragma unroll
            for (int i = 0; i < 8; ++i) { p0[i] = (__bf16)fa[i]; p1[i] = (__bf16)fa[8 + i]; }
            *(bfv8*)(As + ar * LDA_S + ah) = p0;
            *(bfv8*)(As + ar * LDA_S + ah + 8) = p1;
        } else {
            *(bfv8*)(As + ar * LDA_S + ah) = ra0;
            *(bfv8*)(As + ar * LDA_S + ah + 8) = ra1;
        }
        *(bfv8*)(Bs + ar * LDA_S + ah) = rb0;
        *(bfv8*)(Bs + ar * LDA_S + ah + 8) = rb1;
        __syncthreads();
        if (kt + 1 < KT) {
            LOADA((kt + 1) * 32);
            LOADB((kt + 1) * 32);
        }
        {
            int fr = lane & 15, quad = lane >> 4;
            bfv8 af[4], bfr[4];
            const __bf16* Ab = As + quad * 8 + fr * LDA_S;
            const __bf16* Bb2 = Bs + quad * 8 + fr * LDA_S;
#pragma unroll
            for (int t2 = 0; t2 < 4; ++t2) {
                af[t2]  = *(const bfv8*)(Ab + (wm + t2 * 16) * LDA_S);
                bfr[t2] = *(const bfv8*)(Bb2 + (wn + t2 * 16) * LDA_S);
            }
#pragma unroll
            for (int i = 0; i < 4; ++i)
#pragma unroll
                for (int j = 0; j < 4; ++j)
                    acc[i][j] = __builtin_amdgcn_mfma_f32_16x16x32_bf16(af[i], bfr[j], acc[i][j], 0, 0, 0);
        }
    }

    // epilogue: C layout col=lane&15, row=(lane>>4)*4+reg
    int col = lane & 15, rq = (lane >> 4) * 4;
    int relu = J.flags & 1, storeT = J.flags & 2, storeBf = J.flags & 4;
#pragma unroll
    for (int ti = 0; ti < 4; ++ti) {
#pragma unroll
        for (int tj = 0; tj < 4; ++tj) {
#pragma unroll
            for (int r = 0; r < 4; ++r) {
                int gm = tm + wm + ti * 16 + rq + r;
                int gn = tn + wn + tj * 16 + col;
                if (gm < M && gn < N) {
                    float v = acc[ti][tj][r] + (J.bias ? J.bias[gn] : 0.f);
                    if (relu) v = fmaxf(v, 0.f);
                    if (J.scatterOut) {
                        int g = J.scatterList[gm];
                        atomicAdd(&J.scatterOut[(size_t)g * Ec + gn], v * J.wvec[(size_t)g * NEc]);
                    } else if (storeT) {
                        ((float*)J.C)[(size_t)gn * J.ldc + gm] = v;
                    } else if (storeBf) {
                        ((__bf16*)J.C)[(size_t)gm * J.ldc + gn] = (__bf16)v;
                    } else {
                        ((float*)J.C)[(size_t)gm * J.ldc + gn] = v;
                    }
                }
            }
        }
    }
}

// ---------------------------------------------------------------
// Flash attention over compacted tokens. One block = (64-row tile, head).
// Q,K: fp32 [2048][512] compacted rows. Vt: fp32 [512][2048] (d-major).
// AO out: fp32 [2048][512]. Online softmax, bf16 MFMA, fp32 accum.
__global__ __launch_bounds__(256)
void flash_k(const float* __restrict__ Qb, const float* __restrict__ Kb,
             const float* __restrict__ Vt, float* __restrict__ AO,
             const int* __restrict__ cntPtr)
{
    int nv = *cntPtr;
    int r0 = blockIdx.x * 64;
    if (r0 >= nv) return;
    int h = blockIdx.y;
    const int QS = 136, VS = 72;
    __shared__ __bf16 Ql[64 * 136];
    __shared__ __bf16 Kl[64 * 136];
    __shared__ __bf16 Vl[128 * 72];
    __shared__ __bf16 Pl[64 * 72];
    int tid = threadIdx.x, lane = tid & 63, wv = tid >> 6;
    int fr = lane & 15, quad = lane >> 4;

    {   // load Q tile (rows >= nv -> 0)
        int qr = tid >> 2, c0 = (tid & 3) * 32;
        const float* src = Qb + (size_t)(r0 + qr) * Ec + h * HDc + c0;
        __bf16* dst = Ql + qr * QS + c0;
        bool ok = (r0 + qr) < nv;
#pragma unroll
        for (int u = 0; u < 8; ++u) {
            float4 v = ok ? ((const float4*)src)[u] : make_float4(0.f, 0.f, 0.f, 0.f);
            dst[u*4+0] = (__bf16)v.x; dst[u*4+1] = (__bf16)v.y;
            dst[u*4+2] = (__bf16)v.z; dst[u*4+3] = (__bf16)v.w;
        }
    }

    f32x4 accO[8];
#pragma unroll
    for (int j = 0; j < 8; ++j) accO[j] = (f32x4){0.f, 0.f, 0.f, 0.f};
    float mrow[4] = {-1e30f, -1e30f, -1e30f, -1e30f};
    float lrow[4] = {0.f, 0.f, 0.f, 0.f};
    const float invsq = 0.08838834764831845f;   // 1/sqrt(128)

    for (int j0 = 0; j0 < nv; j0 += 64) {
        __syncthreads();
        {   // K tile
            int kr = tid >> 2, c0 = (tid & 3) * 32;
            const float* src = Kb + (size_t)(j0 + kr) * Ec + h * HDc + c0;
            __bf16* dst = Kl + kr * QS + c0;
            bool ok = (j0 + kr) < nv;
#pragma unroll
            for (int u = 0; u < 8; ++u) {
                float4 v = ok ? ((const float4*)src)[u] : make_float4(0.f, 0.f, 0.f, 0.f);
                dst[u*4+0] = (__bf16)v.x; dst[u*4+1] = (__bf16)v.y;
                dst[u*4+2] = (__bf16)v.z; dst[u*4+3] = (__bf16)v.w;
            }
        }
        {   // Vt tile (d-major)
            int dr = tid >> 1, c0 = (tid & 1) * 32;
            const float* src = Vt + (size_t)(h * HDc + dr) * NTc + j0 + c0;
            __bf16* dst = Vl + dr * VS + c0;
            int rem = nv - (j0 + c0);
            if (rem >= 32) {
#pragma unroll
                for (int u = 0; u < 8; ++u) {
                    float4 v = ((const float4*)src)[u];
                    dst[u*4+0] = (__bf16)v.x; dst[u*4+1] = (__bf16)v.y;
                    dst[u*4+2] = (__bf16)v.z; dst[u*4+3] = (__bf16)v.w;
                }
            } else {
                for (int u = 0; u < 32; ++u)
                    dst[u] = (u < rem) ? (__bf16)src[u] : (__bf16)0.f;
            }
        }
        __syncthreads();

        // S = Q K^T (wave owns rows wv*16..+16)
        f32x4 sc[4] = {};
#pragma unroll
        for (int ks = 0; ks < 4; ++ks) {
            bfv8 aq = *(const bfv8*)(Ql + (wv * 16 + fr) * QS + ks * 32 + quad * 8);
#pragma unroll
            for (int tj = 0; tj < 4; ++tj) {
                bfv8 bk8 = *(const bfv8*)(Kl + (tj * 16 + fr) * QS + ks * 32 + quad * 8);
                sc[tj] = __builtin_amdgcn_mfma_f32_16x16x32_bf16(aq, bk8, sc[tj], 0, 0, 0);
            }
        }

        float alpha[4];
#pragma unroll
        for (int r = 0; r < 4; ++r) {
            float sv[4];
            float mx = -1e30f;
#pragma unroll
            for (int tj = 0; tj < 4; ++tj) {
                float s = sc[tj][r] * invsq;
                bool valid = (j0 + tj * 16 + fr) < nv;
                s = valid ? s : -1e30f;
                sv[tj] = s;
                mx = fmaxf(mx, s);
            }
#pragma unroll
            for (int off = 1; off < 16; off <<= 1)
                mx = fmaxf(mx, __shfl_xor(mx, off, 64));
            float mn = fmaxf(mrow[r], mx);
            alpha[r] = expf(mrow[r] - mn);
            float ps = 0.f;
#pragma unroll
            for (int tj = 0; tj < 4; ++tj) {
                bool valid = (j0 + tj * 16 + fr) < nv;
                float p = valid ? expf(sv[tj] - mn) : 0.f;
                Pl[(wv * 16 + quad * 4 + r) * VS + tj * 16 + fr] = (__bf16)p;
                ps += p;
            }
#pragma unroll
            for (int off = 1; off < 16; off <<= 1)
                ps += __shfl_xor(ps, off, 64);
            lrow[r] = lrow[r] * alpha[r] + ps;
            mrow[r] = mn;
        }
#pragma unroll
        for (int tj = 0; tj < 8; ++tj)
#pragma unroll
            for (int r = 0; r < 4; ++r)
                accO[tj][r] *= alpha[r];
        // PV (P per-wave LDS region -> A frag; within-wave, no barrier)
#pragma unroll
        for (int ks = 0; ks < 2; ++ks) {
            bfv8 ap = *(const bfv8*)(Pl + (wv * 16 + fr) * VS + ks * 32 + quad * 8);
#pragma unroll
            for (int tj = 0; tj < 8; ++tj) {
                bfv8 bv8 = *(const bfv8*)(Vl + (tj * 16 + fr) * VS + ks * 32 + quad * 8);
                accO[tj] = __builtin_amdgcn_mfma_f32_16x16x32_bf16(ap, bv8, accO[tj], 0, 0, 0);
            }
        }
    }

#pragma unroll
    for (int r = 0; r < 4; ++r) {
        int row = r0 + wv * 16 + quad * 4 + r;
        if (row < nv) {
            float invl = 1.f / lrow[r];
#pragma unroll
            for (int tj = 0; tj < 8; ++tj)
                AO[(size_t)row * Ec + h * HDc + tj * 16 + fr] = accO[tj][r] * invl;
        }
    }
}

// ---------------------------------------------------------------
__global__ __launch_bounds__(256)
void router_ctx_k(const float* __restrict__ q4, const float* __restrict__ rR,
                  const float* __restrict__ rS,
                  const float* __restrict__ Wk, const float* __restrict__ bk,
                  const float* __restrict__ Wv, const float* __restrict__ bv,
                  float* __restrict__ ctx)
{
    int tid = threadIdx.x;
    int lane = tid & 63;
    int n = blockIdx.x * 4 + (tid >> 6);
    int m = (n >> 7) & 3, t = n & 127, b = n >> 9;
    float q = q4[(size_t)n * AKc + lane];
    float sc[3], rv[3], sv[3];
#pragma unroll
    for (int o = 0; o < 3; ++o) {
        int oth = o + (o >= m ? 1 : 0);
        float r = rR[(((size_t)(b * Mc + m)) * Mc + oth) * Tc + t];
        float s_ = rS[(((size_t)(b * Mc + m)) * Mc + oth) * Tc + t];
        rv[o] = r; sv[o] = s_;
        float key = r * Wk[lane] + s_ * Wk[64 + lane] + bk[lane];
        float p = q * key;
#pragma unroll
        for (int off = 32; off; off >>= 1) p += __shfl_xor(p, off, 64);
        sc[o] = p * 0.125f;
    }
    float mx = fmaxf(sc[0], fmaxf(sc[1], sc[2]));
    float e0 = expf(sc[0] - mx), e1 = expf(sc[1] - mx), e2 = expf(sc[2] - mx);
    float inv = 1.f / (e0 + e1 + e2);
    float p0 = e0 * inv, p1 = e1 * inv, p2 = e2 * inv;
    float v0 = rv[0] * Wv[lane] + sv[0] * Wv[64 + lane] + bv[lane];
    float v1 = rv[1] * Wv[lane] + sv[1] * Wv[64 + lane] + bv[lane];
    float v2 = rv[2] * Wv[lane] + sv[2] * Wv[64 + lane] + bv[lane];
    ctx[(size_t)n * AVc + lane] = p0 * v0 + p1 * v1 + p2 * v2;
}

// ---------------------------------------------------------------
__global__ __launch_bounds__(256)
void gi_k(const float* __restrict__ rU, const float* __restrict__ ctx,
          const float* __restrict__ gWih, const float* __restrict__ gbih,
          float* __restrict__ gi)
{
    int idx = blockIdx.x * 256 + threadIdx.x;   // < 2048*384
    int g = idx % 384, nt = idx / 384;
    const float* Wr = gWih + (size_t)g * 65;
    float a = gbih[g] + rU[nt] * Wr[0];
    const float* c = ctx + (size_t)nt * AVc;
#pragma unroll
    for (int d = 0; d < 64; ++d) a += c[d] * Wr[1 + d];
    gi[(size_t)nt * 384 + g] = a;
}

// ---------------------------------------------------------------
// GRU scan: (384,1) launch bounds -> keep the 128-float weight row in VGPRs
// (round-3 VGPR_Count=116 < 128 proved the default allocation spilled it).
__global__ __launch_bounds__(384, 1)
void gru_scan_k(const float* __restrict__ gi, const float* __restrict__ gWhh,
                const float* __restrict__ gbhh, float* __restrict__ hs)
{
    int seq = blockIdx.x, g = threadIdx.x;
    __shared__ float h[128];
    __shared__ float gh[384];
    float w[128];
    const float4* wr = (const float4*)(gWhh + (size_t)g * 128);
#pragma unroll
    for (int i = 0; i < 32; ++i) {
        float4 t = wr[i];
        w[4*i] = t.x; w[4*i+1] = t.y; w[4*i+2] = t.z; w[4*i+3] = t.w;
    }
    float bh = gbhh[g];
    if (g < 128) h[g] = 0.f;
    __syncthreads();
    for (int t = 0; t < 128; ++t) {
        const float* gr = gi + ((size_t)seq * 128 + t) * 384;
        float g0 = 0.f, g1 = 0.f, g2 = 0.f;
        if (g < 128) { g0 = gr[g]; g1 = gr[128 + g]; g2 = gr[256 + g]; }
        float a0 = 0.f, a1 = 0.f, a2 = 0.f, a3 = 0.f;
#pragma unroll
        for (int d = 0; d < 128; d += 4) {
            float4 h4 = *(const float4*)(&h[d]);
            a0 += h4.x * w[d];     a1 += h4.y * w[d + 1];
            a2 += h4.z * w[d + 2]; a3 += h4.w * w[d + 3];
        }
        gh[g] = bh + (a0 + a1) + (a2 + a3);
        __syncthreads();
        if (g < 128) {
            float r = 1.f / (1.f + expf(-(g0 + gh[g])));
            float z = 1.f / (1.f + expf(-(g1 + gh[128 + g])));
            float nn = tanhf(g2 + r * gh[256 + g]);
            float hn = (1.f - z) * nn + z * h[g];
            hs[((size_t)seq * 128 + t) * 128 + g] = hn;
            h[g] = hn;
        }
        __syncthreads();
    }
}

// ---------------------------------------------------------------
__global__ __launch_bounds__(128)
void mlp_route_k(const float* __restrict__ proc, const float* __restrict__ hs,
                 const float* __restrict__ mW1, const float* __restrict__ mb1,
                 const float* __restrict__ mW2, const float* __restrict__ mb2,
                 float* __restrict__ probsOut, float* __restrict__ idxOut,
                 float* __restrict__ w)
{
    int n = blockIdx.x, tid = threadIdx.x;
    __shared__ float comb[256], tmp[128], lg[8];
    comb[tid] = proc[(size_t)n * 128 + tid];
    comb[128 + tid] = hs[(size_t)n * 128 + tid];
    __syncthreads();
    float a = mb1[tid];
#pragma unroll 8
    for (int d = 0; d < 256; ++d) a += comb[d] * mW1[(size_t)d * 128 + tid];
    tmp[tid] = fmaxf(a, 0.f);
    __syncthreads();
    if (tid < 8) {
        float l = mb2[tid];
        for (int d = 0; d < 128; ++d) l += tmp[d] * mW2[(size_t)d * 8 + tid];
        lg[tid] = l;
    }
    __syncthreads();
    if (tid == 0) {
        float mx = lg[0];
        for (int e = 1; e < 8; ++e) mx = fmaxf(mx, lg[e]);
        float p[8], s = 0.f;
        for (int e = 0; e < 8; ++e) { p[e] = expf(lg[e] - mx); s += p[e]; }
        float inv = 1.f / s;
        for (int e = 0; e < 8; ++e) probsOut[(size_t)n * 8 + e] = p[e] * inv;
        int a0 = 0; float v0 = lg[0];
        for (int e = 1; e < 8; ++e) if (lg[e] > v0) { v0 = lg[e]; a0 = e; }
        int a1 = -1; float v1 = -1e30f;
        for (int e = 0; e < 8; ++e) if (e != a0 && lg[e] > v1) { v1 = lg[e]; a1 = e; }
        float e1 = expf(v1 - v0);
        float t0 = 1.f / (1.f + e1), t1 = e1 / (1.f + e1);
        idxOut[(size_t)n * 2 + 0] = (float)a0;
        idxOut[(size_t)n * 2 + 1] = (float)a1;
        for (int e = 0; e < 8; ++e) w[(size_t)n * 8 + e] = 0.f;
        w[(size_t)n * 8 + a0] = t0;
        w[(size_t)n * 8 + a1] = t1;
    }
}

__global__ __launch_bounds__(256)
void compact_k(const float* __restrict__ w, int* __restrict__ cnt,
               int* __restrict__ list)
{
    int n = blockIdx.x * 256 + threadIdx.x;
    if (n >= NTc) return;
    for (int e = 0; e < NEc; ++e)
        if (w[(size_t)n * 8 + e] > 0.f) {
            int p = atomicAdd(&cnt[e], 1);
            list[e * NTc + p] = n;
        }
}

// ---------------------------------------------------------------
__global__ __launch_bounds__(256)
void ln1_k(const float* __restrict__ x, const int* __restrict__ list,
           const float* __restrict__ add, const float* __restrict__ s,
           const float* __restrict__ b, float* __restrict__ outRows,
           const int* __restrict__ cntPtr)
{
    int i = blockIdx.x;
    if (i >= *cntPtr) return;
    int tid = threadIdx.x;
    int g = list[i];
    float v0 = x[(size_t)g * Ec + tid] + add[(size_t)i * Ec + tid];
    float v1 = x[(size_t)g * Ec + 256 + tid] + add[(size_t)i * Ec + 256 + tid];
    __shared__ float red[256];
    __shared__ float bc;
    red[tid] = v0 + v1; __syncthreads();
    for (int st = 128; st > 0; st >>= 1) { if (tid < st) red[tid] += red[tid + st]; __syncthreads(); }
    if (tid == 0) bc = red[0] * (1.f / 512.f);
    __syncthreads();
    float mu = bc;
    float d0 = v0 - mu, d1 = v1 - mu;
    __syncthreads();
    red[tid] = d0 * d0 + d1 * d1; __syncthreads();
    for (int st = 128; st > 0; st >>= 1) { if (tid < st) red[tid] += red[tid + st]; __syncthreads(); }
    if (tid == 0) bc = rsqrtf(red[0] * (1.f / 512.f) + 1e-5f);
    __syncthreads();
    float inv = bc;
    outRows[(size_t)i * Ec + tid] = d0 * inv * s[tid] + b[tid];
    outRows[(size_t)i * Ec + 256 + tid] = d1 * inv * s[256 + tid] + b[256 + tid];
}

__global__ __launch_bounds__(256)
void ln2_scatter_k(const float* __restrict__ H1, const float* __restrict__ Y,
                   const float* __restrict__ s, const float* __restrict__ b,
                   float* __restrict__ out, const int* __restrict__ list,
                   const int* __restrict__ cntPtr, const float* __restrict__ wvec)
{
    int i = blockIdx.x;
    if (i >= *cntPtr) return;
    int tid = threadIdx.x;
    int g = list[i];
    float v0 = H1[(size_t)i * Ec + tid] + Y[(size_t)i * Ec + tid];
    float v1 = H1[(size_t)i * Ec + 256 + tid] + Y[(size_t)i * Ec + 256 + tid];
    __shared__ float red[256];
    __shared__ float bc;
    red[tid] = v0 + v1; __syncthreads();
    for (int st = 128; st > 0; st >>= 1) { if (tid < st) red[tid] += red[tid + st]; __syncthreads(); }
    if (tid == 0) bc = red[0] * (1.f / 512.f);
    __syncthreads();
    float mu = bc;
    float d0 = v0 - mu, d1 = v1 - mu;
    __syncthreads();
    red[tid] = d0 * d0 + d1 * d1; __syncthreads();
    for (int st = 128; st > 0; st >>= 1) { if (tid < st) red[tid] += red[tid + st]; __syncthreads(); }
    if (tid == 0) bc = rsqrtf(red[0] * (1.f / 512.f) + 1e-5f);
    __syncthreads();
    float inv = bc;
    float wv = wvec[(size_t)g * 8];
    out[(size_t)g * Ec + tid] += (d0 * inv * s[tid] + b[tid]) * wv;
    out[(size_t)g * Ec + 256 + tid] += (d1 * inv * s[256 + tid] + b[256 + tid]) * wv;
}

// ---------------------------------------------------------------
extern "C" void kernel_launch(void* const* d_in, const int* in_sizes, int n_in,
                              void* d_out, int out_size, void* d_ws, size_t ws_size,
                              hipStream_t stream)
{
    const float* x    = (const float*)d_in[0];
    const float* rU   = (const float*)d_in[1];
    const float* rR   = (const float*)d_in[2];
    const float* rS   = (const float*)d_in[3];
    const float* Wtp  = (const float*)d_in[6];
    const float* btp  = (const float*)d_in[7];
    const float* Wq   = (const float*)d_in[8];
    const float* bq   = (const float*)d_in[9];
    const float* Wk   = (const float*)d_in[10];
    const float* bk   = (const float*)d_in[11];
    const float* Wv   = (const float*)d_in[12];
    const float* bv   = (const float*)d_in[13];
    const float* gWih = (const float*)d_in[14];
    const float* gbih = (const float*)d_in[15];
    const float* gWhh = (const float*)d_in[16];
    const float* gbhh = (const float*)d_in[17];
    const float* mW1  = (const float*)d_in[18];
    const float* mb1  = (const float*)d_in[19];
    const float* mW2  = (const float*)d_in[20];
    const float* mb2  = (const float*)d_in[21];
    const float* sWq  = (const float*)d_in[22];
    const float* sbq  = (const float*)d_in[23];
    const float* sWk  = (const float*)d_in[24];
    const float* sbk  = (const float*)d_in[25];
    const float* sWv  = (const float*)d_in[26];
    const float* sbv  = (const float*)d_in[27];
    const float* sWo  = (const float*)d_in[28];
    const float* sbo  = (const float*)d_in[29];
    const float* sln1s = (const float*)d_in[30];
    const float* sln1b = (const float*)d_in[31];
    const float* sW1  = (const float*)d_in[32];
    const float* sb1  = (const float*)d_in[33];
    const float* sW2  = (const float*)d_in[34];
    const float* sb2  = (const float*)d_in[35];
    const float* sln2s = (const float*)d_in[36];
    const float* sln2b = (const float*)d_in[37];
    const float* fW1  = (const float*)d_in[38];
    const float* fb1  = (const float*)d_in[39];
    const float* fW2  = (const float*)d_in[40];
    const float* fb2  = (const float*)d_in[41];

    float* out      = (float*)d_out;                 // [2048,512]
    float* probsOut = out + (size_t)NTc * Ec;        // [2048,8]
    float* idxOut   = probsOut + (size_t)NTc * NEc;  // [2048,2]

    // ---- workspace layout ----
    int*   cnt  = (int*)d_ws;                        // 64 ints
    int*   list = cnt + 64;                          // 8*2048
    float* w    = (float*)d_ws + 64 + NEc * NTc;     // [2048,8]
    // bf16 weight region
    __bf16* WB   = (__bf16*)(w + NTc * NEc);
    __bf16* WqT  = WB;                         // synergy slot [512][512]
    __bf16* WkT  = WB + 262144;
    __bf16* WvT  = WB + 2 * 262144;
    __bf16* WoT  = WB + 3 * 262144;
    __bf16* sW1T = WB + 4 * 262144;            // [2048][512]
    __bf16* sW2T = sW1T + 1048576;             // [512][2048]
    __bf16* fW1T = sW2T + 1048576;             // 3 x [2048][512]
    __bf16* fW2T = fW1T + 3 * 1048576;         // 3 x [512][2048]
    // activation region (fp32)
    float* act = (float*)(fW2T + 3 * 1048576);
    float* Qb  = act;                  // [2048][512]
    float* Kb  = act + 1048576;
    float* Vt  = act + 2 * 1048576;    // [512][2048] d-major
    float* AO  = act + 3 * 1048576;
    float* H1  = act + 4 * 1048576;
    float* PRJ = Qb;                   // alias (Qb dead after flash)
    float* Yb  = Kb;                   // alias (Kb dead after flash)
    __bf16* FF1b = (__bf16*)(act + 5 * 1048576);  // 3 x [2048][2048] bf16
    // router region overlays Qb/Kb (dead before experts start)
    float* proc = act;                 // 2048*128
    float* q4   = act + 262144;        // 2048*64
    float* ctx  = act + 393216;        // 2048*64
    float* gi   = act + 524288;        // 16*128*384 = 786432
    float* hs   = act + 1310720;       // 2048*128

    // ---- init ----
    zero_k<<<1024, 256, 0, stream>>>(out, cnt);

    // ---- router (fp32 — keeps top-2 idx bit-stable) ----
    gemm_k<<<dim3(32, 2), 256, 0, stream>>>(x, Ec, Wtp, Pc, btp, proc, Pc, NTc, Pc, Ec, 1);
    gemm_k<<<dim3(32, 1), 256, 0, stream>>>(proc, Pc, Wq, AKc, bq, q4, AKc, NTc, AKc, Pc, 0);
    router_ctx_k<<<512, 256, 0, stream>>>(q4, rR, rS, Wk, bk, Wv, bv, ctx);
    gi_k<<<3072, 256, 0, stream>>>(rU, ctx, gWih, gbih, gi);
    gru_scan_k<<<16, 384, 0, stream>>>(gi, gWhh, gbhh, hs);
    mlp_route_k<<<2048, 128, 0, stream>>>(proc, hs, mW1, mb1, mW2, mb2,
                                          probsOut, idxOut, w);
    compact_k<<<8, 256, 0, stream>>>(w, cnt, list);

    GJob JZ = {};   // zero template

    // ---- synergy experts ----
    for (int e = 0; e < NSc; ++e) {
        const int* cl = list + e * NTc;
        const int* ce = cnt + e;
        // weight conversion (batched)
        {
            CJob c0 = { sWq + (size_t)e * Ec * Ec, WqT };
            CJob c1 = { sWk + (size_t)e * Ec * Ec, WkT };
            CJob c2 = { sWv + (size_t)e * Ec * Ec, WvT };
            CJob c3 = { sWo + (size_t)e * Ec * Ec, WoT };
            convT_k<<<dim3(16, 16, 4), 256, 0, stream>>>(c0, c1, c2, c3, Ec, Ec);
            CJob w1 = { sW1 + (size_t)e * Ec * Hc, sW1T };
            convT_k<<<dim3(64, 16, 1), 256, 0, stream>>>(w1, w1, w1, w1, Ec, Hc);
            CJob w2 = { sW2 + (size_t)e * Hc * Ec, sW2T };
            convT_k<<<dim3(16, 64, 1), 256, 0, stream>>>(w2, w2, w2, w2, Hc, Ec);
        }
        // QKV batched (z=3); V stored transposed (Vt)
        {
            GJob jq = JZ; jq.A = x; jq.B = WqT; jq.bias = sbq + e * Ec; jq.C = Qb;
            jq.Mptr = ce; jq.gatherA = cl; jq.ldc = Ec; jq.flags = 0;
            GJob jk = jq; jk.B = WkT; jk.bias = sbk + e * Ec; jk.C = Kb;
            GJob jv = jq; jv.B = WvT; jv.bias = sbv + e * Ec; jv.C = Vt;
            jv.ldc = NTc; jv.flags = 2;  // storeT
            gemm_batch_k<0><<<dim3(16, 4, 3), 256, 0, stream>>>(jq, jk, jv, Ec, Ec, Ec, Ec);
        }
        // flash attention
        flash_k<<<dim3(32, 4), 256, 0, stream>>>(Qb, Kb, Vt, AO, ce);
        // Wo projection
        {
            GJob jo = JZ; jo.A = AO; jo.B = WoT; jo.bias = sbo + e * Ec; jo.C = PRJ;
            jo.Mptr = ce; jo.ldc = Ec;
            gemm_batch_k<0><<<dim3(16, 4, 1), 256, 0, stream>>>(jo, jo, jo, Ec, Ec, Ec, Ec);
        }
        ln1_k<<<2048, 256, 0, stream>>>(x, cl, PRJ, sln1s + e * Ec, sln1b + e * Ec, H1, ce);
        // FF1 -> bf16, relu
        {
            GJob j1 = JZ; j1.A = H1; j1.B = sW1T; j1.bias = sb1 + e * Hc; j1.C = FF1b;
            j1.Mptr = ce; j1.ldc = Hc; j1.flags = 1 | 4;
            gemm_batch_k<0><<<dim3(16, 16, 1), 256, 0, stream>>>(j1, j1, j1, Ec, Ec, Hc, Ec);
        }
        // FF2 (bf16 A)
        {
            GJob j2 = JZ; j2.A = FF1b; j2.B = sW2T; j2.bias = sb2 + e * Ec; j2.C = Yb;
            j2.Mptr = ce; j2.ldc = Ec;
            gemm_batch_k<1><<<dim3(16, 4, 1), 256, 0, stream>>>(j2, j2, j2, Hc, Hc, Ec, Hc);
        }
        ln2_scatter_k<<<2048, 256, 0, stream>>>(H1, Yb, sln2s + e * Ec, sln2b + e * Ec,
                                                out, cl, ce, w + e);
    }

    // ---- FFN experts: 2 rounds of 3, batched ----
    for (int rnd = 0; rnd < 2; ++rnd) {
        int f0 = rnd * 3;
        // convert weights for this round
        {
            CJob a0 = { fW1 + (size_t)(f0 + 0) * Ec * Hc, fW1T };
            CJob a1 = { fW1 + (size_t)(f0 + 1) * Ec * Hc, fW1T + 1048576 };
            CJob a2 = { fW1 + (size_t)(f0 + 2) * Ec * Hc, fW1T + 2 * 1048576 };
            convT_k<<<dim3(64, 16, 3), 256, 0, stream>>>(a0, a1, a2, a0, Ec, Hc);
            CJob b0 = { fW2 + (size_t)(f0 + 0) * Hc * Ec, fW2T };
            CJob b1 = { fW2 + (size_t)(f0 + 1) * Hc * Ec, fW2T + 1048576 };
            CJob b2 = { fW2 + (size_t)(f0 + 2) * Hc * Ec, fW2T + 2 * 1048576 };
            convT_k<<<dim3(16, 64, 3), 256, 0, stream>>>(b0, b1, b2, b0, Hc, Ec);
        }
        // FF1 batched (relu, bf16 out)
        {
            GJob j[3];
            for (int u = 0; u < 3; ++u) {
                int f = f0 + u, e = f + NSc;
                j[u] = JZ;
                j[u].A = x; j[u].B = fW1T + (size_t)u * 1048576;
                j[u].bias = fb1 + (size_t)f * Hc;
                j[u].C = FF1b + (size_t)u * NTc * Hc;
                j[u].Mptr = cnt + e; j[u].gatherA = list + e * NTc;
                j[u].ldc = Hc; j[u].flags = 1 | 4;
            }
            gemm_batch_k<0><<<dim3(16, 16, 3), 256, 0, stream>>>(j[0], j[1], j[2], Ec, Ec, Hc, Ec);
        }
        // FF2 batched (bf16 A, atomic scatter to out)
        {
            GJob j[3];
            for (int u = 0; u < 3; ++u) {
                int f = f0 + u, e = f + NSc;
                j[u] = JZ;
                j[u].A = FF1b + (size_t)u * NTc * Hc;
                j[u].B = fW2T + (size_t)u * 1048576;
                j[u].bias = fb2 + (size_t)f * Ec;
                j[u].Mptr = cnt + e;
                j[u].scatterOut = out; j[u].scatterList = list + e * NTc;
                j[u].wvec = w + e; j[u].ldc = Ec;
            }
            gemm_batch_k<1><<<dim3(16, 4, 3), 256, 0, stream>>>(j[0], j[1], j[2], Hc, Hc, Ec, Hc);
        }
    }
}

// Round 5
// 1080.439 us; speedup vs baseline: 5.9398x; 1.1031x over previous
//
#include <hip/hip_runtime.h>
#include <math.h>

// ---------- constants ----------
#define Bc 4
#define Mc 4
#define Tc 128
#define Ec 512
#define Hc 2048
#define NEc 8
#define NSc 2
#define NHEADc 4
#define Pc 128
#define GRUHc 128
#define AKc 64
#define AVc 64
#define NTc 2048        // B*S
#define HDc 128         // E/NHEAD

typedef __bf16 bfv8 __attribute__((ext_vector_type(8)));
typedef float f32x4 __attribute__((ext_vector_type(4)));

// ---------------------------------------------------------------
__global__ __launch_bounds__(256)
void zero_k(float* __restrict__ out, int* __restrict__ cnt)
{
    int i = blockIdx.x * 256 + threadIdx.x;
    float4* o4 = (float4*)out;
    if (i < (NTc * Ec) / 4) o4[i] = make_float4(0.f, 0.f, 0.f, 0.f);
    if (i < NEc) cnt[i] = 0;
}

// ---------------------------------------------------------------
// batched tiled transpose + fp32->bf16 convert: W[K,N] -> Wt[N,K]
struct CJob { const float* src; __bf16* dst; };
struct CJobs8 { CJob j[8]; };

__global__ __launch_bounds__(256)
void convT_k(CJobs8 jobs, int K, int N)
{
    CJob J = jobs.j[blockIdx.z];
    __shared__ float t[32][33];
    int bx = blockIdx.x * 32;   // n tile
    int by = blockIdx.y * 32;   // k tile
    int tx = threadIdx.x & 31, ty = threadIdx.x >> 5;   // 32 x 8
#pragma unroll
    for (int i = 0; i < 4; ++i) {
        int k = by + ty + i * 8, n = bx + tx;
        t[ty + i * 8][tx] = (k < K && n < N) ? J.src[(size_t)k * N + n] : 0.f;
    }
    __syncthreads();
#pragma unroll
    for (int i = 0; i < 4; ++i) {
        int n = bx + ty + i * 8, k = by + tx;
        if (n < N && k < K) J.dst[(size_t)n * K + k] = (__bf16)t[tx][ty + i * 8];
    }
}

// ---------------------------------------------------------------
// fp32 tiled GEMM (router only — keeps top-2 routing bit-stable)
__global__ __launch_bounds__(256)
void gemm_k(const float* __restrict__ A, int lda,
            const float* __restrict__ B, int ldb,
            const float* __restrict__ bias,
            float* __restrict__ C, int ldc,
            int M, int N, int K, int relu)
{
    int tm = blockIdx.x * 64, tn = blockIdx.y * 64;
    if (tm >= M || tn >= N) return;
    __shared__ float As[16][68];
    __shared__ float Bs[16][68];
    int tid = threadIdx.x;
    int tx = tid & 15, ty = tid >> 4;
    float acc[4][4] = {};
    int arow = tid >> 2;
    int ak0  = (tid & 3) * 4;
    int bk   = tid >> 4;
    int bc0  = (tid & 15) * 4;
    int grA = tm + arow;
    const float* Arow = (grA < M) ? (A + (size_t)grA * lda) : nullptr;

    for (int k0 = 0; k0 < K; k0 += 16) {
#pragma unroll
        for (int u = 0; u < 4; ++u) {
            int k = k0 + ak0 + u;
            As[ak0 + u][arow] = (Arow && k < K) ? Arow[k] : 0.f;
        }
        int kb = k0 + bk;
#pragma unroll
        for (int u = 0; u < 4; ++u) {
            int n2 = tn + bc0 + u;
            Bs[bk][bc0 + u] = (kb < K && n2 < N) ? B[(size_t)kb * ldb + n2] : 0.f;
        }
        __syncthreads();
#pragma unroll
        for (int kk = 0; kk < 16; ++kk) {
            float a0 = As[kk][ty * 4 + 0], a1 = As[kk][ty * 4 + 1];
            float a2 = As[kk][ty * 4 + 2], a3 = As[kk][ty * 4 + 3];
            float b0 = Bs[kk][tx * 4 + 0], b1 = Bs[kk][tx * 4 + 1];
            float b2 = Bs[kk][tx * 4 + 2], b3 = Bs[kk][tx * 4 + 3];
            acc[0][0] += a0 * b0; acc[0][1] += a0 * b1; acc[0][2] += a0 * b2; acc[0][3] += a0 * b3;
            acc[1][0] += a1 * b0; acc[1][1] += a1 * b1; acc[1][2] += a1 * b2; acc[1][3] += a1 * b3;
            acc[2][0] += a2 * b0; acc[2][1] += a2 * b1; acc[2][2] += a2 * b2; acc[2][3] += a2 * b3;
            acc[3][0] += a3 * b0; acc[3][1] += a3 * b1; acc[3][2] += a3 * b2; acc[3][3] += a3 * b3;
        }
        __syncthreads();
    }
#pragma unroll
    for (int i = 0; i < 4; ++i) {
        int gr = tm + ty * 4 + i;
        if (gr >= M) continue;
#pragma unroll
        for (int j = 0; j < 4; ++j) {
            int gc = tn + tx * 4 + j;
            if (gc >= N) continue;
            float v = acc[i][j] + (bias ? bias[gc] : 0.f);
            if (relu) v = fmaxf(v, 0.f);
            C[(size_t)gr * ldc + gc] = v;
        }
    }
}

// ---------------------------------------------------------------
// batched bf16 MFMA GEMM. A: fp32 (AMODE=0) or bf16 (AMODE=1) rows,
// optional row gather. B: bf16 [N][K] K-contiguous. 128x128 tile, 4 waves,
// BK=32, register-prefetch pipeline. K % 32 == 0 (512/2048).
// flags: 1=relu, 2=storeT (fp32 C[gn*ldc+gm]), 4=storeBf (bf16 C).
struct GJob {
    const void* A;
    const void* B;
    const float* bias;
    void* C;
    const int* Mptr;
    const int* gatherA;
    float* scatterOut;
    const int* scatterList;
    const float* wvec;
    int ldc;
    int flags;
};
struct GJobs6 { GJob j[6]; };

#define LDA_S 40   // LDS row stride in bf16 elems (32 + 8 pad)
template<int AMODE>
__global__ __launch_bounds__(256)
void gemm_batch_k(GJobs6 jobs, int lda, int ldb, int N, int K)
{
    GJob J = jobs.j[blockIdx.z];
    int M = *J.Mptr;
    int tm = blockIdx.x * 128, tn = blockIdx.y * 128;
    if (tm >= M || tn >= N) return;

    __shared__ __bf16 As[128 * LDA_S];
    __shared__ __bf16 Bs[128 * LDA_S];
    int tid = threadIdx.x, lane = tid & 63, wvi = tid >> 6;
    int wm = (wvi & 1) * 64, wn = (wvi >> 1) * 64;
    f32x4 acc[4][4] = {};

    int ar = tid >> 1, ah = (tid & 1) * 16;   // staging row / k-half
    const float*  Apf = nullptr;
    const __bf16* Apb = nullptr;
    if (tm + ar < M) {
        int g = J.gatherA ? J.gatherA[tm + ar] : (tm + ar);
        if (AMODE == 0) Apf = (const float*)J.A + (size_t)g * lda;
        else            Apb = (const __bf16*)J.A + (size_t)g * lda;
    }
    const __bf16* Bp = ((tn + ar) < N) ? ((const __bf16*)J.B + (size_t)(tn + ar) * ldb)
                                       : nullptr;

    float fa[16];
    bfv8 ra0, ra1, rb0, rb1;

    auto LOADA = [&](int k0) {
        int kb = k0 + ah;
        if (AMODE == 0) {
            if (Apf) {
                const float4* p = (const float4*)(Apf + kb);
                float4 x0 = p[0], x1 = p[1], x2 = p[2], x3 = p[3];
                fa[0]=x0.x; fa[1]=x0.y; fa[2]=x0.z; fa[3]=x0.w;
                fa[4]=x1.x; fa[5]=x1.y; fa[6]=x1.z; fa[7]=x1.w;
                fa[8]=x2.x; fa[9]=x2.y; fa[10]=x2.z; fa[11]=x2.w;
                fa[12]=x3.x; fa[13]=x3.y; fa[14]=x3.z; fa[15]=x3.w;
            } else {
#pragma unroll
                for (int i = 0; i < 16; ++i) fa[i] = 0.f;
            }
        } else {
            if (Apb) {
                ra0 = *(const bfv8*)(Apb + kb);
                ra1 = *(const bfv8*)(Apb + kb + 8);
            } else {
#pragma unroll
                for (int i = 0; i < 8; ++i) { ra0[i] = (__bf16)0.f; ra1[i] = (__bf16)0.f; }
            }
        }
    };
    auto LOADB = [&](int k0) {
        int kb = k0 + ah;
        if (Bp) {
            rb0 = *(const bfv8*)(Bp + kb);
            rb1 = *(const bfv8*)(Bp + kb + 8);
        } else {
#pragma unroll
            for (int i = 0; i < 8; ++i) { rb0[i] = (__bf16)0.f; rb1[i] = (__bf16)0.f; }
        }
    };

    int KT = K / 32;
    LOADA(0);
    LOADB(0);

    for (int kt = 0; kt < KT; ++kt) {
        __syncthreads();
        if (AMODE == 0) {
            bfv8 p0, p1;
#pragma unroll
            for (int i = 0; i < 8; ++i) { p0[i] = (__bf16)fa[i]; p1[i] = (__bf16)fa[8 + i]; }
            *(bfv8*)(As + ar * LDA_S + ah) = p0;
            *(bfv8*)(As + ar * LDA_S + ah + 8) = p1;
        } else {
            *(bfv8*)(As + ar * LDA_S + ah) = ra0;
            *(bfv8*)(As + ar * LDA_S + ah + 8) = ra1;
        }
        *(bfv8*)(Bs + ar * LDA_S + ah) = rb0;
        *(bfv8*)(Bs + ar * LDA_S + ah + 8) = rb1;
        __syncthreads();
        if (kt + 1 < KT) {
            LOADA((kt + 1) * 32);
            LOADB((kt + 1) * 32);
        }
        {
            int fr = lane & 15, quad = lane >> 4;
            bfv8 af[4], bfr[4];
            const __bf16* Ab = As + quad * 8 + fr * LDA_S;
            const __bf16* Bb2 = Bs + quad * 8 + fr * LDA_S;
#pragma unroll
            for (int t2 = 0; t2 < 4; ++t2) {
                af[t2]  = *(const bfv8*)(Ab + (wm + t2 * 16) * LDA_S);
                bfr[t2] = *(const bfv8*)(Bb2 + (wn + t2 * 16) * LDA_S);
            }
#pragma unroll
            for (int i = 0; i < 4; ++i)
#pragma unroll
                for (int j = 0; j < 4; ++j)
                    acc[i][j] = __builtin_amdgcn_mfma_f32_16x16x32_bf16(af[i], bfr[j], acc[i][j], 0, 0, 0);
        }
    }

    // epilogue: C layout col=lane&15, row=(lane>>4)*4+reg
    int col = lane & 15, rq = (lane >> 4) * 4;
    int relu = J.flags & 1, storeT = J.flags & 2, storeBf = J.flags & 4;
#pragma unroll
    for (int ti = 0; ti < 4; ++ti) {
#pragma unroll
        for (int tj = 0; tj < 4; ++tj) {
#pragma unroll
            for (int r = 0; r < 4; ++r) {
                int gm = tm + wm + ti * 16 + rq + r;
                int gn = tn + wn + tj * 16 + col;
                if (gm < M && gn < N) {
                    float v = acc[ti][tj][r] + (J.bias ? J.bias[gn] : 0.f);
                    if (relu) v = fmaxf(v, 0.f);
                    if (J.scatterOut) {
                        int g = J.scatterList[gm];
                        atomicAdd(&J.scatterOut[(size_t)g * Ec + gn], v * J.wvec[(size_t)g * NEc]);
                    } else if (storeT) {
                        ((float*)J.C)[(size_t)gn * J.ldc + gm] = v;
                    } else if (storeBf) {
                        ((__bf16*)J.C)[(size_t)gm * J.ldc + gn] = (__bf16)v;
                    } else {
                        ((float*)J.C)[(size_t)gm * J.ldc + gn] = v;
                    }
                }
            }
        }
    }
}

// ---------------------------------------------------------------
// Flash attention over compacted tokens, batched over experts (blockIdx.z).
// Q,K: fp32 [2048][512] compacted rows. Vt: fp32 [512][2048] (d-major).
__global__ __launch_bounds__(256)
void flash_k(const float* __restrict__ QbB, const float* __restrict__ KbB,
             const float* __restrict__ VtB, float* __restrict__ AOB,
             const int* __restrict__ cntB)
{
    int e = blockIdx.z;
    const float* Qb = QbB + (size_t)e * NTc * Ec;
    const float* Kb = KbB + (size_t)e * NTc * Ec;
    const float* Vt = VtB + (size_t)e * NTc * Ec;
    float* AO = AOB + (size_t)e * NTc * Ec;
    int nv = cntB[e];
    int r0 = blockIdx.x * 64;
    if (r0 >= nv) return;
    int h = blockIdx.y;
    const int QS = 136, VS = 72;
    __shared__ __bf16 Ql[64 * 136];
    __shared__ __bf16 Kl[64 * 136];
    __shared__ __bf16 Vl[128 * 72];
    __shared__ __bf16 Pl[64 * 72];
    int tid = threadIdx.x, lane = tid & 63, wv = tid >> 6;
    int fr = lane & 15, quad = lane >> 4;

    {   // load Q tile (rows >= nv -> 0)
        int qr = tid >> 2, c0 = (tid & 3) * 32;
        const float* src = Qb + (size_t)(r0 + qr) * Ec + h * HDc + c0;
        __bf16* dst = Ql + qr * QS + c0;
        bool ok = (r0 + qr) < nv;
#pragma unroll
        for (int u = 0; u < 8; ++u) {
            float4 v = ok ? ((const float4*)src)[u] : make_float4(0.f, 0.f, 0.f, 0.f);
            dst[u*4+0] = (__bf16)v.x; dst[u*4+1] = (__bf16)v.y;
            dst[u*4+2] = (__bf16)v.z; dst[u*4+3] = (__bf16)v.w;
        }
    }

    f32x4 accO[8];
#pragma unroll
    for (int j = 0; j < 8; ++j) accO[j] = (f32x4){0.f, 0.f, 0.f, 0.f};
    float mrow[4] = {-1e30f, -1e30f, -1e30f, -1e30f};
    float lrow[4] = {0.f, 0.f, 0.f, 0.f};
    const float invsq = 0.08838834764831845f;   // 1/sqrt(128)

    for (int j0 = 0; j0 < nv; j0 += 64) {
        __syncthreads();
        {   // K tile
            int kr = tid >> 2, c0 = (tid & 3) * 32;
            const float* src = Kb + (size_t)(j0 + kr) * Ec + h * HDc + c0;
            __bf16* dst = Kl + kr * QS + c0;
            bool ok = (j0 + kr) < nv;
#pragma unroll
            for (int u = 0; u < 8; ++u) {
                float4 v = ok ? ((const float4*)src)[u] : make_float4(0.f, 0.f, 0.f, 0.f);
                dst[u*4+0] = (__bf16)v.x; dst[u*4+1] = (__bf16)v.y;
                dst[u*4+2] = (__bf16)v.z; dst[u*4+3] = (__bf16)v.w;
            }
        }
        {   // Vt tile (d-major)
            int dr = tid >> 1, c0 = (tid & 1) * 32;
            const float* src = Vt + (size_t)(h * HDc + dr) * NTc + j0 + c0;
            __bf16* dst = Vl + dr * VS + c0;
            int rem = nv - (j0 + c0);
            if (rem >= 32) {
#pragma unroll
                for (int u = 0; u < 8; ++u) {
                    float4 v = ((const float4*)src)[u];
                    dst[u*4+0] = (__bf16)v.x; dst[u*4+1] = (__bf16)v.y;
                    dst[u*4+2] = (__bf16)v.z; dst[u*4+3] = (__bf16)v.w;
                }
            } else {
                for (int u = 0; u < 32; ++u)
                    dst[u] = (u < rem) ? (__bf16)src[u] : (__bf16)0.f;
            }
        }
        __syncthreads();

        // S = Q K^T (wave owns rows wv*16..+16)
        f32x4 sc[4] = {};
#pragma unroll
        for (int ks = 0; ks < 4; ++ks) {
            bfv8 aq = *(const bfv8*)(Ql + (wv * 16 + fr) * QS + ks * 32 + quad * 8);
#pragma unroll
            for (int tj = 0; tj < 4; ++tj) {
                bfv8 bk8 = *(const bfv8*)(Kl + (tj * 16 + fr) * QS + ks * 32 + quad * 8);
                sc[tj] = __builtin_amdgcn_mfma_f32_16x16x32_bf16(aq, bk8, sc[tj], 0, 0, 0);
            }
        }

        float alpha[4];
#pragma unroll
        for (int r = 0; r < 4; ++r) {
            float sv[4];
            float mx = -1e30f;
#pragma unroll
            for (int tj = 0; tj < 4; ++tj) {
                float s = sc[tj][r] * invsq;
                bool valid = (j0 + tj * 16 + fr) < nv;
                s = valid ? s : -1e30f;
                sv[tj] = s;
                mx = fmaxf(mx, s);
            }
#pragma unroll
            for (int off = 1; off < 16; off <<= 1)
                mx = fmaxf(mx, __shfl_xor(mx, off, 64));
            float mn = fmaxf(mrow[r], mx);
            alpha[r] = expf(mrow[r] - mn);
            float ps = 0.f;
#pragma unroll
            for (int tj = 0; tj < 4; ++tj) {
                bool valid = (j0 + tj * 16 + fr) < nv;
                float p = valid ? expf(sv[tj] - mn) : 0.f;
                Pl[(wv * 16 + quad * 4 + r) * VS + tj * 16 + fr] = (__bf16)p;
                ps += p;
            }
#pragma unroll
            for (int off = 1; off < 16; off <<= 1)
                ps += __shfl_xor(ps, off, 64);
            lrow[r] = lrow[r] * alpha[r] + ps;
            mrow[r] = mn;
        }
#pragma unroll
        for (int tj = 0; tj < 8; ++tj)
#pragma unroll
            for (int r = 0; r < 4; ++r)
                accO[tj][r] *= alpha[r];
        // PV (P per-wave LDS region -> A frag; within-wave, no barrier)
#pragma unroll
        for (int ks = 0; ks < 2; ++ks) {
            bfv8 ap = *(const bfv8*)(Pl + (wv * 16 + fr) * VS + ks * 32 + quad * 8);
#pragma unroll
            for (int tj = 0; tj < 8; ++tj) {
                bfv8 bv8 = *(const bfv8*)(Vl + (tj * 16 + fr) * VS + ks * 32 + quad * 8);
                accO[tj] = __builtin_amdgcn_mfma_f32_16x16x32_bf16(ap, bv8, accO[tj], 0, 0, 0);
            }
        }
    }

#pragma unroll
    for (int r = 0; r < 4; ++r) {
        int row = r0 + wv * 16 + quad * 4 + r;
        if (row < nv) {
            float invl = 1.f / lrow[r];
#pragma unroll
            for (int tj = 0; tj < 8; ++tj)
                AO[(size_t)row * Ec + h * HDc + tj * 16 + fr] = accO[tj][r] * invl;
        }
    }
}

// ---------------------------------------------------------------
__global__ __launch_bounds__(256)
void router_ctx_k(const float* __restrict__ q4, const float* __restrict__ rR,
                  const float* __restrict__ rS,
                  const float* __restrict__ Wk, const float* __restrict__ bk,
                  const float* __restrict__ Wv, const float* __restrict__ bv,
                  float* __restrict__ ctx)
{
    int tid = threadIdx.x;
    int lane = tid & 63;
    int n = blockIdx.x * 4 + (tid >> 6);
    int m = (n >> 7) & 3, t = n & 127, b = n >> 9;
    float q = q4[(size_t)n * AKc + lane];
    float sc[3], rv[3], sv[3];
#pragma unroll
    for (int o = 0; o < 3; ++o) {
        int oth = o + (o >= m ? 1 : 0);
        float r = rR[(((size_t)(b * Mc + m)) * Mc + oth) * Tc + t];
        float s_ = rS[(((size_t)(b * Mc + m)) * Mc + oth) * Tc + t];
        rv[o] = r; sv[o] = s_;
        float key = r * Wk[lane] + s_ * Wk[64 + lane] + bk[lane];
        float p = q * key;
#pragma unroll
        for (int off = 32; off; off >>= 1) p += __shfl_xor(p, off, 64);
        sc[o] = p * 0.125f;
    }
    float mx = fmaxf(sc[0], fmaxf(sc[1], sc[2]));
    float e0 = expf(sc[0] - mx), e1 = expf(sc[1] - mx), e2 = expf(sc[2] - mx);
    float inv = 1.f / (e0 + e1 + e2);
    float p0 = e0 * inv, p1 = e1 * inv, p2 = e2 * inv;
    float v0 = rv[0] * Wv[lane] + sv[0] * Wv[64 + lane] + bv[lane];
    float v1 = rv[1] * Wv[lane] + sv[1] * Wv[64 + lane] + bv[lane];
    float v2 = rv[2] * Wv[lane] + sv[2] * Wv[64 + lane] + bv[lane];
    ctx[(size_t)n * AVc + lane] = p0 * v0 + p1 * v1 + p2 * v2;
}

// ---------------------------------------------------------------
__global__ __launch_bounds__(256)
void gi_k(const float* __restrict__ rU, const float* __restrict__ ctx,
          const float* __restrict__ gWih, const float* __restrict__ gbih,
          float* __restrict__ gi)
{
    int idx = blockIdx.x * 256 + threadIdx.x;   // < 2048*384
    int g = idx % 384, nt = idx / 384;
    const float* Wr = gWih + (size_t)g * 65;
    float a = gbih[g] + rU[nt] * Wr[0];
    const float* c = ctx + (size_t)nt * AVc;
#pragma unroll
    for (int d = 0; d < 64; ++d) a += c[d] * Wr[1 + d];
    gi[(size_t)nt * 384 + g] = a;
}

// ---------------------------------------------------------------
// GRU scan, split-K: 768 threads. Thread (g = tid>>1, p = tid&1) holds 64
// weights in VGPRs (~90 total, under the 116-VGPR spill cliff seen in r3/r4),
// computes a half dot-product; halves combine through LDS part[].
__global__ __launch_bounds__(768, 1)
void gru_scan_k(const float* __restrict__ gi, const float* __restrict__ gWhh,
                const float* __restrict__ gbhh, float* __restrict__ hs)
{
    int seq = blockIdx.x, tid = threadIdx.x;
    int g = tid >> 1, p = tid & 1;
    __shared__ float h[128];
    __shared__ float part[768];
    float w[64];
    const float4* wr = (const float4*)(gWhh + (size_t)g * 128 + p * 64);
#pragma unroll
    for (int i = 0; i < 16; ++i) {
        float4 t4 = wr[i];
        w[4*i] = t4.x; w[4*i+1] = t4.y; w[4*i+2] = t4.z; w[4*i+3] = t4.w;
    }
    float bR = 0.f, bZ = 0.f, bN = 0.f;
    if (tid < 128) {
        bR = gbhh[tid]; bZ = gbhh[128 + tid]; bN = gbhh[256 + tid];
        h[tid] = 0.f;
    }
    __syncthreads();
    const int hoff = p * 64;
    for (int t = 0; t < 128; ++t) {
        // prefetch gi row (independent of h)
        float g0 = 0.f, g1 = 0.f, g2 = 0.f;
        if (tid < 128) {
            const float* gr = gi + ((size_t)seq * 128 + t) * 384;
            g0 = gr[tid]; g1 = gr[128 + tid]; g2 = gr[256 + tid];
        }
        float a0 = 0.f, a1 = 0.f, a2 = 0.f, a3 = 0.f;
#pragma unroll
        for (int d = 0; d < 64; d += 4) {
            float4 h4 = *(const float4*)(&h[hoff + d]);
            a0 += h4.x * w[d];     a1 += h4.y * w[d + 1];
            a2 += h4.z * w[d + 2]; a3 += h4.w * w[d + 3];
        }
        part[tid] = (a0 + a1) + (a2 + a3);
        __syncthreads();
        if (tid < 128) {
            float ghR = bR + part[2 * tid] + part[2 * tid + 1];
            float ghZ = bZ + part[2 * (128 + tid)] + part[2 * (128 + tid) + 1];
            float ghN = bN + part[2 * (256 + tid)] + part[2 * (256 + tid) + 1];
            float r = 1.f / (1.f + expf(-(g0 + ghR)));
            float z = 1.f / (1.f + expf(-(g1 + ghZ)));
            float nn = tanhf(g2 + r * ghN);
            float hn = (1.f - z) * nn + z * h[tid];
            hs[((size_t)seq * 128 + t) * 128 + tid] = hn;
            h[tid] = hn;
        }
        __syncthreads();
    }
}

// ---------------------------------------------------------------
__global__ __launch_bounds__(128)
void mlp_route_k(const float* __restrict__ proc, const float* __restrict__ hs,
                 const float* __restrict__ mW1, const float* __restrict__ mb1,
                 const float* __restrict__ mW2, const float* __restrict__ mb2,
                 float* __restrict__ probsOut, float* __restrict__ idxOut,
                 float* __restrict__ w)
{
    int n = blockIdx.x, tid = threadIdx.x;
    __shared__ float comb[256], tmp[128], lg[8];
    comb[tid] = proc[(size_t)n * 128 + tid];
    comb[128 + tid] = hs[(size_t)n * 128 + tid];
    __syncthreads();
    float a = mb1[tid];
#pragma unroll 8
    for (int d = 0; d < 256; ++d) a += comb[d] * mW1[(size_t)d * 128 + tid];
    tmp[tid] = fmaxf(a, 0.f);
    __syncthreads();
    if (tid < 8) {
        float l = mb2[tid];
        for (int d = 0; d < 128; ++d) l += tmp[d] * mW2[(size_t)d * 8 + tid];
        lg[tid] = l;
    }
    __syncthreads();
    if (tid == 0) {
        float mx = lg[0];
        for (int e = 1; e < 8; ++e) mx = fmaxf(mx, lg[e]);
        float p[8], s = 0.f;
        for (int e = 0; e < 8; ++e) { p[e] = expf(lg[e] - mx); s += p[e]; }
        float inv = 1.f / s;
        for (int e = 0; e < 8; ++e) probsOut[(size_t)n * 8 + e] = p[e] * inv;
        int a0 = 0; float v0 = lg[0];
        for (int e = 1; e < 8; ++e) if (lg[e] > v0) { v0 = lg[e]; a0 = e; }
        int a1 = -1; float v1 = -1e30f;
        for (int e = 0; e < 8; ++e) if (e != a0 && lg[e] > v1) { v1 = lg[e]; a1 = e; }
        float e1 = expf(v1 - v0);
        float t0 = 1.f / (1.f + e1), t1 = e1 / (1.f + e1);
        idxOut[(size_t)n * 2 + 0] = (float)a0;
        idxOut[(size_t)n * 2 + 1] = (float)a1;
        for (int e = 0; e < 8; ++e) w[(size_t)n * 8 + e] = 0.f;
        w[(size_t)n * 8 + a0] = t0;
        w[(size_t)n * 8 + a1] = t1;
    }
}

__global__ __launch_bounds__(256)
void compact_k(const float* __restrict__ w, int* __restrict__ cnt,
               int* __restrict__ list)
{
    int n = blockIdx.x * 256 + threadIdx.x;
    if (n >= NTc) return;
    for (int e = 0; e < NEc; ++e)
        if (w[(size_t)n * 8 + e] > 0.f) {
            int p = atomicAdd(&cnt[e], 1);
            list[e * NTc + p] = n;
        }
}

// ---------------------------------------------------------------
// LN1 batched over experts (blockIdx.y): LN(x[list[i]] + PRJ[i]) -> H1[i]
__global__ __launch_bounds__(256)
void ln1_k(const float* __restrict__ x, const int* __restrict__ listB,
           const float* __restrict__ addB, const float* __restrict__ sB,
           const float* __restrict__ bB, float* __restrict__ outB,
           const int* __restrict__ cntB)
{
    int e = blockIdx.y;
    int i = blockIdx.x;
    if (i >= cntB[e]) return;
    const int* list = listB + e * NTc;
    const float* add = addB + (size_t)e * NTc * Ec;
    const float* s = sB + e * Ec;
    const float* b = bB + e * Ec;
    float* outRows = outB + (size_t)e * NTc * Ec;
    int tid = threadIdx.x;
    int g = list[i];
    float v0 = x[(size_t)g * Ec + tid] + add[(size_t)i * Ec + tid];
    float v1 = x[(size_t)g * Ec + 256 + tid] + add[(size_t)i * Ec + 256 + tid];
    __shared__ float red[256];
    __shared__ float bc;
    red[tid] = v0 + v1; __syncthreads();
    for (int st = 128; st > 0; st >>= 1) { if (tid < st) red[tid] += red[tid + st]; __syncthreads(); }
    if (tid == 0) bc = red[0] * (1.f / 512.f);
    __syncthreads();
    float mu = bc;
    float d0 = v0 - mu, d1 = v1 - mu;
    __syncthreads();
    red[tid] = d0 * d0 + d1 * d1; __syncthreads();
    for (int st = 128; st > 0; st >>= 1) { if (tid < st) red[tid] += red[tid + st]; __syncthreads(); }
    if (tid == 0) bc = rsqrtf(red[0] * (1.f / 512.f) + 1e-5f);
    __syncthreads();
    float inv = bc;
    outRows[(size_t)i * Ec + tid] = d0 * inv * s[tid] + b[tid];
    outRows[(size_t)i * Ec + 256 + tid] = d1 * inv * s[256 + tid] + b[256 + tid];
}

// LN2 batched over experts; atomic scatter (experts' token sets overlap)
__global__ __launch_bounds__(256)
void ln2_scatter_k(const float* __restrict__ H1B, const float* __restrict__ YB,
                   const float* __restrict__ sB, const float* __restrict__ bB,
                   float* __restrict__ out, const int* __restrict__ listB,
                   const int* __restrict__ cntB, const float* __restrict__ wB)
{
    int e = blockIdx.y;
    int i = blockIdx.x;
    if (i >= cntB[e]) return;
    const int* list = listB + e * NTc;
    const float* H1 = H1B + (size_t)e * NTc * Ec;
    const float* Y = YB + (size_t)e * NTc * Ec;
    const float* s = sB + e * Ec;
    const float* b = bB + e * Ec;
    const float* wvec = wB + e;
    int tid = threadIdx.x;
    int g = list[i];
    float v0 = H1[(size_t)i * Ec + tid] + Y[(size_t)i * Ec + tid];
    float v1 = H1[(size_t)i * Ec + 256 + tid] + Y[(size_t)i * Ec + 256 + tid];
    __shared__ float red[256];
    __shared__ float bc;
    red[tid] = v0 + v1; __syncthreads();
    for (int st = 128; st > 0; st >>= 1) { if (tid < st) red[tid] += red[tid + st]; __syncthreads(); }
    if (tid == 0) bc = red[0] * (1.f / 512.f);
    __syncthreads();
    float mu = bc;
    float d0 = v0 - mu, d1 = v1 - mu;
    __syncthreads();
    red[tid] = d0 * d0 + d1 * d1; __syncthreads();
    for (int st = 128; st > 0; st >>= 1) { if (tid < st) red[tid] += red[tid + st]; __syncthreads(); }
    if (tid == 0) bc = rsqrtf(red[0] * (1.f / 512.f) + 1e-5f);
    __syncthreads();
    float inv = bc;
    float wv = wvec[(size_t)g * 8];
    atomicAdd(&out[(size_t)g * Ec + tid], (d0 * inv * s[tid] + b[tid]) * wv);
    atomicAdd(&out[(size_t)g * Ec + 256 + tid], (d1 * inv * s[256 + tid] + b[256 + tid]) * wv);
}

// ---------------------------------------------------------------
extern "C" void kernel_launch(void* const* d_in, const int* in_sizes, int n_in,
                              void* d_out, int out_size, void* d_ws, size_t ws_size,
                              hipStream_t stream)
{
    const float* x    = (const float*)d_in[0];
    const float* rU   = (const float*)d_in[1];
    const float* rR   = (const float*)d_in[2];
    const float* rS   = (const float*)d_in[3];
    const float* Wtp  = (const float*)d_in[6];
    const float* btp  = (const float*)d_in[7];
    const float* Wq   = (const float*)d_in[8];
    const float* bq   = (const float*)d_in[9];
    const float* Wk   = (const float*)d_in[10];
    const float* bk   = (const float*)d_in[11];
    const float* Wv   = (const float*)d_in[12];
    const float* bv   = (const float*)d_in[13];
    const float* gWih = (const float*)d_in[14];
    const float* gbih = (const float*)d_in[15];
    const float* gWhh = (const float*)d_in[16];
    const float* gbhh = (const float*)d_in[17];
    const float* mW1  = (const float*)d_in[18];
    const float* mb1  = (const float*)d_in[19];
    const float* mW2  = (const float*)d_in[20];
    const float* mb2  = (const float*)d_in[21];
    const float* sWq  = (const float*)d_in[22];
    const float* sbq  = (const float*)d_in[23];
    const float* sWk  = (const float*)d_in[24];
    const float* sbk  = (const float*)d_in[25];
    const float* sWv  = (const float*)d_in[26];
    const float* sbv  = (const float*)d_in[27];
    const float* sWo  = (const float*)d_in[28];
    const float* sbo  = (const float*)d_in[29];
    const float* sln1s = (const float*)d_in[30];
    const float* sln1b = (const float*)d_in[31];
    const float* sW1  = (const float*)d_in[32];
    const float* sb1  = (const float*)d_in[33];
    const float* sW2  = (const float*)d_in[34];
    const float* sb2  = (const float*)d_in[35];
    const float* sln2s = (const float*)d_in[36];
    const float* sln2b = (const float*)d_in[37];
    const float* fW1  = (const float*)d_in[38];
    const float* fb1  = (const float*)d_in[39];
    const float* fW2  = (const float*)d_in[40];
    const float* fb2  = (const float*)d_in[41];

    float* out      = (float*)d_out;                 // [2048,512]
    float* probsOut = out + (size_t)NTc * Ec;        // [2048,8]
    float* idxOut   = probsOut + (size_t)NTc * NEc;  // [2048,2]

    // ---- workspace layout ----
    int*   cnt  = (int*)d_ws;                        // 64 ints
    int*   list = cnt + 64;                          // 8*2048
    float* w    = (float*)d_ws + 64 + NEc * NTc;     // [2048,8]
    __bf16* WB = (__bf16*)(w + NTc * NEc);
    // QKVO_T(e,i) : 8 x [512][512] bf16
    auto QKVO_T = [&](int e, int i) { return WB + ((size_t)(e * 4 + i)) * 262144; };
    __bf16* sW1T = WB + 8 * 262144;            // 2 x [2048][512]
    __bf16* sW2T = sW1T + 2 * 1048576;         // 2 x [512][2048]
    __bf16* fW1T = sW2T + 2 * 1048576;         // 3 x [2048][512] (rotating)
    __bf16* fW2T = fW1T + 3 * 1048576;         // 3 x [512][2048] (rotating)
    float* act = (float*)(fW2T + 3 * 1048576);
    float* QbB = act;                          // 2 x [2048][512]
    float* KbB = act + 2 * 1048576;            // 2 x
    float* VtB = act + 4 * 1048576;            // 2 x [512][2048] d-major
    float* AOB = act + 6 * 1048576;            // 2 x
    float* H1B = act + 8 * 1048576;            // 2 x
    float* PRJB = QbB;                         // alias (Qb dead after flash)
    float* YbB  = KbB;                         // alias (Kb dead after flash)
    __bf16* FF1syn = (__bf16*)VtB;             // 2 x [2048][2048] bf16 (Vt/AO dead)
    __bf16* FF1ffn = (__bf16*)act;             // 3 x [2048][2048] bf16 (FFN phase)
    // router region overlays act (dead before experts start)
    float* proc = act;                 // 2048*128
    float* q4   = act + 262144;
    float* ctx  = act + 393216;
    float* gi   = act + 524288;        // 16*128*384
    float* hs   = act + 1310720;       // 2048*128

    // ---- init ----
    zero_k<<<1024, 256, 0, stream>>>(out, cnt);

    // ---- router (fp32 — keeps top-2 idx bit-stable) ----
    gemm_k<<<dim3(32, 2), 256, 0, stream>>>(x, Ec, Wtp, Pc, btp, proc, Pc, NTc, Pc, Ec, 1);
    gemm_k<<<dim3(32, 1), 256, 0, stream>>>(proc, Pc, Wq, AKc, bq, q4, AKc, NTc, AKc, Pc, 0);
    router_ctx_k<<<512, 256, 0, stream>>>(q4, rR, rS, Wk, bk, Wv, bv, ctx);
    gi_k<<<3072, 256, 0, stream>>>(rU, ctx, gWih, gbih, gi);
    gru_scan_k<<<16, 768, 0, stream>>>(gi, gWhh, gbhh, hs);
    mlp_route_k<<<2048, 128, 0, stream>>>(proc, hs, mW1, mb1, mW2, mb2,
                                          probsOut, idxOut, w);
    compact_k<<<8, 256, 0, stream>>>(w, cnt, list);

    GJob JZ = {};

    // ---- synergy weight conversion (3 dispatches) ----
    {
        CJobs8 cq = {};
        for (int e = 0; e < 2; ++e) {
            cq.j[e * 4 + 0] = { sWq + (size_t)e * Ec * Ec, QKVO_T(e, 0) };
            cq.j[e * 4 + 1] = { sWk + (size_t)e * Ec * Ec, QKVO_T(e, 1) };
            cq.j[e * 4 + 2] = { sWv + (size_t)e * Ec * Ec, QKVO_T(e, 2) };
            cq.j[e * 4 + 3] = { sWo + (size_t)e * Ec * Ec, QKVO_T(e, 3) };
        }
        convT_k<<<dim3(16, 16, 8), 256, 0, stream>>>(cq, Ec, Ec);
        CJobs8 c1 = {};
        c1.j[0] = { sW1, sW1T };
        c1.j[1] = { sW1 + (size_t)Ec * Hc, sW1T + 1048576 };
        convT_k<<<dim3(64, 16, 2), 256, 0, stream>>>(c1, Ec, Hc);
        CJobs8 c2 = {};
        c2.j[0] = { sW2, sW2T };
        c2.j[1] = { sW2 + (size_t)Hc * Ec, sW2T + 1048576 };
        convT_k<<<dim3(16, 64, 2), 256, 0, stream>>>(c2, Hc, Ec);
    }

    // ---- QKV for both experts: one 6-job dispatch ----
    {
        GJobs6 js = {};
        for (int e = 0; e < 2; ++e) {
            GJob jq = JZ;
            jq.A = x; jq.Mptr = cnt + e; jq.gatherA = list + e * NTc;
            jq.B = QKVO_T(e, 0); jq.bias = sbq + e * Ec;
            jq.C = QbB + (size_t)e * NTc * Ec; jq.ldc = Ec; jq.flags = 0;
            GJob jk = jq; jk.B = QKVO_T(e, 1); jk.bias = sbk + e * Ec;
            jk.C = KbB + (size_t)e * NTc * Ec;
            GJob jv = jq; jv.B = QKVO_T(e, 2); jv.bias = sbv + e * Ec;
            jv.C = VtB + (size_t)e * NTc * Ec; jv.ldc = NTc; jv.flags = 2;
            js.j[e * 3 + 0] = jq; js.j[e * 3 + 1] = jk; js.j[e * 3 + 2] = jv;
        }
        gemm_batch_k<0><<<dim3(16, 4, 6), 256, 0, stream>>>(js, Ec, Ec, Ec, Ec);
    }

    // ---- flash attention, both experts ----
    flash_k<<<dim3(32, 4, 2), 256, 0, stream>>>(QbB, KbB, VtB, AOB, cnt);

    // ---- Wo projection, both experts ----
    {
        GJobs6 js = {};
        for (int e = 0; e < 2; ++e) {
            GJob jo = JZ;
            jo.A = AOB + (size_t)e * NTc * Ec; jo.Mptr = cnt + e;
            jo.B = QKVO_T(e, 3); jo.bias = sbo + e * Ec;
            jo.C = PRJB + (size_t)e * NTc * Ec; jo.ldc = Ec;
            js.j[e] = jo;
        }
        gemm_batch_k<0><<<dim3(16, 4, 2), 256, 0, stream>>>(js, Ec, Ec, Ec, Ec);
    }

    // ---- LN1, both experts ----
    ln1_k<<<dim3(2048, 2), 256, 0, stream>>>(x, list, PRJB, sln1s, sln1b, H1B, cnt);

    // ---- FF1 (relu, bf16 out), both experts ----
    {
        GJobs6 js = {};
        for (int e = 0; e < 2; ++e) {
            GJob j1 = JZ;
            j1.A = H1B + (size_t)e * NTc * Ec; j1.Mptr = cnt + e;
            j1.B = sW1T + (size_t)e * 1048576; j1.bias = sb1 + (size_t)e * Hc;
            j1.C = FF1syn + (size_t)e * NTc * Hc; j1.ldc = Hc; j1.flags = 1 | 4;
            js.j[e] = j1;
        }
        gemm_batch_k<0><<<dim3(16, 16, 2), 256, 0, stream>>>(js, Ec, Ec, Hc, Ec);
    }

    // ---- FF2 (bf16 A), both experts ----
    {
        GJobs6 js = {};
        for (int e = 0; e < 2; ++e) {
            GJob j2 = JZ;
            j2.A = FF1syn + (size_t)e * NTc * Hc; j2.Mptr = cnt + e;
            j2.B = sW2T + (size_t)e * 1048576; j2.bias = sb2 + (size_t)e * Ec;
            j2.C = YbB + (size_t)e * NTc * Ec; j2.ldc = Ec;
            js.j[e] = j2;
        }
        gemm_batch_k<1><<<dim3(16, 4, 2), 256, 0, stream>>>(js, Hc, Hc, Ec, Hc);
    }

    // ---- LN2 + weighted scatter (atomic), both experts ----
    ln2_scatter_k<<<dim3(2048, 2), 256, 0, stream>>>(H1B, YbB, sln2s, sln2b,
                                                     out, list, cnt, w);

    // ---- FFN experts: 2 rounds of 3, batched ----
    for (int rnd = 0; rnd < 2; ++rnd) {
        int f0 = rnd * 3;
        {
            CJobs8 a = {};
            for (int u = 0; u < 3; ++u)
                a.j[u] = { fW1 + (size_t)(f0 + u) * Ec * Hc, fW1T + (size_t)u * 1048576 };
            convT_k<<<dim3(64, 16, 3), 256, 0, stream>>>(a, Ec, Hc);
            CJobs8 b = {};
            for (int u = 0; u < 3; ++u)
                b.j[u] = { fW2 + (size_t)(f0 + u) * Hc * Ec, fW2T + (size_t)u * 1048576 };
            convT_k<<<dim3(16, 64, 3), 256, 0, stream>>>(b, Hc, Ec);
        }
        {
            GJobs6 js = {};
            for (int u = 0; u < 3; ++u) {
                int f = f0 + u, e = f + NSc;
                GJob j1 = JZ;
                j1.A = x; j1.Mptr = cnt + e; j1.gatherA = list + e * NTc;
                j1.B = fW1T + (size_t)u * 1048576; j1.bias = fb1 + (size_t)f * Hc;
                j1.C = FF1ffn + (size_t)u * NTc * Hc; j1.ldc = Hc; j1.flags = 1 | 4;
                js.j[u] = j1;
            }
            gemm_batch_k<0><<<dim3(16, 16, 3), 256, 0, stream>>>(js, Ec, Ec, Hc, Ec);
        }
        {
            GJobs6 js = {};
            for (int u = 0; u < 3; ++u) {
                int f = f0 + u, e = f + NSc;
                GJob j2 = JZ;
                j2.A = FF1ffn + (size_t)u * NTc * Hc; j2.Mptr = cnt + e;
                j2.B = fW2T + (size_t)u * 1048576; j2.bias = fb2 + (size_t)f * Ec;
                j2.scatterOut = out; j2.scatterList = list + e * NTc;
                j2.wvec = w + e; j2.ldc = Ec;
                js.j[u] = j2;
            }
            gemm_batch_k<1><<<dim3(16, 4, 3), 256, 0, stream>>>(js, Hc, Hc, Ec, Hc);
        }
    }
}

// Round 6
// 1039.312 us; speedup vs baseline: 6.1749x; 1.0396x over previous
//
#include <hip/hip_runtime.h>
#include <math.h>

// ---------- constants ----------
#define Bc 4
#define Mc 4
#define Tc 128
#define Ec 512
#define Hc 2048
#define NEc 8
#define NSc 2
#define NHEADc 4
#define Pc 128
#define GRUHc 128
#define AKc 64
#define AVc 64
#define NTc 2048        // B*S
#define HDc 128         // E/NHEAD

typedef __bf16 bfv8 __attribute__((ext_vector_type(8)));
typedef float f32x4 __attribute__((ext_vector_type(4)));
typedef float f32v16 __attribute__((ext_vector_type(16)));

// ---------------------------------------------------------------
__global__ __launch_bounds__(256)
void zero_k(float* __restrict__ out, int* __restrict__ cnt)
{
    int i = blockIdx.x * 256 + threadIdx.x;
    float4* o4 = (float4*)out;
    if (i < (NTc * Ec) / 4) o4[i] = make_float4(0.f, 0.f, 0.f, 0.f);
    if (i < NEc) cnt[i] = 0;
}

// ---------------------------------------------------------------
// batched tiled transpose + fp32->bf16 convert: W[K,N] -> Wt[N,K]
struct CJob { const float* src; __bf16* dst; };
struct CJobs8 { CJob j[8]; };

__global__ __launch_bounds__(256)
void convT_k(CJobs8 jobs, int K, int N)
{
    CJob J = jobs.j[blockIdx.z];
    __shared__ float t[32][33];
    int bx = blockIdx.x * 32;   // n tile
    int by = blockIdx.y * 32;   // k tile
    int tx = threadIdx.x & 31, ty = threadIdx.x >> 5;   // 32 x 8
#pragma unroll
    for (int i = 0; i < 4; ++i) {
        int k = by + ty + i * 8, n = bx + tx;
        t[ty + i * 8][tx] = (k < K && n < N) ? J.src[(size_t)k * N + n] : 0.f;
    }
    __syncthreads();
#pragma unroll
    for (int i = 0; i < 4; ++i) {
        int n = bx + ty + i * 8, k = by + tx;
        if (n < N && k < K) J.dst[(size_t)n * K + k] = (__bf16)t[tx][ty + i * 8];
    }
}

// ---------------------------------------------------------------
// fp32 tiled GEMM (router only — keeps top-2 routing bit-stable)
__global__ __launch_bounds__(256)
void gemm_k(const float* __restrict__ A, int lda,
            const float* __restrict__ B, int ldb,
            const float* __restrict__ bias,
            float* __restrict__ C, int ldc,
            int M, int N, int K, int relu)
{
    int tm = blockIdx.x * 64, tn = blockIdx.y * 64;
    if (tm >= M || tn >= N) return;
    __shared__ float As[16][68];
    __shared__ float Bs[16][68];
    int tid = threadIdx.x;
    int tx = tid & 15, ty = tid >> 4;
    float acc[4][4] = {};
    int arow = tid >> 2;
    int ak0  = (tid & 3) * 4;
    int bk   = tid >> 4;
    int bc0  = (tid & 15) * 4;
    int grA = tm + arow;
    const float* Arow = (grA < M) ? (A + (size_t)grA * lda) : nullptr;

    for (int k0 = 0; k0 < K; k0 += 16) {
#pragma unroll
        for (int u = 0; u < 4; ++u) {
            int k = k0 + ak0 + u;
            As[ak0 + u][arow] = (Arow && k < K) ? Arow[k] : 0.f;
        }
        int kb = k0 + bk;
#pragma unroll
        for (int u = 0; u < 4; ++u) {
            int n2 = tn + bc0 + u;
            Bs[bk][bc0 + u] = (kb < K && n2 < N) ? B[(size_t)kb * ldb + n2] : 0.f;
        }
        __syncthreads();
#pragma unroll
        for (int kk = 0; kk < 16; ++kk) {
            float a0 = As[kk][ty * 4 + 0], a1 = As[kk][ty * 4 + 1];
            float a2 = As[kk][ty * 4 + 2], a3 = As[kk][ty * 4 + 3];
            float b0 = Bs[kk][tx * 4 + 0], b1 = Bs[kk][tx * 4 + 1];
            float b2 = Bs[kk][tx * 4 + 2], b3 = Bs[kk][tx * 4 + 3];
            acc[0][0] += a0 * b0; acc[0][1] += a0 * b1; acc[0][2] += a0 * b2; acc[0][3] += a0 * b3;
            acc[1][0] += a1 * b0; acc[1][1] += a1 * b1; acc[1][2] += a1 * b2; acc[1][3] += a1 * b3;
            acc[2][0] += a2 * b0; acc[2][1] += a2 * b1; acc[2][2] += a2 * b2; acc[2][3] += a2 * b3;
            acc[3][0] += a3 * b0; acc[3][1] += a3 * b1; acc[3][2] += a3 * b2; acc[3][3] += a3 * b3;
        }
        __syncthreads();
    }
#pragma unroll
    for (int i = 0; i < 4; ++i) {
        int gr = tm + ty * 4 + i;
        if (gr >= M) continue;
#pragma unroll
        for (int j = 0; j < 4; ++j) {
            int gc = tn + tx * 4 + j;
            if (gc >= N) continue;
            float v = acc[i][j] + (bias ? bias[gc] : 0.f);
            if (relu) v = fmaxf(v, 0.f);
            C[(size_t)gr * ldc + gc] = v;
        }
    }
}

// ---------------------------------------------------------------
// batched bf16 MFMA GEMM (see r5 notes). flags: 1=relu, 2=storeT, 4=storeBf.
struct GJob {
    const void* A;
    const void* B;
    const float* bias;
    void* C;
    const int* Mptr;
    const int* gatherA;
    float* scatterOut;
    const int* scatterList;
    const float* wvec;
    int ldc;
    int flags;
};
struct GJobs6 { GJob j[6]; };

#define LDA_S 40   // LDS row stride in bf16 elems (32 + 8 pad)
template<int AMODE>
__global__ __launch_bounds__(256)
void gemm_batch_k(GJobs6 jobs, int lda, int ldb, int N, int K)
{
    GJob J = jobs.j[blockIdx.z];
    int M = *J.Mptr;
    int tm = blockIdx.x * 128, tn = blockIdx.y * 128;
    if (tm >= M || tn >= N) return;

    __shared__ __bf16 As[128 * LDA_S];
    __shared__ __bf16 Bs[128 * LDA_S];
    int tid = threadIdx.x, lane = tid & 63, wvi = tid >> 6;
    int wm = (wvi & 1) * 64, wn = (wvi >> 1) * 64;
    f32x4 acc[4][4] = {};

    int ar = tid >> 1, ah = (tid & 1) * 16;   // staging row / k-half
    const float*  Apf = nullptr;
    const __bf16* Apb = nullptr;
    if (tm + ar < M) {
        int g = J.gatherA ? J.gatherA[tm + ar] : (tm + ar);
        if (AMODE == 0) Apf = (const float*)J.A + (size_t)g * lda;
        else            Apb = (const __bf16*)J.A + (size_t)g * lda;
    }
    const __bf16* Bp = ((tn + ar) < N) ? ((const __bf16*)J.B + (size_t)(tn + ar) * ldb)
                                       : nullptr;

    float fa[16];
    bfv8 ra0, ra1, rb0, rb1;

    auto LOADA = [&](int k0) {
        int kb = k0 + ah;
        if (AMODE == 0) {
            if (Apf) {
                const float4* p = (const float4*)(Apf + kb);
                float4 x0 = p[0], x1 = p[1], x2 = p[2], x3 = p[3];
                fa[0]=x0.x; fa[1]=x0.y; fa[2]=x0.z; fa[3]=x0.w;
                fa[4]=x1.x; fa[5]=x1.y; fa[6]=x1.z; fa[7]=x1.w;
                fa[8]=x2.x; fa[9]=x2.y; fa[10]=x2.z; fa[11]=x2.w;
                fa[12]=x3.x; fa[13]=x3.y; fa[14]=x3.z; fa[15]=x3.w;
            } else {
#pragma unroll
                for (int i = 0; i < 16; ++i) fa[i] = 0.f;
            }
        } else {
            if (Apb) {
                ra0 = *(const bfv8*)(Apb + kb);
                ra1 = *(const bfv8*)(Apb + kb + 8);
            } else {
#pragma unroll
                for (int i = 0; i < 8; ++i) { ra0[i] = (__bf16)0.f; ra1[i] = (__bf16)0.f; }
            }
        }
    };
    auto LOADB = [&](int k0) {
        int kb = k0 + ah;
        if (Bp) {
            rb0 = *(const bfv8*)(Bp + kb);
            rb1 = *(const bfv8*)(Bp + kb + 8);
        } else {
#pragma unroll
            for (int i = 0; i < 8; ++i) { rb0[i] = (__bf16)0.f; rb1[i] = (__bf16)0.f; }
        }
    };

    int KT = K / 32;
    LOADA(0);
    LOADB(0);

    for (int kt = 0; kt < KT; ++kt) {
        __syncthreads();
        if (AMODE == 0) {
            bfv8 p0, p1;
#pragma unroll
            for (int i = 0; i < 8; ++i) { p0[i] = (__bf16)fa[i]; p1[i] = (__bf16)fa[8 + i]; }
            *(bfv8*)(As + ar * LDA_S + ah) = p0;
            *(bfv8*)(As + ar * LDA_S + ah + 8) = p1;
        } else {
            *(bfv8*)(As + ar * LDA_S + ah) = ra0;
            *(bfv8*)(As + ar * LDA_S + ah + 8) = ra1;
        }
        *(bfv8*)(Bs + ar * LDA_S + ah) = rb0;
        *(bfv8*)(Bs + ar * LDA_S + ah + 8) = rb1;
        __syncthreads();
        if (kt + 1 < KT) {
            LOADA((kt + 1) * 32);
            LOADB((kt + 1) * 32);
        }
        {
            int fr = lane & 15, quad = lane >> 4;
            bfv8 af[4], bfr[4];
            const __bf16* Ab = As + quad * 8 + fr * LDA_S;
            const __bf16* Bb2 = Bs + quad * 8 + fr * LDA_S;
#pragma unroll
            for (int t2 = 0; t2 < 4; ++t2) {
                af[t2]  = *(const bfv8*)(Ab + (wm + t2 * 16) * LDA_S);
                bfr[t2] = *(const bfv8*)(Bb2 + (wn + t2 * 16) * LDA_S);
            }
#pragma unroll
            for (int i = 0; i < 4; ++i)
#pragma unroll
                for (int j = 0; j < 4; ++j)
                    acc[i][j] = __builtin_amdgcn_mfma_f32_16x16x32_bf16(af[i], bfr[j], acc[i][j], 0, 0, 0);
        }
    }

    // epilogue: C layout col=lane&15, row=(lane>>4)*4+reg
    int col = lane & 15, rq = (lane >> 4) * 4;
    int relu = J.flags & 1, storeT = J.flags & 2, storeBf = J.flags & 4;
#pragma unroll
    for (int ti = 0; ti < 4; ++ti) {
#pragma unroll
        for (int tj = 0; tj < 4; ++tj) {
#pragma unroll
            for (int r = 0; r < 4; ++r) {
                int gm = tm + wm + ti * 16 + rq + r;
                int gn = tn + wn + tj * 16 + col;
                if (gm < M && gn < N) {
                    float v = acc[ti][tj][r] + (J.bias ? J.bias[gn] : 0.f);
                    if (relu) v = fmaxf(v, 0.f);
                    if (J.scatterOut) {
                        int g = J.scatterList[gm];
                        atomicAdd(&J.scatterOut[(size_t)g * Ec + gn], v * J.wvec[(size_t)g * NEc]);
                    } else if (storeT) {
                        ((float*)J.C)[(size_t)gn * J.ldc + gm] = v;
                    } else if (storeBf) {
                        ((__bf16*)J.C)[(size_t)gm * J.ldc + gn] = (__bf16)v;
                    } else {
                        ((float*)J.C)[(size_t)gm * J.ldc + gn] = v;
                    }
                }
            }
        }
    }
}

// ---------------------------------------------------------------
// Flash attention over compacted tokens, batched over experts (blockIdx.z).
__global__ __launch_bounds__(256)
void flash_k(const float* __restrict__ QbB, const float* __restrict__ KbB,
             const float* __restrict__ VtB, float* __restrict__ AOB,
             const int* __restrict__ cntB)
{
    int e = blockIdx.z;
    const float* Qb = QbB + (size_t)e * NTc * Ec;
    const float* Kb = KbB + (size_t)e * NTc * Ec;
    const float* Vt = VtB + (size_t)e * NTc * Ec;
    float* AO = AOB + (size_t)e * NTc * Ec;
    int nv = cntB[e];
    int r0 = blockIdx.x * 64;
    if (r0 >= nv) return;
    int h = blockIdx.y;
    const int QS = 136, VS = 72;
    __shared__ __bf16 Ql[64 * 136];
    __shared__ __bf16 Kl[64 * 136];
    __shared__ __bf16 Vl[128 * 72];
    __shared__ __bf16 Pl[64 * 72];
    int tid = threadIdx.x, lane = tid & 63, wv = tid >> 6;
    int fr = lane & 15, quad = lane >> 4;

    {   // load Q tile (rows >= nv -> 0)
        int qr = tid >> 2, c0 = (tid & 3) * 32;
        const float* src = Qb + (size_t)(r0 + qr) * Ec + h * HDc + c0;
        __bf16* dst = Ql + qr * QS + c0;
        bool ok = (r0 + qr) < nv;
#pragma unroll
        for (int u = 0; u < 8; ++u) {
            float4 v = ok ? ((const float4*)src)[u] : make_float4(0.f, 0.f, 0.f, 0.f);
            dst[u*4+0] = (__bf16)v.x; dst[u*4+1] = (__bf16)v.y;
            dst[u*4+2] = (__bf16)v.z; dst[u*4+3] = (__bf16)v.w;
        }
    }

    f32x4 accO[8];
#pragma unroll
    for (int j = 0; j < 8; ++j) accO[j] = (f32x4){0.f, 0.f, 0.f, 0.f};
    float mrow[4] = {-1e30f, -1e30f, -1e30f, -1e30f};
    float lrow[4] = {0.f, 0.f, 0.f, 0.f};
    const float invsq = 0.08838834764831845f;   // 1/sqrt(128)

    for (int j0 = 0; j0 < nv; j0 += 64) {
        __syncthreads();
        {   // K tile
            int kr = tid >> 2, c0 = (tid & 3) * 32;
            const float* src = Kb + (size_t)(j0 + kr) * Ec + h * HDc + c0;
            __bf16* dst = Kl + kr * QS + c0;
            bool ok = (j0 + kr) < nv;
#pragma unroll
            for (int u = 0; u < 8; ++u) {
                float4 v = ok ? ((const float4*)src)[u] : make_float4(0.f, 0.f, 0.f, 0.f);
                dst[u*4+0] = (__bf16)v.x; dst[u*4+1] = (__bf16)v.y;
                dst[u*4+2] = (__bf16)v.z; dst[u*4+3] = (__bf16)v.w;
            }
        }
        {   // Vt tile (d-major)
            int dr = tid >> 1, c0 = (tid & 1) * 32;
            const float* src = Vt + (size_t)(h * HDc + dr) * NTc + j0 + c0;
            __bf16* dst = Vl + dr * VS + c0;
            int rem = nv - (j0 + c0);
            if (rem >= 32) {
#pragma unroll
                for (int u = 0; u < 8; ++u) {
                    float4 v = ((const float4*)src)[u];
                    dst[u*4+0] = (__bf16)v.x; dst[u*4+1] = (__bf16)v.y;
                    dst[u*4+2] = (__bf16)v.z; dst[u*4+3] = (__bf16)v.w;
                }
            } else {
                for (int u = 0; u < 32; ++u)
                    dst[u] = (u < rem) ? (__bf16)src[u] : (__bf16)0.f;
            }
        }
        __syncthreads();

        // S = Q K^T (wave owns rows wv*16..+16)
        f32x4 sc[4] = {};
#pragma unroll
        for (int ks = 0; ks < 4; ++ks) {
            bfv8 aq = *(const bfv8*)(Ql + (wv * 16 + fr) * QS + ks * 32 + quad * 8);
#pragma unroll
            for (int tj = 0; tj < 4; ++tj) {
                bfv8 bk8 = *(const bfv8*)(Kl + (tj * 16 + fr) * QS + ks * 32 + quad * 8);
                sc[tj] = __builtin_amdgcn_mfma_f32_16x16x32_bf16(aq, bk8, sc[tj], 0, 0, 0);
            }
        }

        float alpha[4];
#pragma unroll
        for (int r = 0; r < 4; ++r) {
            float sv[4];
            float mx = -1e30f;
#pragma unroll
            for (int tj = 0; tj < 4; ++tj) {
                float s = sc[tj][r] * invsq;
                bool valid = (j0 + tj * 16 + fr) < nv;
                s = valid ? s : -1e30f;
                sv[tj] = s;
                mx = fmaxf(mx, s);
            }
#pragma unroll
            for (int off = 1; off < 16; off <<= 1)
                mx = fmaxf(mx, __shfl_xor(mx, off, 64));
            float mn = fmaxf(mrow[r], mx);
            alpha[r] = expf(mrow[r] - mn);
            float ps = 0.f;
#pragma unroll
            for (int tj = 0; tj < 4; ++tj) {
                bool valid = (j0 + tj * 16 + fr) < nv;
                float p = valid ? expf(sv[tj] - mn) : 0.f;
                Pl[(wv * 16 + quad * 4 + r) * VS + tj * 16 + fr] = (__bf16)p;
                ps += p;
            }
#pragma unroll
            for (int off = 1; off < 16; off <<= 1)
                ps += __shfl_xor(ps, off, 64);
            lrow[r] = lrow[r] * alpha[r] + ps;
            mrow[r] = mn;
        }
#pragma unroll
        for (int tj = 0; tj < 8; ++tj)
#pragma unroll
            for (int r = 0; r < 4; ++r)
                accO[tj][r] *= alpha[r];
        // PV (P per-wave LDS region -> A frag; within-wave, no barrier)
#pragma unroll
        for (int ks = 0; ks < 2; ++ks) {
            bfv8 ap = *(const bfv8*)(Pl + (wv * 16 + fr) * VS + ks * 32 + quad * 8);
#pragma unroll
            for (int tj = 0; tj < 8; ++tj) {
                bfv8 bv8 = *(const bfv8*)(Vl + (tj * 16 + fr) * VS + ks * 32 + quad * 8);
                accO[tj] = __builtin_amdgcn_mfma_f32_16x16x32_bf16(ap, bv8, accO[tj], 0, 0, 0);
            }
        }
    }

#pragma unroll
    for (int r = 0; r < 4; ++r) {
        int row = r0 + wv * 16 + quad * 4 + r;
        if (row < nv) {
            float invl = 1.f / lrow[r];
#pragma unroll
            for (int tj = 0; tj < 8; ++tj)
                AO[(size_t)row * Ec + h * HDc + tj * 16 + fr] = accO[tj][r] * invl;
        }
    }
}

// ---------------------------------------------------------------
__global__ __launch_bounds__(256)
void router_ctx_k(const float* __restrict__ q4, const float* __restrict__ rR,
                  const float* __restrict__ rS,
                  const float* __restrict__ Wk, const float* __restrict__ bk,
                  const float* __restrict__ Wv, const float* __restrict__ bv,
                  float* __restrict__ ctx)
{
    int tid = threadIdx.x;
    int lane = tid & 63;
    int n = blockIdx.x * 4 + (tid >> 6);
    int m = (n >> 7) & 3, t = n & 127, b = n >> 9;
    float q = q4[(size_t)n * AKc + lane];
    float sc[3], rv[3], sv[3];
#pragma unroll
    for (int o = 0; o < 3; ++o) {
        int oth = o + (o >= m ? 1 : 0);
        float r = rR[(((size_t)(b * Mc + m)) * Mc + oth) * Tc + t];
        float s_ = rS[(((size_t)(b * Mc + m)) * Mc + oth) * Tc + t];
        rv[o] = r; sv[o] = s_;
        float key = r * Wk[lane] + s_ * Wk[64 + lane] + bk[lane];
        float p = q * key;
#pragma unroll
        for (int off = 32; off; off >>= 1) p += __shfl_xor(p, off, 64);
        sc[o] = p * 0.125f;
    }
    float mx = fmaxf(sc[0], fmaxf(sc[1], sc[2]));
    float e0 = expf(sc[0] - mx), e1 = expf(sc[1] - mx), e2 = expf(sc[2] - mx);
    float inv = 1.f / (e0 + e1 + e2);
    float p0 = e0 * inv, p1 = e1 * inv, p2 = e2 * inv;
    float v0 = rv[0] * Wv[lane] + sv[0] * Wv[64 + lane] + bv[lane];
    float v1 = rv[1] * Wv[lane] + sv[1] * Wv[64 + lane] + bv[lane];
    float v2 = rv[2] * Wv[lane] + sv[2] * Wv[64 + lane] + bv[lane];
    ctx[(size_t)n * AVc + lane] = p0 * v0 + p1 * v1 + p2 * v2;
}

// ---------------------------------------------------------------
__global__ __launch_bounds__(256)
void gi_k(const float* __restrict__ rU, const float* __restrict__ ctx,
          const float* __restrict__ gWih, const float* __restrict__ gbih,
          float* __restrict__ gi)
{
    int idx = blockIdx.x * 256 + threadIdx.x;   // < 2048*384
    int g = idx % 384, nt = idx / 384;
    const float* Wr = gWih + (size_t)g * 65;
    float a = gbih[g] + rU[nt] * Wr[0];
    const float* c = ctx + (size_t)nt * AVc;
#pragma unroll
    for (int d = 0; d < 64; ++d) a += c[d] * Wr[1 + d];
    gi[(size_t)nt * 384 + g] = a;
}

// ---------------------------------------------------------------
// GRU scan. One block per sequence (16 blocks), 384 threads, one output
// row g per thread. The 128 weights live in EIGHT NAMED ext_vector_type(16)
// variables — no alloca, so SROA/regalloc cannot demote them (r4/r5 showed
// float arrays of 64/128 elems get spilled: VGPR_Count 116/52). gi row for
// step t+1 is prefetched during step t's matvec.
__global__ __launch_bounds__(384, 1)
void gru_scan_k(const float* __restrict__ gi, const float* __restrict__ gWhh,
                const float* __restrict__ gbhh, float* __restrict__ hs)
{
    int seq = blockIdx.x, g = threadIdx.x;
    __shared__ float h[128];
    __shared__ float gh[384];
    const f32v16* wp = (const f32v16*)(gWhh + (size_t)g * 128);
    f32v16 w0 = wp[0], w1 = wp[1], w2 = wp[2], w3 = wp[3];
    f32v16 w4 = wp[4], w5 = wp[5], w6 = wp[6], w7 = wp[7];
    float bh = gbhh[g];
    if (g < 128) h[g] = 0.f;
    // preload gi row for t=0
    float g0 = 0.f, g1 = 0.f, g2 = 0.f;
    if (g < 128) {
        const float* gr = gi + (size_t)seq * 128 * 384;
        g0 = gr[g]; g1 = gr[128 + g]; g2 = gr[256 + g];
    }
    __syncthreads();
    for (int t = 0; t < 128; ++t) {
        float a0 = 0.f, a1 = 0.f, a2 = 0.f, a3 = 0.f;
#define GRU_STEP16(W, B) { \
        float4 x0 = *(const float4*)&h[B];      float4 x1 = *(const float4*)&h[(B) + 4]; \
        float4 x2 = *(const float4*)&h[(B) + 8]; float4 x3 = *(const float4*)&h[(B) + 12]; \
        a0 += x0.x * W[0];  a1 += x0.y * W[1];  a2 += x0.z * W[2];  a3 += x0.w * W[3]; \
        a0 += x1.x * W[4];  a1 += x1.y * W[5];  a2 += x1.z * W[6];  a3 += x1.w * W[7]; \
        a0 += x2.x * W[8];  a1 += x2.y * W[9];  a2 += x2.z * W[10]; a3 += x2.w * W[11]; \
        a0 += x3.x * W[12]; a1 += x3.y * W[13]; a2 += x3.z * W[14]; a3 += x3.w * W[15]; }
        GRU_STEP16(w0, 0)   GRU_STEP16(w1, 16)  GRU_STEP16(w2, 32)  GRU_STEP16(w3, 48)
        GRU_STEP16(w4, 64)  GRU_STEP16(w5, 80)  GRU_STEP16(w6, 96)  GRU_STEP16(w7, 112)
#undef GRU_STEP16
        gh[g] = bh + (a0 + a1) + (a2 + a3);
        __syncthreads();
        if (g < 128) {
            float r = 1.f / (1.f + expf(-(g0 + gh[g])));
            float z = 1.f / (1.f + expf(-(g1 + gh[128 + g])));
            float nn = tanhf(g2 + r * gh[256 + g]);
            float hn = (1.f - z) * nn + z * h[g];
            hs[((size_t)seq * 128 + t) * 128 + g] = hn;
            h[g] = hn;
            // prefetch gi row t+1 (result needed only after next barrier+matvec)
            if (t + 1 < 128) {
                const float* gr = gi + ((size_t)seq * 128 + t + 1) * 384;
                g0 = gr[g]; g1 = gr[128 + g]; g2 = gr[256 + g];
            }
        }
        __syncthreads();
    }
}

// ---------------------------------------------------------------
__global__ __launch_bounds__(128)
void mlp_route_k(const float* __restrict__ proc, const float* __restrict__ hs,
                 const float* __restrict__ mW1, const float* __restrict__ mb1,
                 const float* __restrict__ mW2, const float* __restrict__ mb2,
                 float* __restrict__ probsOut, float* __restrict__ idxOut,
                 float* __restrict__ w)
{
    int n = blockIdx.x, tid = threadIdx.x;
    __shared__ float comb[256], tmp[128], lg[8];
    comb[tid] = proc[(size_t)n * 128 + tid];
    comb[128 + tid] = hs[(size_t)n * 128 + tid];
    __syncthreads();
    float a = mb1[tid];
#pragma unroll 8
    for (int d = 0; d < 256; ++d) a += comb[d] * mW1[(size_t)d * 128 + tid];
    tmp[tid] = fmaxf(a, 0.f);
    __syncthreads();
    if (tid < 8) {
        float l = mb2[tid];
        for (int d = 0; d < 128; ++d) l += tmp[d] * mW2[(size_t)d * 8 + tid];
        lg[tid] = l;
    }
    __syncthreads();
    if (tid == 0) {
        float mx = lg[0];
        for (int e = 1; e < 8; ++e) mx = fmaxf(mx, lg[e]);
        float p[8], s = 0.f;
        for (int e = 0; e < 8; ++e) { p[e] = expf(lg[e] - mx); s += p[e]; }
        float inv = 1.f / s;
        for (int e = 0; e < 8; ++e) probsOut[(size_t)n * 8 + e] = p[e] * inv;
        int a0 = 0; float v0 = lg[0];
        for (int e = 1; e < 8; ++e) if (lg[e] > v0) { v0 = lg[e]; a0 = e; }
        int a1 = -1; float v1 = -1e30f;
        for (int e = 0; e < 8; ++e) if (e != a0 && lg[e] > v1) { v1 = lg[e]; a1 = e; }
        float e1 = expf(v1 - v0);
        float t0 = 1.f / (1.f + e1), t1 = e1 / (1.f + e1);
        idxOut[(size_t)n * 2 + 0] = (float)a0;
        idxOut[(size_t)n * 2 + 1] = (float)a1;
        for (int e = 0; e < 8; ++e) w[(size_t)n * 8 + e] = 0.f;
        w[(size_t)n * 8 + a0] = t0;
        w[(size_t)n * 8 + a1] = t1;
    }
}

__global__ __launch_bounds__(256)
void compact_k(const float* __restrict__ w, int* __restrict__ cnt,
               int* __restrict__ list)
{
    int n = blockIdx.x * 256 + threadIdx.x;
    if (n >= NTc) return;
    for (int e = 0; e < NEc; ++e)
        if (w[(size_t)n * 8 + e] > 0.f) {
            int p = atomicAdd(&cnt[e], 1);
            list[e * NTc + p] = n;
        }
}

// ---------------------------------------------------------------
// LN1 batched over experts (blockIdx.y): LN(x[list[i]] + PRJ[i]) -> H1[i]
__global__ __launch_bounds__(256)
void ln1_k(const float* __restrict__ x, const int* __restrict__ listB,
           const float* __restrict__ addB, const float* __restrict__ sB,
           const float* __restrict__ bB, float* __restrict__ outB,
           const int* __restrict__ cntB)
{
    int e = blockIdx.y;
    int i = blockIdx.x;
    if (i >= cntB[e]) return;
    const int* list = listB + e * NTc;
    const float* add = addB + (size_t)e * NTc * Ec;
    const float* s = sB + e * Ec;
    const float* b = bB + e * Ec;
    float* outRows = outB + (size_t)e * NTc * Ec;
    int tid = threadIdx.x;
    int g = list[i];
    float v0 = x[(size_t)g * Ec + tid] + add[(size_t)i * Ec + tid];
    float v1 = x[(size_t)g * Ec + 256 + tid] + add[(size_t)i * Ec + 256 + tid];
    __shared__ float red[256];
    __shared__ float bc;
    red[tid] = v0 + v1; __syncthreads();
    for (int st = 128; st > 0; st >>= 1) { if (tid < st) red[tid] += red[tid + st]; __syncthreads(); }
    if (tid == 0) bc = red[0] * (1.f / 512.f);
    __syncthreads();
    float mu = bc;
    float d0 = v0 - mu, d1 = v1 - mu;
    __syncthreads();
    red[tid] = d0 * d0 + d1 * d1; __syncthreads();
    for (int st = 128; st > 0; st >>= 1) { if (tid < st) red[tid] += red[tid + st]; __syncthreads(); }
    if (tid == 0) bc = rsqrtf(red[0] * (1.f / 512.f) + 1e-5f);
    __syncthreads();
    float inv = bc;
    outRows[(size_t)i * Ec + tid] = d0 * inv * s[tid] + b[tid];
    outRows[(size_t)i * Ec + 256 + tid] = d1 * inv * s[256 + tid] + b[256 + tid];
}

// LN2 batched over experts; atomic scatter (experts' token sets overlap)
__global__ __launch_bounds__(256)
void ln2_scatter_k(const float* __restrict__ H1B, const float* __restrict__ YB,
                   const float* __restrict__ sB, const float* __restrict__ bB,
                   float* __restrict__ out, const int* __restrict__ listB,
                   const int* __restrict__ cntB, const float* __restrict__ wB)
{
    int e = blockIdx.y;
    int i = blockIdx.x;
    if (i >= cntB[e]) return;
    const int* list = listB + e * NTc;
    const float* H1 = H1B + (size_t)e * NTc * Ec;
    const float* Y = YB + (size_t)e * NTc * Ec;
    const float* s = sB + e * Ec;
    const float* b = bB + e * Ec;
    const float* wvec = wB + e;
    int tid = threadIdx.x;
    int g = list[i];
    float v0 = H1[(size_t)i * Ec + tid] + Y[(size_t)i * Ec + tid];
    float v1 = H1[(size_t)i * Ec + 256 + tid] + Y[(size_t)i * Ec + 256 + tid];
    __shared__ float red[256];
    __shared__ float bc;
    red[tid] = v0 + v1; __syncthreads();
    for (int st = 128; st > 0; st >>= 1) { if (tid < st) red[tid] += red[tid + st]; __syncthreads(); }
    if (tid == 0) bc = red[0] * (1.f / 512.f);
    __syncthreads();
    float mu = bc;
    float d0 = v0 - mu, d1 = v1 - mu;
    __syncthreads();
    red[tid] = d0 * d0 + d1 * d1; __syncthreads();
    for (int st = 128; st > 0; st >>= 1) { if (tid < st) red[tid] += red[tid + st]; __syncthreads(); }
    if (tid == 0) bc = rsqrtf(red[0] * (1.f / 512.f) + 1e-5f);
    __syncthreads();
    float inv = bc;
    float wv = wvec[(size_t)g * 8];
    atomicAdd(&out[(size_t)g * Ec + tid], (d0 * inv * s[tid] + b[tid]) * wv);
    atomicAdd(&out[(size_t)g * Ec + 256 + tid], (d1 * inv * s[256 + tid] + b[256 + tid]) * wv);
}

// ---------------------------------------------------------------
extern "C" void kernel_launch(void* const* d_in, const int* in_sizes, int n_in,
                              void* d_out, int out_size, void* d_ws, size_t ws_size,
                              hipStream_t stream)
{
    const float* x    = (const float*)d_in[0];
    const float* rU   = (const float*)d_in[1];
    const float* rR   = (const float*)d_in[2];
    const float* rS   = (const float*)d_in[3];
    const float* Wtp  = (const float*)d_in[6];
    const float* btp  = (const float*)d_in[7];
    const float* Wq   = (const float*)d_in[8];
    const float* bq   = (const float*)d_in[9];
    const float* Wk   = (const float*)d_in[10];
    const float* bk   = (const float*)d_in[11];
    const float* Wv   = (const float*)d_in[12];
    const float* bv   = (const float*)d_in[13];
    const float* gWih = (const float*)d_in[14];
    const float* gbih = (const float*)d_in[15];
    const float* gWhh = (const float*)d_in[16];
    const float* gbhh = (const float*)d_in[17];
    const float* mW1  = (const float*)d_in[18];
    const float* mb1  = (const float*)d_in[19];
    const float* mW2  = (const float*)d_in[20];
    const float* mb2  = (const float*)d_in[21];
    const float* sWq  = (const float*)d_in[22];
    const float* sbq  = (const float*)d_in[23];
    const float* sWk  = (const float*)d_in[24];
    const float* sbk  = (const float*)d_in[25];
    const float* sWv  = (const float*)d_in[26];
    const float* sbv  = (const float*)d_in[27];
    const float* sWo  = (const float*)d_in[28];
    const float* sbo  = (const float*)d_in[29];
    const float* sln1s = (const float*)d_in[30];
    const float* sln1b = (const float*)d_in[31];
    const float* sW1  = (const float*)d_in[32];
    const float* sb1  = (const float*)d_in[33];
    const float* sW2  = (const float*)d_in[34];
    const float* sb2  = (const float*)d_in[35];
    const float* sln2s = (const float*)d_in[36];
    const float* sln2b = (const float*)d_in[37];
    const float* fW1  = (const float*)d_in[38];
    const float* fb1  = (const float*)d_in[39];
    const float* fW2  = (const float*)d_in[40];
    const float* fb2  = (const float*)d_in[41];

    float* out      = (float*)d_out;                 // [2048,512]
    float* probsOut = out + (size_t)NTc * Ec;        // [2048,8]
    float* idxOut   = probsOut + (size_t)NTc * NEc;  // [2048,2]

    // ---- workspace layout ----
    int*   cnt  = (int*)d_ws;                        // 64 ints
    int*   list = cnt + 64;                          // 8*2048
    float* w    = (float*)d_ws + 64 + NEc * NTc;     // [2048,8]
    __bf16* WB = (__bf16*)(w + NTc * NEc);
    auto QKVO_T = [&](int e, int i) { return WB + ((size_t)(e * 4 + i)) * 262144; };
    __bf16* sW1T = WB + 8 * 262144;            // 2 x [2048][512]
    __bf16* sW2T = sW1T + 2 * 1048576;         // 2 x [512][2048]
    __bf16* fW1T = sW2T + 2 * 1048576;         // 3 x [2048][512] (rotating)
    __bf16* fW2T = fW1T + 3 * 1048576;         // 3 x [512][2048] (rotating)
    float* act = (float*)(fW2T + 3 * 1048576);
    float* QbB = act;                          // 2 x [2048][512]
    float* KbB = act + 2 * 1048576;            // 2 x
    float* VtB = act + 4 * 1048576;            // 2 x [512][2048] d-major
    float* AOB = act + 6 * 1048576;            // 2 x
    float* H1B = act + 8 * 1048576;            // 2 x
    float* PRJB = QbB;                         // alias (Qb dead after flash)
    float* YbB  = KbB;                         // alias (Kb dead after flash)
    __bf16* FF1syn = (__bf16*)VtB;             // 2 x [2048][2048] bf16 (Vt/AO dead)
    __bf16* FF1ffn = (__bf16*)act;             // 3 x [2048][2048] bf16 (FFN phase)
    // router region overlays act (dead before experts start)
    float* proc = act;                 // 2048*128
    float* q4   = act + 262144;
    float* ctx  = act + 393216;
    float* gi   = act + 524288;        // 16*128*384
    float* hs   = act + 1310720;       // 2048*128

    // ---- init ----
    zero_k<<<1024, 256, 0, stream>>>(out, cnt);

    // ---- router (fp32 — keeps top-2 idx bit-stable) ----
    gemm_k<<<dim3(32, 2), 256, 0, stream>>>(x, Ec, Wtp, Pc, btp, proc, Pc, NTc, Pc, Ec, 1);
    gemm_k<<<dim3(32, 1), 256, 0, stream>>>(proc, Pc, Wq, AKc, bq, q4, AKc, NTc, AKc, Pc, 0);
    router_ctx_k<<<512, 256, 0, stream>>>(q4, rR, rS, Wk, bk, Wv, bv, ctx);
    gi_k<<<3072, 256, 0, stream>>>(rU, ctx, gWih, gbih, gi);
    gru_scan_k<<<16, 384, 0, stream>>>(gi, gWhh, gbhh, hs);
    mlp_route_k<<<2048, 128, 0, stream>>>(proc, hs, mW1, mb1, mW2, mb2,
                                          probsOut, idxOut, w);
    compact_k<<<8, 256, 0, stream>>>(w, cnt, list);

    GJob JZ = {};

    // ---- synergy weight conversion (3 dispatches) ----
    {
        CJobs8 cq = {};
        for (int e = 0; e < 2; ++e) {
            cq.j[e * 4 + 0] = { sWq + (size_t)e * Ec * Ec, QKVO_T(e, 0) };
            cq.j[e * 4 + 1] = { sWk + (size_t)e * Ec * Ec, QKVO_T(e, 1) };
            cq.j[e * 4 + 2] = { sWv + (size_t)e * Ec * Ec, QKVO_T(e, 2) };
            cq.j[e * 4 + 3] = { sWo + (size_t)e * Ec * Ec, QKVO_T(e, 3) };
        }
        convT_k<<<dim3(16, 16, 8), 256, 0, stream>>>(cq, Ec, Ec);
        CJobs8 c1 = {};
        c1.j[0] = { sW1, sW1T };
        c1.j[1] = { sW1 + (size_t)Ec * Hc, sW1T + 1048576 };
        convT_k<<<dim3(64, 16, 2), 256, 0, stream>>>(c1, Ec, Hc);
        CJobs8 c2 = {};
        c2.j[0] = { sW2, sW2T };
        c2.j[1] = { sW2 + (size_t)Hc * Ec, sW2T + 1048576 };
        convT_k<<<dim3(16, 64, 2), 256, 0, stream>>>(c2, Hc, Ec);
    }

    // ---- QKV for both experts: one 6-job dispatch ----
    {
        GJobs6 js = {};
        for (int e = 0; e < 2; ++e) {
            GJob jq = JZ;
            jq.A = x; jq.Mptr = cnt + e; jq.gatherA = list + e * NTc;
            jq.B = QKVO_T(e, 0); jq.bias = sbq + e * Ec;
            jq.C = QbB + (size_t)e * NTc * Ec; jq.ldc = Ec; jq.flags = 0;
            GJob jk = jq; jk.B = QKVO_T(e, 1); jk.bias = sbk + e * Ec;
            jk.C = KbB + (size_t)e * NTc * Ec;
            GJob jv = jq; jv.B = QKVO_T(e, 2); jv.bias = sbv + e * Ec;
            jv.C = VtB + (size_t)e * NTc * Ec; jv.ldc = NTc; jv.flags = 2;
            js.j[e * 3 + 0] = jq; js.j[e * 3 + 1] = jk; js.j[e * 3 + 2] = jv;
        }
        gemm_batch_k<0><<<dim3(16, 4, 6), 256, 0, stream>>>(js, Ec, Ec, Ec, Ec);
    }

    // ---- flash attention, both experts ----
    flash_k<<<dim3(32, 4, 2), 256, 0, stream>>>(QbB, KbB, VtB, AOB, cnt);

    // ---- Wo projection, both experts ----
    {
        GJobs6 js = {};
        for (int e = 0; e < 2; ++e) {
            GJob jo = JZ;
            jo.A = AOB + (size_t)e * NTc * Ec; jo.Mptr = cnt + e;
            jo.B = QKVO_T(e, 3); jo.bias = sbo + e * Ec;
            jo.C = PRJB + (size_t)e * NTc * Ec; jo.ldc = Ec;
            js.j[e] = jo;
        }
        gemm_batch_k<0><<<dim3(16, 4, 2), 256, 0, stream>>>(js, Ec, Ec, Ec, Ec);
    }

    // ---- LN1, both experts ----
    ln1_k<<<dim3(2048, 2), 256, 0, stream>>>(x, list, PRJB, sln1s, sln1b, H1B, cnt);

    // ---- FF1 (relu, bf16 out), both experts ----
    {
        GJobs6 js = {};
        for (int e = 0; e < 2; ++e) {
            GJob j1 = JZ;
            j1.A = H1B + (size_t)e * NTc * Ec; j1.Mptr = cnt + e;
            j1.B = sW1T + (size_t)e * 1048576; j1.bias = sb1 + (size_t)e * Hc;
            j1.C = FF1syn + (size_t)e * NTc * Hc; j1.ldc = Hc; j1.flags = 1 | 4;
            js.j[e] = j1;
        }
        gemm_batch_k<0><<<dim3(16, 16, 2), 256, 0, stream>>>(js, Ec, Ec, Hc, Ec);
    }

    // ---- FF2 (bf16 A), both experts ----
    {
        GJobs6 js = {};
        for (int e = 0; e < 2; ++e) {
            GJob j2 = JZ;
            j2.A = FF1syn + (size_t)e * NTc * Hc; j2.Mptr = cnt + e;
            j2.B = sW2T + (size_t)e * 1048576; j2.bias = sb2 + (size_t)e * Ec;
            j2.C = YbB + (size_t)e * NTc * Ec; j2.ldc = Ec;
            js.j[e] = j2;
        }
        gemm_batch_k<1><<<dim3(16, 4, 2), 256, 0, stream>>>(js, Hc, Hc, Ec, Hc);
    }

    // ---- LN2 + weighted scatter (atomic), both experts ----
    ln2_scatter_k<<<dim3(2048, 2), 256, 0, stream>>>(H1B, YbB, sln2s, sln2b,
                                                     out, list, cnt, w);

    // ---- FFN experts: 2 rounds of 3, batched ----
    for (int rnd = 0; rnd < 2; ++rnd) {
        int f0 = rnd * 3;
        {
            CJobs8 a = {};
            for (int u = 0; u < 3; ++u)
                a.j[u] = { fW1 + (size_t)(f0 + u) * Ec * Hc, fW1T + (size_t)u * 1048576 };
            convT_k<<<dim3(64, 16, 3), 256, 0, stream>>>(a, Ec, Hc);
            CJobs8 b = {};
            for (int u = 0; u < 3; ++u)
                b.j[u] = { fW2 + (size_t)(f0 + u) * Hc * Ec, fW2T + (size_t)u * 1048576 };
            convT_k<<<dim3(16, 64, 3), 256, 0, stream>>>(b, Hc, Ec);
        }
        {
            GJobs6 js = {};
            for (int u = 0; u < 3; ++u) {
                int f = f0 + u, e = f + NSc;
                GJob j1 = JZ;
                j1.A = x; j1.Mptr = cnt + e; j1.gatherA = list + e * NTc;
                j1.B = fW1T + (size_t)u * 1048576; j1.bias = fb1 + (size_t)f * Hc;
                j1.C = FF1ffn + (size_t)u * NTc * Hc; j1.ldc = Hc; j1.flags = 1 | 4;
                js.j[u] = j1;
            }
            gemm_batch_k<0><<<dim3(16, 16, 3), 256, 0, stream>>>(js, Ec, Ec, Hc, Ec);
        }
        {
            GJobs6 js = {};
            for (int u = 0; u < 3; ++u) {
                int f = f0 + u, e = f + NSc;
                GJob j2 = JZ;
                j2.A = FF1ffn + (size_t)u * NTc * Hc; j2.Mptr = cnt + e;
                j2.B = fW2T + (size_t)u * 1048576; j2.bias = fb2 + (size_t)f * Ec;
                j2.scatterOut = out; j2.scatterList = list + e * NTc;
                j2.wvec = w + e; j2.ldc = Ec;
                js.j[u] = j2;
            }
            gemm_batch_k<1><<<dim3(16, 4, 3), 256, 0, stream>>>(js, Hc, Hc, Ec, Hc);
        }
    }
}

// Round 7
// 985.641 us; speedup vs baseline: 6.5111x; 1.0545x over previous
//
#include <hip/hip_runtime.h>
#include <math.h>

// ---------- constants ----------
#define Bc 4
#define Mc 4
#define Tc 128
#define Ec 512
#define Hc 2048
#define NEc 8
#define NSc 2
#define NHEADc 4
#define Pc 128
#define GRUHc 128
#define AKc 64
#define AVc 64
#define NTc 2048        // B*S
#define HDc 128         // E/NHEAD

typedef __bf16 bfv8 __attribute__((ext_vector_type(8)));
typedef float f32x4 __attribute__((ext_vector_type(4)));
typedef float f32v16 __attribute__((ext_vector_type(16)));

// ---------------------------------------------------------------
__global__ __launch_bounds__(256)
void zero_k(float* __restrict__ out, int* __restrict__ cnt)
{
    int i = blockIdx.x * 256 + threadIdx.x;
    float4* o4 = (float4*)out;
    if (i < (NTc * Ec) / 4) o4[i] = make_float4(0.f, 0.f, 0.f, 0.f);
    if (i < NEc) cnt[i] = 0;
}

// ---------------------------------------------------------------
// batched tiled transpose + fp32->bf16 convert: W[K,N] -> Wt[N,K]
struct CJob { const float* src; __bf16* dst; };
struct CJobs8 { CJob j[8]; };

__global__ __launch_bounds__(256)
void convT_k(CJobs8 jobs, int K, int N)
{
    CJob J = jobs.j[blockIdx.z];
    __shared__ float t[32][33];
    int bx = blockIdx.x * 32;   // n tile
    int by = blockIdx.y * 32;   // k tile
    int tx = threadIdx.x & 31, ty = threadIdx.x >> 5;   // 32 x 8
#pragma unroll
    for (int i = 0; i < 4; ++i) {
        int k = by + ty + i * 8, n = bx + tx;
        t[ty + i * 8][tx] = (k < K && n < N) ? J.src[(size_t)k * N + n] : 0.f;
    }
    __syncthreads();
#pragma unroll
    for (int i = 0; i < 4; ++i) {
        int n = bx + ty + i * 8, k = by + tx;
        if (n < N && k < K) J.dst[(size_t)n * K + k] = (__bf16)t[tx][ty + i * 8];
    }
}

// ---------------------------------------------------------------
// fp32 tiled GEMM (router only — keeps top-2 routing bit-stable)
__global__ __launch_bounds__(256)
void gemm_k(const float* __restrict__ A, int lda,
            const float* __restrict__ B, int ldb,
            const float* __restrict__ bias,
            float* __restrict__ C, int ldc,
            int M, int N, int K, int relu)
{
    int tm = blockIdx.x * 64, tn = blockIdx.y * 64;
    if (tm >= M || tn >= N) return;
    __shared__ float As[16][68];
    __shared__ float Bs[16][68];
    int tid = threadIdx.x;
    int tx = tid & 15, ty = tid >> 4;
    float acc[4][4] = {};
    int arow = tid >> 2;
    int ak0  = (tid & 3) * 4;
    int bk   = tid >> 4;
    int bc0  = (tid & 15) * 4;
    int grA = tm + arow;
    const float* Arow = (grA < M) ? (A + (size_t)grA * lda) : nullptr;

    for (int k0 = 0; k0 < K; k0 += 16) {
#pragma unroll
        for (int u = 0; u < 4; ++u) {
            int k = k0 + ak0 + u;
            As[ak0 + u][arow] = (Arow && k < K) ? Arow[k] : 0.f;
        }
        int kb = k0 + bk;
#pragma unroll
        for (int u = 0; u < 4; ++u) {
            int n2 = tn + bc0 + u;
            Bs[bk][bc0 + u] = (kb < K && n2 < N) ? B[(size_t)kb * ldb + n2] : 0.f;
        }
        __syncthreads();
#pragma unroll
        for (int kk = 0; kk < 16; ++kk) {
            float a0 = As[kk][ty * 4 + 0], a1 = As[kk][ty * 4 + 1];
            float a2 = As[kk][ty * 4 + 2], a3 = As[kk][ty * 4 + 3];
            float b0 = Bs[kk][tx * 4 + 0], b1 = Bs[kk][tx * 4 + 1];
            float b2 = Bs[kk][tx * 4 + 2], b3 = Bs[kk][tx * 4 + 3];
            acc[0][0] += a0 * b0; acc[0][1] += a0 * b1; acc[0][2] += a0 * b2; acc[0][3] += a0 * b3;
            acc[1][0] += a1 * b0; acc[1][1] += a1 * b1; acc[1][2] += a1 * b2; acc[1][3] += a1 * b3;
            acc[2][0] += a2 * b0; acc[2][1] += a2 * b1; acc[2][2] += a2 * b2; acc[2][3] += a2 * b3;
            acc[3][0] += a3 * b0; acc[3][1] += a3 * b1; acc[3][2] += a3 * b2; acc[3][3] += a3 * b3;
        }
        __syncthreads();
    }
#pragma unroll
    for (int i = 0; i < 4; ++i) {
        int gr = tm + ty * 4 + i;
        if (gr >= M) continue;
#pragma unroll
        for (int j = 0; j < 4; ++j) {
            int gc = tn + tx * 4 + j;
            if (gc >= N) continue;
            float v = acc[i][j] + (bias ? bias[gc] : 0.f);
            if (relu) v = fmaxf(v, 0.f);
            C[(size_t)gr * ldc + gc] = v;
        }
    }
}

// ---------------------------------------------------------------
// batched bf16 MFMA GEMM with optional split-K.
// blockIdx.y encodes (ko, ny): ny = by % nTilesY, ko = by / nTilesY.
// Each chunk covers kIters BK=32 tiles. Bias applied only by ko==0
// (correct when split-K used with atomic-scatter epilogue).
// flags: 1=relu, 2=storeT, 4=storeBf.
struct GJob {
    const void* A;
    const void* B;
    const float* bias;
    void* C;
    const int* Mptr;
    const int* gatherA;
    float* scatterOut;
    const int* scatterList;
    const float* wvec;
    int ldc;
    int flags;
};
struct GJobs6 { GJob j[6]; };

#define LDA_S 40   // LDS row stride in bf16 elems (32 + 8 pad)
template<int AMODE>
__global__ __launch_bounds__(256)
void gemm_batch_k(GJobs6 jobs, int lda, int ldb, int N, int K,
                  int nTilesY, int kIters)
{
    GJob J = jobs.j[blockIdx.z];
    int M = *J.Mptr;
    int by = blockIdx.y;
    int ny = by % nTilesY, ko = by / nTilesY;
    int tm = blockIdx.x * 128, tn = ny * 128;
    if (tm >= M || tn >= N) return;
    int KT = K / 32;
    int kt0 = ko * kIters;
    int ktE = kt0 + kIters; if (ktE > KT) ktE = KT;
    if (kt0 >= KT) return;

    __shared__ __bf16 As[128 * LDA_S];
    __shared__ __bf16 Bs[128 * LDA_S];
    int tid = threadIdx.x, lane = tid & 63, wvi = tid >> 6;
    int wm = (wvi & 1) * 64, wn = (wvi >> 1) * 64;
    f32x4 acc[4][4] = {};

    int ar = tid >> 1, ah = (tid & 1) * 16;   // staging row / k-half
    const float*  Apf = nullptr;
    const __bf16* Apb = nullptr;
    if (tm + ar < M) {
        int g = J.gatherA ? J.gatherA[tm + ar] : (tm + ar);
        if (AMODE == 0) Apf = (const float*)J.A + (size_t)g * lda;
        else            Apb = (const __bf16*)J.A + (size_t)g * lda;
    }
    const __bf16* Bp = ((tn + ar) < N) ? ((const __bf16*)J.B + (size_t)(tn + ar) * ldb)
                                       : nullptr;

    float fa[16];
    bfv8 ra0, ra1, rb0, rb1;

    auto LOADA = [&](int k0) {
        int kb = k0 + ah;
        if (AMODE == 0) {
            if (Apf) {
                const float4* p = (const float4*)(Apf + kb);
                float4 x0 = p[0], x1 = p[1], x2 = p[2], x3 = p[3];
                fa[0]=x0.x; fa[1]=x0.y; fa[2]=x0.z; fa[3]=x0.w;
                fa[4]=x1.x; fa[5]=x1.y; fa[6]=x1.z; fa[7]=x1.w;
                fa[8]=x2.x; fa[9]=x2.y; fa[10]=x2.z; fa[11]=x2.w;
                fa[12]=x3.x; fa[13]=x3.y; fa[14]=x3.z; fa[15]=x3.w;
            } else {
#pragma unroll
                for (int i = 0; i < 16; ++i) fa[i] = 0.f;
            }
        } else {
            if (Apb) {
                ra0 = *(const bfv8*)(Apb + kb);
                ra1 = *(const bfv8*)(Apb + kb + 8);
            } else {
#pragma unroll
                for (int i = 0; i < 8; ++i) { ra0[i] = (__bf16)0.f; ra1[i] = (__bf16)0.f; }
            }
        }
    };
    auto LOADB = [&](int k0) {
        int kb = k0 + ah;
        if (Bp) {
            rb0 = *(const bfv8*)(Bp + kb);
            rb1 = *(const bfv8*)(Bp + kb + 8);
        } else {
#pragma unroll
            for (int i = 0; i < 8; ++i) { rb0[i] = (__bf16)0.f; rb1[i] = (__bf16)0.f; }
        }
    };

    LOADA(kt0 * 32);
    LOADB(kt0 * 32);

    for (int kt = kt0; kt < ktE; ++kt) {
        __syncthreads();
        if (AMODE == 0) {
            bfv8 p0, p1;
#pragma unroll
            for (int i = 0; i < 8; ++i) { p0[i] = (__bf16)fa[i]; p1[i] = (__bf16)fa[8 + i]; }
            *(bfv8*)(As + ar * LDA_S + ah) = p0;
            *(bfv8*)(As + ar * LDA_S + ah + 8) = p1;
        } else {
            *(bfv8*)(As + ar * LDA_S + ah) = ra0;
            *(bfv8*)(As + ar * LDA_S + ah + 8) = ra1;
        }
        *(bfv8*)(Bs + ar * LDA_S + ah) = rb0;
        *(bfv8*)(Bs + ar * LDA_S + ah + 8) = rb1;
        __syncthreads();
        if (kt + 1 < ktE) {
            LOADA((kt + 1) * 32);
            LOADB((kt + 1) * 32);
        }
        {
            int fr = lane & 15, quad = lane >> 4;
            bfv8 af[4], bfr[4];
            const __bf16* Ab = As + quad * 8 + fr * LDA_S;
            const __bf16* Bb2 = Bs + quad * 8 + fr * LDA_S;
#pragma unroll
            for (int t2 = 0; t2 < 4; ++t2) {
                af[t2]  = *(const bfv8*)(Ab + (wm + t2 * 16) * LDA_S);
                bfr[t2] = *(const bfv8*)(Bb2 + (wn + t2 * 16) * LDA_S);
            }
#pragma unroll
            for (int i = 0; i < 4; ++i)
#pragma unroll
                for (int j = 0; j < 4; ++j)
                    acc[i][j] = __builtin_amdgcn_mfma_f32_16x16x32_bf16(af[i], bfr[j], acc[i][j], 0, 0, 0);
        }
    }

    // epilogue: C layout col=lane&15, row=(lane>>4)*4+reg
    int col = lane & 15, rq = (lane >> 4) * 4;
    int relu = J.flags & 1, storeT = J.flags & 2, storeBf = J.flags & 4;
    int addBias = (J.bias != nullptr) && (ko == 0);
#pragma unroll
    for (int ti = 0; ti < 4; ++ti) {
#pragma unroll
        for (int tj = 0; tj < 4; ++tj) {
#pragma unroll
            for (int r = 0; r < 4; ++r) {
                int gm = tm + wm + ti * 16 + rq + r;
                int gn = tn + wn + tj * 16 + col;
                if (gm < M && gn < N) {
                    float v = acc[ti][tj][r] + (addBias ? J.bias[gn] : 0.f);
                    if (relu) v = fmaxf(v, 0.f);
                    if (J.scatterOut) {
                        int g = J.scatterList[gm];
                        atomicAdd(&J.scatterOut[(size_t)g * Ec + gn], v * J.wvec[(size_t)g * NEc]);
                    } else if (storeT) {
                        ((float*)J.C)[(size_t)gn * J.ldc + gm] = v;
                    } else if (storeBf) {
                        ((__bf16*)J.C)[(size_t)gm * J.ldc + gn] = (__bf16)v;
                    } else {
                        ((float*)J.C)[(size_t)gm * J.ldc + gn] = v;
                    }
                }
            }
        }
    }
}

// ---------------------------------------------------------------
// Flash attention over compacted tokens, batched over experts (blockIdx.z).
__global__ __launch_bounds__(256)
void flash_k(const float* __restrict__ QbB, const float* __restrict__ KbB,
             const float* __restrict__ VtB, float* __restrict__ AOB,
             const int* __restrict__ cntB)
{
    int e = blockIdx.z;
    const float* Qb = QbB + (size_t)e * NTc * Ec;
    const float* Kb = KbB + (size_t)e * NTc * Ec;
    const float* Vt = VtB + (size_t)e * NTc * Ec;
    float* AO = AOB + (size_t)e * NTc * Ec;
    int nv = cntB[e];
    int r0 = blockIdx.x * 64;
    if (r0 >= nv) return;
    int h = blockIdx.y;
    const int QS = 136, VS = 72;
    __shared__ __bf16 Ql[64 * 136];
    __shared__ __bf16 Kl[64 * 136];
    __shared__ __bf16 Vl[128 * 72];
    __shared__ __bf16 Pl[64 * 72];
    int tid = threadIdx.x, lane = tid & 63, wv = tid >> 6;
    int fr = lane & 15, quad = lane >> 4;

    {   // load Q tile (rows >= nv -> 0)
        int qr = tid >> 2, c0 = (tid & 3) * 32;
        const float* src = Qb + (size_t)(r0 + qr) * Ec + h * HDc + c0;
        __bf16* dst = Ql + qr * QS + c0;
        bool ok = (r0 + qr) < nv;
#pragma unroll
        for (int u = 0; u < 8; ++u) {
            float4 v = ok ? ((const float4*)src)[u] : make_float4(0.f, 0.f, 0.f, 0.f);
            dst[u*4+0] = (__bf16)v.x; dst[u*4+1] = (__bf16)v.y;
            dst[u*4+2] = (__bf16)v.z; dst[u*4+3] = (__bf16)v.w;
        }
    }

    f32x4 accO[8];
#pragma unroll
    for (int j = 0; j < 8; ++j) accO[j] = (f32x4){0.f, 0.f, 0.f, 0.f};
    float mrow[4] = {-1e30f, -1e30f, -1e30f, -1e30f};
    float lrow[4] = {0.f, 0.f, 0.f, 0.f};
    const float invsq = 0.08838834764831845f;   // 1/sqrt(128)

    for (int j0 = 0; j0 < nv; j0 += 64) {
        __syncthreads();
        {   // K tile
            int kr = tid >> 2, c0 = (tid & 3) * 32;
            const float* src = Kb + (size_t)(j0 + kr) * Ec + h * HDc + c0;
            __bf16* dst = Kl + kr * QS + c0;
            bool ok = (j0 + kr) < nv;
#pragma unroll
            for (int u = 0; u < 8; ++u) {
                float4 v = ok ? ((const float4*)src)[u] : make_float4(0.f, 0.f, 0.f, 0.f);
                dst[u*4+0] = (__bf16)v.x; dst[u*4+1] = (__bf16)v.y;
                dst[u*4+2] = (__bf16)v.z; dst[u*4+3] = (__bf16)v.w;
            }
        }
        {   // Vt tile (d-major)
            int dr = tid >> 1, c0 = (tid & 1) * 32;
            const float* src = Vt + (size_t)(h * HDc + dr) * NTc + j0 + c0;
            __bf16* dst = Vl + dr * VS + c0;
            int rem = nv - (j0 + c0);
            if (rem >= 32) {
#pragma unroll
                for (int u = 0; u < 8; ++u) {
                    float4 v = ((const float4*)src)[u];
                    dst[u*4+0] = (__bf16)v.x; dst[u*4+1] = (__bf16)v.y;
                    dst[u*4+2] = (__bf16)v.z; dst[u*4+3] = (__bf16)v.w;
                }
            } else {
                for (int u = 0; u < 32; ++u)
                    dst[u] = (u < rem) ? (__bf16)src[u] : (__bf16)0.f;
            }
        }
        __syncthreads();

        // S = Q K^T (wave owns rows wv*16..+16)
        f32x4 sc[4] = {};
#pragma unroll
        for (int ks = 0; ks < 4; ++ks) {
            bfv8 aq = *(const bfv8*)(Ql + (wv * 16 + fr) * QS + ks * 32 + quad * 8);
#pragma unroll
            for (int tj = 0; tj < 4; ++tj) {
                bfv8 bk8 = *(const bfv8*)(Kl + (tj * 16 + fr) * QS + ks * 32 + quad * 8);
                sc[tj] = __builtin_amdgcn_mfma_f32_16x16x32_bf16(aq, bk8, sc[tj], 0, 0, 0);
            }
        }

        float alpha[4];
#pragma unroll
        for (int r = 0; r < 4; ++r) {
            float sv[4];
            float mx = -1e30f;
#pragma unroll
            for (int tj = 0; tj < 4; ++tj) {
                float s = sc[tj][r] * invsq;
                bool valid = (j0 + tj * 16 + fr) < nv;
                s = valid ? s : -1e30f;
                sv[tj] = s;
                mx = fmaxf(mx, s);
            }
#pragma unroll
            for (int off = 1; off < 16; off <<= 1)
                mx = fmaxf(mx, __shfl_xor(mx, off, 64));
            float mn = fmaxf(mrow[r], mx);
            alpha[r] = expf(mrow[r] - mn);
            float ps = 0.f;
#pragma unroll
            for (int tj = 0; tj < 4; ++tj) {
                bool valid = (j0 + tj * 16 + fr) < nv;
                float p = valid ? expf(sv[tj] - mn) : 0.f;
                Pl[(wv * 16 + quad * 4 + r) * VS + tj * 16 + fr] = (__bf16)p;
                ps += p;
            }
#pragma unroll
            for (int off = 1; off < 16; off <<= 1)
                ps += __shfl_xor(ps, off, 64);
            lrow[r] = lrow[r] * alpha[r] + ps;
            mrow[r] = mn;
        }
#pragma unroll
        for (int tj = 0; tj < 8; ++tj)
#pragma unroll
            for (int r = 0; r < 4; ++r)
                accO[tj][r] *= alpha[r];
        // PV (P per-wave LDS region -> A frag; within-wave, no barrier)
#pragma unroll
        for (int ks = 0; ks < 2; ++ks) {
            bfv8 ap = *(const bfv8*)(Pl + (wv * 16 + fr) * VS + ks * 32 + quad * 8);
#pragma unroll
            for (int tj = 0; tj < 8; ++tj) {
                bfv8 bv8 = *(const bfv8*)(Vl + (tj * 16 + fr) * VS + ks * 32 + quad * 8);
                accO[tj] = __builtin_amdgcn_mfma_f32_16x16x32_bf16(ap, bv8, accO[tj], 0, 0, 0);
            }
        }
    }

#pragma unroll
    for (int r = 0; r < 4; ++r) {
        int row = r0 + wv * 16 + quad * 4 + r;
        if (row < nv) {
            float invl = 1.f / lrow[r];
#pragma unroll
            for (int tj = 0; tj < 8; ++tj)
                AO[(size_t)row * Ec + h * HDc + tj * 16 + fr] = accO[tj][r] * invl;
        }
    }
}

// ---------------------------------------------------------------
__global__ __launch_bounds__(256)
void router_ctx_k(const float* __restrict__ q4, const float* __restrict__ rR,
                  const float* __restrict__ rS,
                  const float* __restrict__ Wk, const float* __restrict__ bk,
                  const float* __restrict__ Wv, const float* __restrict__ bv,
                  float* __restrict__ ctx)
{
    int tid = threadIdx.x;
    int lane = tid & 63;
    int n = blockIdx.x * 4 + (tid >> 6);
    int m = (n >> 7) & 3, t = n & 127, b = n >> 9;
    float q = q4[(size_t)n * AKc + lane];
    float sc[3], rv[3], sv[3];
#pragma unroll
    for (int o = 0; o < 3; ++o) {
        int oth = o + (o >= m ? 1 : 0);
        float r = rR[(((size_t)(b * Mc + m)) * Mc + oth) * Tc + t];
        float s_ = rS[(((size_t)(b * Mc + m)) * Mc + oth) * Tc + t];
        rv[o] = r; sv[o] = s_;
        float key = r * Wk[lane] + s_ * Wk[64 + lane] + bk[lane];
        float p = q * key;
#pragma unroll
        for (int off = 32; off; off >>= 1) p += __shfl_xor(p, off, 64);
        sc[o] = p * 0.125f;
    }
    float mx = fmaxf(sc[0], fmaxf(sc[1], sc[2]));
    float e0 = expf(sc[0] - mx), e1 = expf(sc[1] - mx), e2 = expf(sc[2] - mx);
    float inv = 1.f / (e0 + e1 + e2);
    float p0 = e0 * inv, p1 = e1 * inv, p2 = e2 * inv;
    float v0 = rv[0] * Wv[lane] + sv[0] * Wv[64 + lane] + bv[lane];
    float v1 = rv[1] * Wv[lane] + sv[1] * Wv[64 + lane] + bv[lane];
    float v2 = rv[2] * Wv[lane] + sv[2] * Wv[64 + lane] + bv[lane];
    ctx[(size_t)n * AVc + lane] = p0 * v0 + p1 * v1 + p2 * v2;
}

// ---------------------------------------------------------------
__global__ __launch_bounds__(256)
void gi_k(const float* __restrict__ rU, const float* __restrict__ ctx,
          const float* __restrict__ gWih, const float* __restrict__ gbih,
          float* __restrict__ gi)
{
    int idx = blockIdx.x * 256 + threadIdx.x;   // < 2048*384
    int g = idx % 384, nt = idx / 384;
    const float* Wr = gWih + (size_t)g * 65;
    float a = gbih[g] + rU[nt] * Wr[0];
    const float* c = ctx + (size_t)nt * AVc;
#pragma unroll
    for (int d = 0; d < 64; ++d) a += c[d] * Wr[1 + d];
    gi[(size_t)nt * 384 + g] = a;
}

// ---------------------------------------------------------------
// GRU scan. r6 post-mortem: VGPR_Count=120 < 128 weights — the compiler
// REMATERIALIZES the weight loads inside the barrier loop instead of keeping
// them resident. Fixes: (a) amdgpu_waves_per_eu(2,2) raises the per-wave
// budget to 256 VGPRs (6-wave block => 2 waves/SIMD is the HW floor anyway);
// (b) empty asm marks w0..w7 as asm-defined — rematerialization impossible.
__global__ __launch_bounds__(384) __attribute__((amdgpu_waves_per_eu(2, 2)))
void gru_scan_k(const float* __restrict__ gi, const float* __restrict__ gWhh,
                const float* __restrict__ gbhh, float* __restrict__ hs)
{
    int seq = blockIdx.x, g = threadIdx.x;
    __shared__ float h[128];
    __shared__ float gh[384];
    const f32v16* wp = (const f32v16*)(gWhh + (size_t)g * 128);
    f32v16 w0 = wp[0], w1 = wp[1], w2 = wp[2], w3 = wp[3];
    f32v16 w4 = wp[4], w5 = wp[5], w6 = wp[6], w7 = wp[7];
    asm volatile("" : "+v"(w0), "+v"(w1), "+v"(w2), "+v"(w3),
                      "+v"(w4), "+v"(w5), "+v"(w6), "+v"(w7));
    float bh = gbhh[g];
    if (g < 128) h[g] = 0.f;
    // preload gi row for t=0
    float g0 = 0.f, g1 = 0.f, g2 = 0.f;
    if (g < 128) {
        const float* gr = gi + (size_t)seq * 128 * 384;
        g0 = gr[g]; g1 = gr[128 + g]; g2 = gr[256 + g];
    }
    __syncthreads();
    for (int t = 0; t < 128; ++t) {
        float a0 = 0.f, a1 = 0.f, a2 = 0.f, a3 = 0.f;
#define GRU_STEP16(W, B) { \
        float4 x0 = *(const float4*)&h[B];      float4 x1 = *(const float4*)&h[(B) + 4]; \
        float4 x2 = *(const float4*)&h[(B) + 8]; float4 x3 = *(const float4*)&h[(B) + 12]; \
        a0 += x0.x * W[0];  a1 += x0.y * W[1];  a2 += x0.z * W[2];  a3 += x0.w * W[3]; \
        a0 += x1.x * W[4];  a1 += x1.y * W[5];  a2 += x1.z * W[6];  a3 += x1.w * W[7]; \
        a0 += x2.x * W[8];  a1 += x2.y * W[9];  a2 += x2.z * W[10]; a3 += x2.w * W[11]; \
        a0 += x3.x * W[12]; a1 += x3.y * W[13]; a2 += x3.z * W[14]; a3 += x3.w * W[15]; }
        GRU_STEP16(w0, 0)   GRU_STEP16(w1, 16)  GRU_STEP16(w2, 32)  GRU_STEP16(w3, 48)
        GRU_STEP16(w4, 64)  GRU_STEP16(w5, 80)  GRU_STEP16(w6, 96)  GRU_STEP16(w7, 112)
#undef GRU_STEP16
        gh[g] = bh + (a0 + a1) + (a2 + a3);
        __syncthreads();
        if (g < 128) {
            float r = 1.f / (1.f + expf(-(g0 + gh[g])));
            float z = 1.f / (1.f + expf(-(g1 + gh[128 + g])));
            float nn = tanhf(g2 + r * gh[256 + g]);
            float hn = (1.f - z) * nn + z * h[g];
            hs[((size_t)seq * 128 + t) * 128 + g] = hn;
            h[g] = hn;
            if (t + 1 < 128) {
                const float* gr = gi + ((size_t)seq * 128 + t + 1) * 384;
                g0 = gr[g]; g1 = gr[128 + g]; g2 = gr[256 + g];
            }
        }
        __syncthreads();
    }
}

// ---------------------------------------------------------------
__global__ __launch_bounds__(128)
void mlp_route_k(const float* __restrict__ proc, const float* __restrict__ hs,
                 const float* __restrict__ mW1, const float* __restrict__ mb1,
                 const float* __restrict__ mW2, const float* __restrict__ mb2,
                 float* __restrict__ probsOut, float* __restrict__ idxOut,
                 float* __restrict__ w)
{
    int n = blockIdx.x, tid = threadIdx.x;
    __shared__ float comb[256], tmp[128], lg[8];
    comb[tid] = proc[(size_t)n * 128 + tid];
    comb[128 + tid] = hs[(size_t)n * 128 + tid];
    __syncthreads();
    float a = mb1[tid];
#pragma unroll 8
    for (int d = 0; d < 256; ++d) a += comb[d] * mW1[(size_t)d * 128 + tid];
    tmp[tid] = fmaxf(a, 0.f);
    __syncthreads();
    if (tid < 8) {
        float l = mb2[tid];
        for (int d = 0; d < 128; ++d) l += tmp[d] * mW2[(size_t)d * 8 + tid];
        lg[tid] = l;
    }
    __syncthreads();
    if (tid == 0) {
        float mx = lg[0];
        for (int e = 1; e < 8; ++e) mx = fmaxf(mx, lg[e]);
        float p[8], s = 0.f;
        for (int e = 0; e < 8; ++e) { p[e] = expf(lg[e] - mx); s += p[e]; }
        float inv = 1.f / s;
        for (int e = 0; e < 8; ++e) probsOut[(size_t)n * 8 + e] = p[e] * inv;
        int a0 = 0; float v0 = lg[0];
        for (int e = 1; e < 8; ++e) if (lg[e] > v0) { v0 = lg[e]; a0 = e; }
        int a1 = -1; float v1 = -1e30f;
        for (int e = 0; e < 8; ++e) if (e != a0 && lg[e] > v1) { v1 = lg[e]; a1 = e; }
        float e1 = expf(v1 - v0);
        float t0 = 1.f / (1.f + e1), t1 = e1 / (1.f + e1);
        idxOut[(size_t)n * 2 + 0] = (float)a0;
        idxOut[(size_t)n * 2 + 1] = (float)a1;
        for (int e = 0; e < 8; ++e) w[(size_t)n * 8 + e] = 0.f;
        w[(size_t)n * 8 + a0] = t0;
        w[(size_t)n * 8 + a1] = t1;
    }
}

__global__ __launch_bounds__(256)
void compact_k(const float* __restrict__ w, int* __restrict__ cnt,
               int* __restrict__ list)
{
    int n = blockIdx.x * 256 + threadIdx.x;
    if (n >= NTc) return;
    for (int e = 0; e < NEc; ++e)
        if (w[(size_t)n * 8 + e] > 0.f) {
            int p = atomicAdd(&cnt[e], 1);
            list[e * NTc + p] = n;
        }
}

// ---------------------------------------------------------------
// LN1 batched over experts (blockIdx.y): LN(x[list[i]] + PRJ[i]) -> H1[i]
__global__ __launch_bounds__(256)
void ln1_k(const float* __restrict__ x, const int* __restrict__ listB,
           const float* __restrict__ addB, const float* __restrict__ sB,
           const float* __restrict__ bB, float* __restrict__ outB,
           const int* __restrict__ cntB)
{
    int e = blockIdx.y;
    int i = blockIdx.x;
    if (i >= cntB[e]) return;
    const int* list = listB + e * NTc;
    const float* add = addB + (size_t)e * NTc * Ec;
    const float* s = sB + e * Ec;
    const float* b = bB + e * Ec;
    float* outRows = outB + (size_t)e * NTc * Ec;
    int tid = threadIdx.x;
    int g = list[i];
    float v0 = x[(size_t)g * Ec + tid] + add[(size_t)i * Ec + tid];
    float v1 = x[(size_t)g * Ec + 256 + tid] + add[(size_t)i * Ec + 256 + tid];
    __shared__ float red[256];
    __shared__ float bc;
    red[tid] = v0 + v1; __syncthreads();
    for (int st = 128; st > 0; st >>= 1) { if (tid < st) red[tid] += red[tid + st]; __syncthreads(); }
    if (tid == 0) bc = red[0] * (1.f / 512.f);
    __syncthreads();
    float mu = bc;
    float d0 = v0 - mu, d1 = v1 - mu;
    __syncthreads();
    red[tid] = d0 * d0 + d1 * d1; __syncthreads();
    for (int st = 128; st > 0; st >>= 1) { if (tid < st) red[tid] += red[tid + st]; __syncthreads(); }
    if (tid == 0) bc = rsqrtf(red[0] * (1.f / 512.f) + 1e-5f);
    __syncthreads();
    float inv = bc;
    outRows[(size_t)i * Ec + tid] = d0 * inv * s[tid] + b[tid];
    outRows[(size_t)i * Ec + 256 + tid] = d1 * inv * s[256 + tid] + b[256 + tid];
}

// LN2 batched over experts; atomic scatter (experts' token sets overlap)
__global__ __launch_bounds__(256)
void ln2_scatter_k(const float* __restrict__ H1B, const float* __restrict__ YB,
                   const float* __restrict__ sB, const float* __restrict__ bB,
                   float* __restrict__ out, const int* __restrict__ listB,
                   const int* __restrict__ cntB, const float* __restrict__ wB)
{
    int e = blockIdx.y;
    int i = blockIdx.x;
    if (i >= cntB[e]) return;
    const int* list = listB + e * NTc;
    const float* H1 = H1B + (size_t)e * NTc * Ec;
    const float* Y = YB + (size_t)e * NTc * Ec;
    const float* s = sB + e * Ec;
    const float* b = bB + e * Ec;
    const float* wvec = wB + e;
    int tid = threadIdx.x;
    int g = list[i];
    float v0 = H1[(size_t)i * Ec + tid] + Y[(size_t)i * Ec + tid];
    float v1 = H1[(size_t)i * Ec + 256 + tid] + Y[(size_t)i * Ec + 256 + tid];
    __shared__ float red[256];
    __shared__ float bc;
    red[tid] = v0 + v1; __syncthreads();
    for (int st = 128; st > 0; st >>= 1) { if (tid < st) red[tid] += red[tid + st]; __syncthreads(); }
    if (tid == 0) bc = red[0] * (1.f / 512.f);
    __syncthreads();
    float mu = bc;
    float d0 = v0 - mu, d1 = v1 - mu;
    __syncthreads();
    red[tid] = d0 * d0 + d1 * d1; __syncthreads();
    for (int st = 128; st > 0; st >>= 1) { if (tid < st) red[tid] += red[tid + st]; __syncthreads(); }
    if (tid == 0) bc = rsqrtf(red[0] * (1.f / 512.f) + 1e-5f);
    __syncthreads();
    float inv = bc;
    float wv = wvec[(size_t)g * 8];
    atomicAdd(&out[(size_t)g * Ec + tid], (d0 * inv * s[tid] + b[tid]) * wv);
    atomicAdd(&out[(size_t)g * Ec + 256 + tid], (d1 * inv * s[256 + tid] + b[256 + tid]) * wv);
}

// ---------------------------------------------------------------
extern "C" void kernel_launch(void* const* d_in, const int* in_sizes, int n_in,
                              void* d_out, int out_size, void* d_ws, size_t ws_size,
                              hipStream_t stream)
{
    const float* x    = (const float*)d_in[0];
    const float* rU   = (const float*)d_in[1];
    const float* rR   = (const float*)d_in[2];
    const float* rS   = (const float*)d_in[3];
    const float* Wtp  = (const float*)d_in[6];
    const float* btp  = (const float*)d_in[7];
    const float* Wq   = (const float*)d_in[8];
    const float* bq   = (const float*)d_in[9];
    const float* Wk   = (const float*)d_in[10];
    const float* bk   = (const float*)d_in[11];
    const float* Wv   = (const float*)d_in[12];
    const float* bv   = (const float*)d_in[13];
    const float* gWih = (const float*)d_in[14];
    const float* gbih = (const float*)d_in[15];
    const float* gWhh = (const float*)d_in[16];
    const float* gbhh = (const float*)d_in[17];
    const float* mW1  = (const float*)d_in[18];
    const float* mb1  = (const float*)d_in[19];
    const float* mW2  = (const float*)d_in[20];
    const float* mb2  = (const float*)d_in[21];
    const float* sWq  = (const float*)d_in[22];
    const float* sbq  = (const float*)d_in[23];
    const float* sWk  = (const float*)d_in[24];
    const float* sbk  = (const float*)d_in[25];
    const float* sWv  = (const float*)d_in[26];
    const float* sbv  = (const float*)d_in[27];
    const float* sWo  = (const float*)d_in[28];
    const float* sbo  = (const float*)d_in[29];
    const float* sln1s = (const float*)d_in[30];
    const float* sln1b = (const float*)d_in[31];
    const float* sW1  = (const float*)d_in[32];
    const float* sb1  = (const float*)d_in[33];
    const float* sW2  = (const float*)d_in[34];
    const float* sb2  = (const float*)d_in[35];
    const float* sln2s = (const float*)d_in[36];
    const float* sln2b = (const float*)d_in[37];
    const float* fW1  = (const float*)d_in[38];
    const float* fb1  = (const float*)d_in[39];
    const float* fW2  = (const float*)d_in[40];
    const float* fb2  = (const float*)d_in[41];

    float* out      = (float*)d_out;                 // [2048,512]
    float* probsOut = out + (size_t)NTc * Ec;        // [2048,8]
    float* idxOut   = probsOut + (size_t)NTc * NEc;  // [2048,2]

    // ---- workspace layout ----
    int*   cnt  = (int*)d_ws;                        // 64 ints
    int*   list = cnt + 64;                          // 8*2048
    float* w    = (float*)d_ws + 64 + NEc * NTc;     // [2048,8]
    __bf16* WB = (__bf16*)(w + NTc * NEc);
    auto QKVO_T = [&](int e, int i) { return WB + ((size_t)(e * 4 + i)) * 262144; };
    __bf16* sW1T = WB + 8 * 262144;            // 2 x [2048][512]
    __bf16* sW2T = sW1T + 2 * 1048576;         // 2 x [512][2048]
    __bf16* fW1T = sW2T + 2 * 1048576;         // 3 x [2048][512] (round 1)
    __bf16* fW2T = fW1T + 3 * 1048576;         // 3 x [512][2048] (round 1)
    float* act = (float*)(fW2T + 3 * 1048576);
    float* QbB = act;                          // 2 x [2048][512]
    float* KbB = act + 2 * 1048576;            // 2 x
    float* VtB = act + 4 * 1048576;            // 2 x [512][2048] d-major
    float* AOB = act + 6 * 1048576;            // 2 x
    float* H1B = act + 8 * 1048576;            // 2 x
    float* PRJB = QbB;                         // alias (Qb dead after flash)
    float* YbB  = KbB;                         // alias (Kb dead after flash)
    __bf16* FF1syn = (__bf16*)VtB;             // 2 x [2048][2048] bf16 (Vt/AO dead)
    __bf16* FF1ffn = (__bf16*)act;             // 3 x [2048][2048] bf16 (FFN phase)
    // round-2 FFN weights live in the act tail (free once synergy is done):
    __bf16* fW1T2 = FF1ffn + (size_t)3 * NTc * Hc;   // 3 x [2048][512]
    __bf16* fW2T2 = fW1T2 + 3 * 1048576;             // 3 x [512][2048]
    // router region overlays act (dead before experts start)
    float* proc = act;                 // 2048*128
    float* q4   = act + 262144;
    float* ctx  = act + 393216;
    float* gi   = act + 524288;        // 16*128*384
    float* hs   = act + 1310720;       // 2048*128

    // ---- init ----
    zero_k<<<1024, 256, 0, stream>>>(out, cnt);

    // ---- router (fp32 — keeps top-2 idx bit-stable) ----
    gemm_k<<<dim3(32, 2), 256, 0, stream>>>(x, Ec, Wtp, Pc, btp, proc, Pc, NTc, Pc, Ec, 1);
    gemm_k<<<dim3(32, 1), 256, 0, stream>>>(proc, Pc, Wq, AKc, bq, q4, AKc, NTc, AKc, Pc, 0);
    router_ctx_k<<<512, 256, 0, stream>>>(q4, rR, rS, Wk, bk, Wv, bv, ctx);
    gi_k<<<3072, 256, 0, stream>>>(rU, ctx, gWih, gbih, gi);
    gru_scan_k<<<16, 384, 0, stream>>>(gi, gWhh, gbhh, hs);
    mlp_route_k<<<2048, 128, 0, stream>>>(proc, hs, mW1, mb1, mW2, mb2,
                                          probsOut, idxOut, w);
    compact_k<<<8, 256, 0, stream>>>(w, cnt, list);

    GJob JZ = {};

    // ---- synergy weight conversion (3 dispatches) ----
    {
        CJobs8 cq = {};
        for (int e = 0; e < 2; ++e) {
            cq.j[e * 4 + 0] = { sWq + (size_t)e * Ec * Ec, QKVO_T(e, 0) };
            cq.j[e * 4 + 1] = { sWk + (size_t)e * Ec * Ec, QKVO_T(e, 1) };
            cq.j[e * 4 + 2] = { sWv + (size_t)e * Ec * Ec, QKVO_T(e, 2) };
            cq.j[e * 4 + 3] = { sWo + (size_t)e * Ec * Ec, QKVO_T(e, 3) };
        }
        convT_k<<<dim3(16, 16, 8), 256, 0, stream>>>(cq, Ec, Ec);
        CJobs8 c1 = {};
        c1.j[0] = { sW1, sW1T };
        c1.j[1] = { sW1 + (size_t)Ec * Hc, sW1T + 1048576 };
        convT_k<<<dim3(64, 16, 2), 256, 0, stream>>>(c1, Ec, Hc);
        CJobs8 c2 = {};
        c2.j[0] = { sW2, sW2T };
        c2.j[1] = { sW2 + (size_t)Hc * Ec, sW2T + 1048576 };
        convT_k<<<dim3(16, 64, 2), 256, 0, stream>>>(c2, Hc, Ec);
    }

    // ---- QKV for both experts: one 6-job dispatch ----
    {
        GJobs6 js = {};
        for (int e = 0; e < 2; ++e) {
            GJob jq = JZ;
            jq.A = x; jq.Mptr = cnt + e; jq.gatherA = list + e * NTc;
            jq.B = QKVO_T(e, 0); jq.bias = sbq + e * Ec;
            jq.C = QbB + (size_t)e * NTc * Ec; jq.ldc = Ec; jq.flags = 0;
            GJob jk = jq; jk.B = QKVO_T(e, 1); jk.bias = sbk + e * Ec;
            jk.C = KbB + (size_t)e * NTc * Ec;
            GJob jv = jq; jv.B = QKVO_T(e, 2); jv.bias = sbv + e * Ec;
            jv.C = VtB + (size_t)e * NTc * Ec; jv.ldc = NTc; jv.flags = 2;
            js.j[e * 3 + 0] = jq; js.j[e * 3 + 1] = jk; js.j[e * 3 + 2] = jv;
        }
        gemm_batch_k<0><<<dim3(16, 4, 6), 256, 0, stream>>>(js, Ec, Ec, Ec, Ec, 4, 16);
    }

    // ---- flash attention, both experts ----
    flash_k<<<dim3(32, 4, 2), 256, 0, stream>>>(QbB, KbB, VtB, AOB, cnt);

    // ---- Wo projection, both experts ----
    {
        GJobs6 js = {};
        for (int e = 0; e < 2; ++e) {
            GJob jo = JZ;
            jo.A = AOB + (size_t)e * NTc * Ec; jo.Mptr = cnt + e;
            jo.B = QKVO_T(e, 3); jo.bias = sbo + e * Ec;
            jo.C = PRJB + (size_t)e * NTc * Ec; jo.ldc = Ec;
            js.j[e] = jo;
        }
        gemm_batch_k<0><<<dim3(16, 4, 2), 256, 0, stream>>>(js, Ec, Ec, Ec, Ec, 4, 16);
    }

    // ---- LN1, both experts ----
    ln1_k<<<dim3(2048, 2), 256, 0, stream>>>(x, list, PRJB, sln1s, sln1b, H1B, cnt);

    // ---- FF1 (relu, bf16 out), both experts ----
    {
        GJobs6 js = {};
        for (int e = 0; e < 2; ++e) {
            GJob j1 = JZ;
            j1.A = H1B + (size_t)e * NTc * Ec; j1.Mptr = cnt + e;
            j1.B = sW1T + (size_t)e * 1048576; j1.bias = sb1 + (size_t)e * Hc;
            j1.C = FF1syn + (size_t)e * NTc * Hc; j1.ldc = Hc; j1.flags = 1 | 4;
            js.j[e] = j1;
        }
        gemm_batch_k<0><<<dim3(16, 16, 2), 256, 0, stream>>>(js, Ec, Ec, Hc, Ec, 16, 16);
    }

    // ---- FF2 (bf16 A), both experts ----
    {
        GJobs6 js = {};
        for (int e = 0; e < 2; ++e) {
            GJob j2 = JZ;
            j2.A = FF1syn + (size_t)e * NTc * Hc; j2.Mptr = cnt + e;
            j2.B = sW2T + (size_t)e * 1048576; j2.bias = sb2 + (size_t)e * Ec;
            j2.C = YbB + (size_t)e * NTc * Ec; j2.ldc = Ec;
            js.j[e] = j2;
        }
        gemm_batch_k<1><<<dim3(16, 4, 2), 256, 0, stream>>>(js, Hc, Hc, Ec, Hc, 4, 64);
    }

    // ---- LN2 + weighted scatter (atomic), both experts ----
    ln2_scatter_k<<<dim3(2048, 2), 256, 0, stream>>>(H1B, YbB, sln2s, sln2b,
                                                     out, list, cnt, w);

    // ---- FFN experts: all 6 weight conversions upfront (2 dispatches) ----
    {
        CJobs8 a = {};
        for (int u = 0; u < 6; ++u)
            a.j[u] = { fW1 + (size_t)u * Ec * Hc,
                       (u < 3 ? fW1T + (size_t)u * 1048576
                              : fW1T2 + (size_t)(u - 3) * 1048576) };
        convT_k<<<dim3(64, 16, 6), 256, 0, stream>>>(a, Ec, Hc);
        CJobs8 b = {};
        for (int u = 0; u < 6; ++u)
            b.j[u] = { fW2 + (size_t)u * Hc * Ec,
                       (u < 3 ? fW2T + (size_t)u * 1048576
                              : fW2T2 + (size_t)(u - 3) * 1048576) };
        convT_k<<<dim3(16, 64, 6), 256, 0, stream>>>(b, Hc, Ec);
    }

    // ---- FFN GEMMs: 2 rounds of 3 ----
    for (int rnd = 0; rnd < 2; ++rnd) {
        int f0 = rnd * 3;
        __bf16* W1 = rnd == 0 ? fW1T : fW1T2;
        __bf16* W2 = rnd == 0 ? fW2T : fW2T2;
        {
            GJobs6 js = {};
            for (int u = 0; u < 3; ++u) {
                int f = f0 + u, e = f + NSc;
                GJob j1 = JZ;
                j1.A = x; j1.Mptr = cnt + e; j1.gatherA = list + e * NTc;
                j1.B = W1 + (size_t)u * 1048576; j1.bias = fb1 + (size_t)f * Hc;
                j1.C = FF1ffn + (size_t)u * NTc * Hc; j1.ldc = Hc; j1.flags = 1 | 4;
                js.j[u] = j1;
            }
            gemm_batch_k<0><<<dim3(16, 16, 3), 256, 0, stream>>>(js, Ec, Ec, Hc, Ec, 16, 16);
        }
        {
            // FF2 scatter with split-K: 4 chunks of 16 k-iters (K=2048)
            GJobs6 js = {};
            for (int u = 0; u < 3; ++u) {
                int f = f0 + u, e = f + NSc;
                GJob j2 = JZ;
                j2.A = FF1ffn + (size_t)u * NTc * Hc; j2.Mptr = cnt + e;
                j2.B = W2 + (size_t)u * 1048576; j2.bias = fb2 + (size_t)f * Ec;
                j2.scatterOut = out; j2.scatterList = list + e * NTc;
                j2.wvec = w + e; j2.ldc = Ec;
                js.j[u] = j2;
            }
            gemm_batch_k<1><<<dim3(16, 16, 3), 256, 0, stream>>>(js, Hc, Hc, Ec, Hc, 4, 16);
        }
    }
}